// Round 1
// 952.883 us; speedup vs baseline: 1.0368x; 1.0368x over previous
//
#include <hip/hip_runtime.h>
#include <cstdint>
#include <cstddef>

#define B_ 2
#define S_ 1024
#define H_ 2048
#define HV_ 32
#define HK_ 16
#define DK_ 128
#define DV_ 128
#define CC_ 8192
#define KEYDIM_ 2048
#define VALDIM_ 4096
#define NC_ 16          // chunks
#define CS_ 64          // chunk size
#define NBIG 12416      // fused GEMM1 N (real, C pitch): 8192 qkv + 4096 z + 32 b + 32 a + 64 pad
#define NBIGP 12544     // padded to 49*256 for the 256-wide GEMM tile (B-matrix rows only)

typedef __attribute__((ext_vector_type(8))) short bf16x8;
typedef __attribute__((ext_vector_type(4))) float f32x4;

__device__ __forceinline__ ushort f2bf_rne(float x) {
  union { float f; uint32_t u; } c; c.f = x;
  uint32_t u = c.u + 0x7FFFu + ((c.u >> 16) & 1u);
  return (ushort)(u >> 16);
}

// async 16B global->LDS (DMA; LDS dest = wave-uniform base + lane*16)
__device__ __forceinline__ void gld16(const void* g, void* l) {
  __builtin_amdgcn_global_load_lds(
      (const __attribute__((address_space(1))) void*)g,
      (__attribute__((address_space(3))) void*)l, 16, 0, 0);
}

// ---------------------------------------------------------------------------
// fp32 -> bf16 convert (n multiple of 1024)
// ---------------------------------------------------------------------------
__global__ void f2bf_kernel(const float* __restrict__ in, ushort* __restrict__ out, int n) {
  int i = (blockIdx.x * 256 + threadIdx.x) * 4;
  if (i >= n) return;
  float4 v = *(const float4*)(in + i);
  ushort4 o;
  o.x = f2bf_rne(v.x); o.y = f2bf_rne(v.y);
  o.z = f2bf_rne(v.z); o.w = f2bf_rne(v.w);
  *(ushort4*)(out + i) = o;
}

// ---------------------------------------------------------------------------
// wcat: build concatenated bf16 weight (NBIGP, H): [W_qkv; W_z; W_b; W_a; 0]
// rows 12352..12543 are zero pad (last 128 rows exist only for tile alignment)
// ---------------------------------------------------------------------------
__global__ void wcat_kernel(const float* __restrict__ Wqkv, const float* __restrict__ Wz,
                            const float* __restrict__ Wb, const float* __restrict__ Wa,
                            ushort* __restrict__ out) {
  int i = (blockIdx.x * 256 + threadIdx.x) * 4;
  if (i >= NBIGP * H_) return;
  int n = i >> 11;           // / H_
  int k = i & (H_ - 1);
  float4 v = make_float4(0.f, 0.f, 0.f, 0.f);
  if (n < 8192)       v = *(const float4*)(Wqkv + (size_t)n * H_ + k);
  else if (n < 12288) v = *(const float4*)(Wz + (size_t)(n - 8192) * H_ + k);
  else if (n < 12320) v = *(const float4*)(Wb + (size_t)(n - 12288) * H_ + k);
  else if (n < 12352) v = *(const float4*)(Wa + (size_t)(n - 12320) * H_ + k);
  ushort4 o;
  o.x = f2bf_rne(v.x); o.y = f2bf_rne(v.y);
  o.z = f2bf_rne(v.z); o.w = f2bf_rne(v.w);
  *(ushort4*)(out + i) = o;
}

// ===========================================================================
// gemm256_8ph: bf16 MFMA GEMM (NT), 256x256 tile, BK=64, 8 waves (2Mx4N),
// 128 KiB LDS double-buffer, derived-waits deep pipeline (T3+T4+T5):
//   per K-tile, 4 phases; each phase: vmcnt(4) -> s_barrier -> issue one
//   quarter-stage of tile t+1 -> ds_read one operand sub-tile -> 16 MFMA
//   under setprio(1). vmcnt NEVER drains to 0 in the main loop; each
//   quarter-stage has 3-4 phases of latency slack.
// Stage order S0=A[a0], S1=B[b0], S2=B[b1], S3=A[a1] Gray-matched to compute
// order (a0,b0),(a0,b1),(a1,b1),(a1,b0) => uniform vmcnt(4) and frag reuse
// (A read once per a-half, B once per b-half).
// LDS is fragment-ordered (1 KiB segments, lane-sequential 16B) => 0 bank
// conflicts by construction, and matches global_load_lds' linear lane order.
// Correctness: every wave's vmcnt precedes its barrier => after barrier the
// needed quarter is resident for ALL waves. Buffer-swap WAR is protected by
// the next block's phase-0 barrier (stages are issued only after it).
// C stores guarded at col < Ns (B rows >= Ns are zero pad).
// ===========================================================================
#define MEMF() asm volatile("" ::: "memory")
#define VMW(n) asm volatile("s_waitcnt vmcnt(" #n ")" ::: "memory")
#define BARR() do { __builtin_amdgcn_s_barrier(); MEMF(); } while (0)

#define ST(P, SHM, RG, o, kq) do {                                  \
    gld16((P) + (kq),      &SHM[o][((RG) * 2 + 0) * 512]);          \
    gld16((P) + (kq) + 32, &SHM[o][((RG) * 2 + 1) * 512]);          \
  } while (0)

#define LDA(ah, c) do { _Pragma("unroll")                                            \
    for (int i_ = 0; i_ < 4; i_++) { _Pragma("unroll")                               \
      for (int h_ = 0; h_ < 2; h_++)                                                 \
        aF[i_ * 2 + h_] = *(const bf16x8*)(                                          \
            &sAm[c][((wm * 8 + (ah) * 4 + i_) * 2 + h_) * 512 + lane * 8]); } } while (0)

#define LDB(dst, bh, c) do { _Pragma("unroll")                                       \
    for (int j_ = 0; j_ < 2; j_++) { _Pragma("unroll")                               \
      for (int h_ = 0; h_ < 2; h_++)                                                 \
        dst[j_ * 2 + h_] = *(const bf16x8*)(                                         \
            &sBm[c][((wn * 4 + (bh) * 2 + j_) * 2 + h_) * 512 + lane * 8]); } } while (0)

#define MM(ah, bh, bsrc) do {                                                        \
    __builtin_amdgcn_s_setprio(1);                                                   \
    _Pragma("unroll") for (int h_ = 0; h_ < 2; h_++)                                 \
    _Pragma("unroll") for (int i_ = 0; i_ < 4; i_++)                                 \
    _Pragma("unroll") for (int j_ = 0; j_ < 2; j_++)                                 \
      acc[(ah) * 4 + i_][(bh) * 2 + j_] = __builtin_amdgcn_mfma_f32_16x16x32_bf16(   \
          aF[i_ * 2 + h_], bsrc[j_ * 2 + h_], acc[(ah) * 4 + i_][(bh) * 2 + j_],     \
          0, 0, 0);                                                                  \
    __builtin_amdgcn_s_setprio(0);                                                   \
  } while (0)

__global__ __launch_bounds__(512, 2) void gemm256_8ph(
    const ushort* __restrict__ A, const ushort* __restrict__ B,
    float* __restrict__ C, int Ns, int K)
{
  __shared__ ushort sAm[2][16384];   // 2 bufs x 256 rows x 64 k (fragment-ordered)
  __shared__ ushort sBm[2][16384];

  const int t = threadIdx.x;
  const int wave = t >> 6, lane = t & 63;
  const int wm = wave >> 2, wn = wave & 3;
  const int l15 = lane & 15, l4 = lane >> 4;
  const int mt = blockIdx.x, nt = blockIdx.y;

  // per-wave row-groups (16 rows each) for the 4 stage-sets
  const int rgS0 = (wave & 3) + (wave >> 2) * 8;   // A rows {0-63,128-191}
  const int rgS3 = rgS0 + 4;                       // A rows {64-127,192-255}
  const int rgS1 = (wave & 1) + (wave >> 1) * 4;   // B rows, b-half 0
  const int rgS2 = rgS1 + 2;                       // B rows, b-half 1

  const ushort* aP0 = A + (size_t)(mt * 256 + rgS0 * 16 + l15) * K + l4 * 8;
  const ushort* aP1 = A + (size_t)(mt * 256 + rgS3 * 16 + l15) * K + l4 * 8;
  const ushort* bP0 = B + (size_t)(nt * 256 + rgS1 * 16 + l15) * K + l4 * 8;
  const ushort* bP1 = B + (size_t)(nt * 256 + rgS2 * 16 + l15) * K + l4 * 8;

  f32x4 acc[8][4];
  #pragma unroll
  for (int i = 0; i < 8; i++)
    #pragma unroll
    for (int j = 0; j < 4; j++)
      #pragma unroll
      for (int r = 0; r < 4; r++) acc[i][j][r] = 0.f;

  bf16x8 aF[8], bF0[4], bF1[4];

  // prologue: tile 0, issue order S0,S1,S2,S3 (fenced so vmcnt counting holds)
  ST(aP0, sAm, rgS0, 0, 0); MEMF();
  ST(bP0, sBm, rgS1, 0, 0); MEMF();
  ST(bP1, sBm, rgS2, 0, 0); MEMF();
  ST(aP1, sAm, rgS3, 0, 0); MEMF();

  const int NT = K >> 6;
  for (int tt = 0; tt < NT - 1; tt++) {
    const int c = tt & 1, o = c ^ 1;
    const int kq = (tt + 1) << 6;
    // phase 0: needs S0(t),S1(t); newer = S2(t),S3(t) -> vmcnt(4)
    VMW(4); BARR();
    ST(aP0, sAm, rgS0, o, kq);
    LDA(0, c); LDB(bF0, 0, c);
    MM(0, 0, bF0);
    // phase 1: needs S2(t); newer = S3(t),S0(t+1) -> vmcnt(4)
    VMW(4); BARR();
    ST(bP0, sBm, rgS1, o, kq);
    LDB(bF1, 1, c);
    MM(0, 1, bF1);
    // phase 2: needs S3(t); newer = S0(t+1),S1(t+1) -> vmcnt(4)
    VMW(4); BARR();
    ST(bP1, sBm, rgS2, o, kq);
    LDA(1, c);
    MM(1, 1, bF1);
    // phase 3: no new residency need; no barrier (next block's phase-0
    // barrier provides the buffer-swap WAR protection)
    MEMF();
    ST(aP1, sAm, rgS3, o, kq);
    MM(1, 0, bF0);
  }
  { // epilogue K-tile: no staging; drain 4 -> 2 -> 0
    const int c = (NT - 1) & 1;
    VMW(4); BARR();
    LDA(0, c); LDB(bF0, 0, c);
    MM(0, 0, bF0);
    VMW(2); BARR();
    LDB(bF1, 1, c);
    MM(0, 1, bF1);
    VMW(0); BARR();
    LDA(1, c);
    MM(1, 1, bF1);
    MM(1, 0, bF0);
  }

  #pragma unroll
  for (int mf = 0; mf < 8; mf++) {
    const int row0 = mt * 256 + wm * 128 + mf * 16 + l4 * 4;
    #pragma unroll
    for (int nf = 0; nf < 4; nf++) {
      const int col = nt * 256 + wn * 64 + nf * 16 + l15;
      if (col < Ns) {
        #pragma unroll
        for (int r = 0; r < 4; r++)
          C[(size_t)(row0 + r) * Ns + col] = acc[mf][nf][r];
      }
    }
  }
}

// ---------------------------------------------------------------------------
// Double-buffered stage of one BK=64 tile half-pair (8 gld16 per wave).
// Fragment-ordered segments: h*4096 + seg*512 ushorts; seg = 16 rows.
// (kept for the 128x128 kernel used by GEMM2)
// ---------------------------------------------------------------------------
__device__ __forceinline__ void stage_tile(
    const ushort* aS0, const ushort* aS1, const ushort* bS0, const ushort* bS1,
    ushort* ldsA, ushort* ldsB, int wave, int k0)
{
  #pragma unroll
  for (int h = 0; h < 2; h++) {
    gld16(aS0 + k0 + h * 32, ldsA + h * 4096 + (wave * 2 + 0) * 512);
    gld16(aS1 + k0 + h * 32, ldsA + h * 4096 + (wave * 2 + 1) * 512);
    gld16(bS0 + k0 + h * 32, ldsB + h * 4096 + (wave * 2 + 0) * 512);
    gld16(bS1 + k0 + h * 32, ldsB + h * 4096 + (wave * 2 + 1) * 512);
  }
}

// ---------------------------------------------------------------------------
// bf16 MFMA GEMM (NT): 128x128 tile, BK=64, double-buffered. Used for GEMM2
// (M=2048,N=2048: only 64 tiles at 256 width -> 128 tile keeps CUs busy).
// ---------------------------------------------------------------------------
__global__ __launch_bounds__(256) void gemm_bf16_nt(
    const ushort* __restrict__ A, const ushort* __restrict__ B,
    float* __restrict__ C, int M, int N, int K)
{
  __shared__ ushort sL[2][2][8192];   // [buf][A/B][2 halves x 8 segs x 512]
  int t = threadIdx.x;
  int wave = t >> 6, lane = t & 63;
  int wm = wave >> 1, wn = wave & 1;
  int lrow = lane & 15, quad = lane >> 4;
  int mt = blockIdx.x, nt = blockIdx.y;

  f32x4 acc[4][4];
  #pragma unroll
  for (int i = 0; i < 4; i++)
    #pragma unroll
    for (int j = 0; j < 4; j++)
      #pragma unroll
      for (int r = 0; r < 4; r++) acc[i][j][r] = 0.f;

  const ushort* aS0 = A + (size_t)(mt * 128 + (wave * 2 + 0) * 16 + lrow) * K + quad * 8;
  const ushort* aS1 = A + (size_t)(mt * 128 + (wave * 2 + 1) * 16 + lrow) * K + quad * 8;
  const ushort* bS0 = B + (size_t)(nt * 128 + (wave * 2 + 0) * 16 + lrow) * K + quad * 8;
  const ushort* bS1 = B + (size_t)(nt * 128 + (wave * 2 + 1) * 16 + lrow) * K + quad * 8;

  stage_tile(aS0, aS1, bS0, bS1, &sL[0][0][0], &sL[0][1][0], wave, 0);
  __syncthreads();

  const int NK = K >> 6;
  for (int it = 0; it < NK; it++) {
    if (it + 1 < NK)
      stage_tile(aS0, aS1, bS0, bS1,
                 &sL[(it + 1) & 1][0][0], &sL[(it + 1) & 1][1][0],
                 wave, (it + 1) * 64);
    const ushort* bufA = &sL[it & 1][0][0];
    const ushort* bufB = &sL[it & 1][1][0];
    #pragma unroll
    for (int h = 0; h < 2; h++) {
      bf16x8 af[4], bfr[4];
      #pragma unroll
      for (int i = 0; i < 4; i++)
        af[i] = *(const bf16x8*)(bufA + h * 4096 + (wm * 4 + i) * 512 + lane * 8);
      #pragma unroll
      for (int j = 0; j < 4; j++)
        bfr[j] = *(const bf16x8*)(bufB + h * 4096 + (wn * 4 + j) * 512 + lane * 8);
      #pragma unroll
      for (int i = 0; i < 4; i++)
        #pragma unroll
        for (int j = 0; j < 4; j++)
          acc[i][j] = __builtin_amdgcn_mfma_f32_16x16x32_bf16(af[i], bfr[j], acc[i][j], 0, 0, 0);
    }
    __syncthreads();
  }

  #pragma unroll
  for (int i = 0; i < 4; i++) {
    int m_base = mt * 128 + wm * 64 + i * 16 + quad * 4;
    #pragma unroll
    for (int j = 0; j < 4; j++) {
      int n = nt * 128 + wn * 64 + j * 16 + lrow;
      #pragma unroll
      for (int rr = 0; rr < 4; rr++)
        C[(size_t)(m_base + rr) * N + n] = acc[i][j][rr];
    }
  }
}

// ---------------------------------------------------------------------------
// conv_state_new[b][c][j] = mixed_qkv[b][S-3+j][c]  (from (B,S,NBIG) C-matrix)
// ---------------------------------------------------------------------------
__global__ void convstate_kernel(const float* __restrict__ Cbig,
                                 float* __restrict__ out)
{
  int idx = blockIdx.x * blockDim.x + threadIdx.x;
  if (idx >= B_ * CC_ * 3) return;
  int j = idx % 3;
  int c = (idx / 3) % CC_;
  int b = idx / (3 * CC_);
  out[idx] = Cbig[((size_t)(b * S_ + (S_ - 3 + j))) * NBIG + c];
}

// ---------------------------------------------------------------------------
// prep_qkv: conv(K=4)+silu; l2norm q/k heads. qkv read from C-matrix cols 0..8191
// ---------------------------------------------------------------------------
__global__ __launch_bounds__(128) void prep_qkv(
    const float* __restrict__ Cbig, const float* __restrict__ conv_state,
    const float* __restrict__ conv_w,
    float* __restrict__ Qn, float* __restrict__ Kn, float* __restrict__ Vb)
{
  int group = blockIdx.x, s = blockIdx.y, b = blockIdx.z;
  int t = threadIdx.x;
  int c = group * 128 + t;
  float acc = 0.f;
  #pragma unroll
  for (int kk = 0; kk < 4; kk++) {
    int sp = s - 3 + kk;
    float x = (sp < 0) ? conv_state[((size_t)(b * CC_ + c)) * 3 + (3 + sp)]
                       : Cbig[((size_t)(b * S_ + sp)) * NBIG + c];
    acc += conv_w[c * 4 + kk] * x;
  }
  float val = acc / (1.f + __expf(-acc));   // silu

  if (group < 32) {
    __shared__ float red2[2];
    float p = val * val;
    #pragma unroll
    for (int off = 32; off > 0; off >>= 1) p += __shfl_xor(p, off);
    if ((t & 63) == 0) red2[t >> 6] = p;
    __syncthreads();
    float r = rsqrtf(red2[0] + red2[1] + 1e-6f);
    if (group < 16) {
      r *= 0.08838834764831845f;  // 128^-0.5
      Qn[(((size_t)(b * HK_ + group)) * S_ + s) * DK_ + t] = val * r;
    } else {
      Kn[(((size_t)(b * HK_ + (group - 16))) * S_ + s) * DK_ + t] = val * r;
    }
  } else {
    Vb[(((size_t)(b * HV_ + (group - 32))) * S_ + s) * DV_ + t] = val;
  }
}

// ---------------------------------------------------------------------------
// prep_gb: g/beta from C-matrix cols 12288..12351
// ---------------------------------------------------------------------------
__global__ void prep_gb(const float* __restrict__ Cbig,
                        const float* __restrict__ A_log, const float* __restrict__ dt_bias,
                        float* __restrict__ g_buf, float* __restrict__ beta_buf)
{
  int idx = blockIdx.x * blockDim.x + threadIdx.x;
  if (idx >= B_ * HV_ * S_) return;
  int s = idx & (S_ - 1);
  int hv = (idx >> 10) & 31;
  int b = idx >> 15;
  float bv = Cbig[((size_t)(b * S_ + s)) * NBIG + 12288 + hv];
  float av = Cbig[((size_t)(b * S_ + s)) * NBIG + 12320 + hv];
  float x = av + dt_bias[hv];
  float sp = (x > 20.f) ? x : log1pf(__expf(x));
  g_buf[idx] = -__expf(A_log[hv]) * sp;
  beta_buf[idx] = 1.f / (1.f + __expf(-bv));
}

// ---------------------------------------------------------------------------
// cp_kernel: per (b,hv,chunk). G cumsum, M, A, Tinv, Kc, D0.
// ---------------------------------------------------------------------------
__device__ __forceinline__ int swf4(int r, int f) { return r * 32 + (f ^ (r & 31)); }
__device__ __forceinline__ int swf1(int r, int k) {
  return r * 128 + 4 * ((k >> 2) ^ (r & 31)) + (k & 3);
}

__global__ __launch_bounds__(256) void cp_kernel(
    const float* __restrict__ Qn, const float* __restrict__ Kn,
    const float* __restrict__ Vb,
    const float* __restrict__ g_buf, const float* __restrict__ beta_buf,
    float* __restrict__ G_buf, float* __restrict__ M_buf,
    float* __restrict__ KcD, float* __restrict__ D0p)
{
  __shared__ float sK[64 * 128];
  __shared__ float sX[32 * 128];
  __shared__ float sT[64 * 64];
  float* sG  = sT;
  float* sBe = sT + 64;
  float* sA  = sX;
  float* tTw = sX;
  float* tTb = sX;
  float4* sK4 = (float4*)sK;
  float4* sX4 = (float4*)sX;

  const int ch = blockIdx.x;
  const int bh = ch / NC_, c = ch % NC_;
  const int b = bh >> 5, hv = bh & 31, hk = hv >> 1;
  const int s0 = c * CS_;
  const int t = threadIdx.x;
  const size_t gOff = (size_t)bh * S_ + s0;

  float Gw0 = 0.f, Bw0 = 0.f;
  if (t < 64) {
    float gi = g_buf[gOff + t];
    Gw0 = gi;
    #pragma unroll
    for (int off = 1; off < 64; off <<= 1) {
      float o = __shfl_up(Gw0, off);
      if (t >= off) Gw0 += o;
    }
    G_buf[gOff + t] = Gw0;
    sG[t] = Gw0;
    Bw0 = beta_buf[gOff + t];
    sBe[t] = Bw0;
  }
  {
    const float4* src = (const float4*)(Kn + ((size_t)(b * HK_ + hk) * S_ + s0) * DK_);
    #pragma unroll
    for (int u = 0; u < 8; u++) {
      int idx = u * 256 + t;
      sK4[swf4(idx >> 5, idx & 31)] = src[idx];
    }
  }
  __syncthreads();

  const float4* qsrc = (const float4*)(Qn + ((size_t)(b * HK_ + hk) * S_ + s0) * DK_);
  {
    int ti2 = t >> 4, tj = t & 15;
    for (int h = 0; h < 2; h++) {
      #pragma unroll
      for (int u = 0; u < 4; u++) {
        int idx = u * 256 + t;
        sX4[swf4(idx >> 5, idx & 31)] = qsrc[h * 1024 + idx];
      }
      __syncthreads();
      float accM[2][4];
      #pragma unroll
      for (int a = 0; a < 2; a++)
        #pragma unroll
        for (int e = 0; e < 4; e++) accM[a][e] = 0.f;
      for (int k4 = 0; k4 < 32; k4++) {
        float4 qv[2], kv[4];
        qv[0] = sX4[swf4(ti2, k4)];
        qv[1] = sX4[swf4(ti2 + 16, k4)];
        #pragma unroll
        for (int e = 0; e < 4; e++) kv[e] = sK4[swf4(tj + 16 * e, k4)];
        #pragma unroll
        for (int a = 0; a < 2; a++)
          #pragma unroll
          for (int e = 0; e < 4; e++)
            accM[a][e] += qv[a].x * kv[e].x + qv[a].y * kv[e].y +
                          qv[a].z * kv[e].z + qv[a].w * kv[e].w;
      }
      #pragma unroll
      for (int a = 0; a < 2; a++) {
        int iG = h * 32 + ti2 + 16 * a;
        float Gi = sG[iG];
        #pragma unroll
        for (int e = 0; e < 4; e++) {
          int j = tj + 16 * e;
          float m = (j <= iG) ? __expf(Gi - sG[j]) * accM[a][e] : 0.f;
          M_buf[(size_t)ch * 4096 + iG * 64 + j] = m;
        }
      }
      __syncthreads();
    }
  }

  {
    int ti = t >> 4, tj = t & 15;
    float accA[4][4];
    #pragma unroll
    for (int a = 0; a < 4; a++)
      #pragma unroll
      for (int e = 0; e < 4; e++) accA[a][e] = 0.f;
    for (int k4 = 0; k4 < 32; k4++) {
      float4 ki[4], kj[4];
      #pragma unroll
      for (int e = 0; e < 4; e++) {
        ki[e] = sK4[swf4(ti + 16 * e, k4)];
        kj[e] = sK4[swf4(tj + 16 * e, k4)];
      }
      #pragma unroll
      for (int a = 0; a < 4; a++)
        #pragma unroll
        for (int e = 0; e < 4; e++)
          accA[a][e] += ki[a].x * kj[e].x + ki[a].y * kj[e].y +
                        ki[a].z * kj[e].z + ki[a].w * kj[e].w;
    }
    float resA[4][4];
    #pragma unroll
    for (int a = 0; a < 4; a++) {
      int i = ti + 16 * a;
      float Gi = sG[i], Bi = sBe[i];
      #pragma unroll
      for (int e = 0; e < 4; e++) {
        int j = tj + 16 * e;
        resA[a][e] = (j < i) ? Bi * __expf(Gi - sG[j]) * accA[a][e] : 0.f;
      }
    }
    __syncthreads();
    #pragma unroll
    for (int a = 0; a < 4; a++)
      #pragma unroll
      for (int e = 0; e < 4; e++)
        sA[(ti + 16 * a) * 64 + (tj + 16 * e)] = resA[a][e];
  }
  __syncthreads();

  if (t < 64) {
    sT[t] = (t == 0) ? 1.f : 0.f;
    for (int i = 1; i < 64; i++) {
      float acc = 0.f;
      for (int j = 0; j < i; j++) acc += sA[i * 64 + j] * sT[j * 64 + t];
      sT[i * 64 + t] = ((t == i) ? 1.f : 0.f) - acc;
    }
    float w = Bw0 * __expf(Gw0);
    for (int j = 0; j < 64; j++) {
      float wj = __shfl(w, j);
      tTw[j * 64 + t] = sT[t * 64 + j] * wj;
    }
  }
  __syncthreads();

  {
    int i04 = t >> 4, tk = t & 15;
    float accK[4][8];
    #pragma unroll
    for (int r = 0; r < 4; r++)
      #pragma unroll
      for (int u = 0; u < 8; u++) accK[r][u] = 0.f;
    for (int j = 0; j < 64; j++) {
      float4 tw = ((float4*)tTw)[j * 16 + i04];
      #pragma unroll
      for (int u = 0; u < 8; u++) {
        float kv = sK[swf1(j, tk + 16 * u)];
        accK[0][u] += tw.x * kv; accK[1][u] += tw.y * kv;
        accK[2][u] += tw.z * kv; accK[3][u] += tw.w * kv;
      }
    }
    size_t base = (size_t)ch * NBIG;
    #pragma unroll
    for (int r = 0; r < 4; r++)
      #pragma unroll
      for (int u = 0; u < 8; u++)
        KcD[base + (i04 * 4 + r) * 128 + tk + 16 * u] = accK[r][u];
  }
  __syncthreads();

  if (t < 64) {
    for (int j = 0; j < 64; j++) {
      float bj = __shfl(Bw0, j);
      tTb[j * 64 + t] = sT[t * 64 + j] * bj;
    }
  }
  {
    const float4* src = (const float4*)(Vb + ((size_t)bh * S_ + s0) * DV_);
    #pragma unroll
    for (int u = 0; u < 8; u++) {
      int idx = u * 256 + t;
      sK4[swf4(idx >> 5, idx & 31)] = src[idx];
    }
  }
  __syncthreads();

  {
    int i04 = t >> 4, tv_ = t & 15;
    float accD[4][8];
    #pragma unroll
    for (int r = 0; r < 4; r++)
      #pragma unroll
      for (int u = 0; u < 8; u++) accD[r][u] = 0.f;
    for (int j = 0; j < 64; j++) {
      float4 tb = ((float4*)tTb)[j * 16 + i04];
      #pragma unroll
      for (int u = 0; u < 8; u++) {
        float vv = sK[swf1(j, tv_ + 16 * u)];
        accD[0][u] += tb.x * vv; accD[1][u] += tb.y * vv;
        accD[2][u] += tb.z * vv; accD[3][u] += tb.w * vv;
      }
    }
    size_t base = (size_t)ch * NBIG;
    #pragma unroll
    for (int r = 0; r < 4; r++)
      #pragma unroll
      for (int u = 0; u < 8; u++)
        D0p[base + (i04 * 4 + r) * 128 + tv_ + 16 * u] = accD[r][u];
  }
}

// ---------------------------------------------------------------------------
// phaseb v4: 256 blocks, XCD-swizzled; Kd LDS layout XOR-swizzled.
// ---------------------------------------------------------------------------
__global__ __launch_bounds__(256) void phaseb_kernel(
    const float* __restrict__ rec_state, const float* __restrict__ Qn,
    const float* __restrict__ Kn, const float* __restrict__ G_buf,
    float* __restrict__ KcD, const float* __restrict__ D0p,
    float* __restrict__ Oq_buf, float* __restrict__ final_state)
{
  __shared__ float sS[128 * 32];    // state [k][v]
  __shared__ float sKT[128 * 64];   // Kc^T [k][i]; then Kd (swizzled) [i][k]
  __shared__ float sQT[128 * 64];   // Qb^T [k][i]
  __shared__ float sD[64 * 32];     // D [i][v]

  const int blk = blockIdx.x;       // xcd | vq<<3 | g<<5
  const int bh = (blk & 7) | ((blk >> 5) << 3);
  const int vq = (blk >> 3) & 3;
  const int b = bh >> 5, hv = bh & 31, hk = hv >> 1;
  const int t = threadIdx.x;
  const int vbase = vq * 32;
  const float* gG = G_buf + (size_t)bh * S_;

  #pragma unroll
  for (int u = 0; u < 4; u++) {
    int idx = u * 256 + t;
    int k = idx >> 3;
    int v4 = (idx & 7) * 4;
    *(float4*)(&sS[k * 32 + v4]) =
        *(const float4*)(&rec_state[((size_t)bh * 128 + k) * 128 + vbase + v4]);
  }
  __syncthreads();

  const int si = t & 63, skq = t >> 6;
  const int ti = t >> 3;
  const int tv = t & 7;
  const int tk = t >> 3;

  for (int c = 0; c < NC_; c++) {
    const size_t ch = (size_t)bh * NC_ + c;
    const int s0 = c * CS_;
    const float GC = gG[s0 + 63];
    const float eGC = __expf(GC);

    {
      float eGi = __expf(gG[s0 + si]);
      const float* kcRow = KcD + ch * NBIG + si * 128 + skq * 32;
      const float* qRow  = Qn + ((size_t)(b * HK_ + hk) * S_ + s0 + si) * DK_ + skq * 32;
      #pragma unroll
      for (int u = 0; u < 8; u++) {
        float4 kc = *(const float4*)(kcRow + u * 4);
        float4 qv = *(const float4*)(qRow + u * 4);
        int kk = skq * 32 + u * 4;
        sKT[(kk + 0) * 64 + si] = kc.x; sKT[(kk + 1) * 64 + si] = kc.y;
        sKT[(kk + 2) * 64 + si] = kc.z; sKT[(kk + 3) * 64 + si] = kc.w;
        sQT[(kk + 0) * 64 + si] = qv.x * eGi; sQT[(kk + 1) * 64 + si] = qv.y * eGi;
        sQT[(kk + 2) * 64 + si] = qv.z * eGi; sQT[(kk + 3) * 64 + si] = qv.w * eGi;
      }
    }
    __syncthreads();

    {
      float accD[2][4], accO[2][4];
      #pragma unroll
      for (int r = 0; r < 2; r++) {
        float4 d0 = *(const float4*)(&D0p[ch * NBIG + (size_t)(ti * 2 + r) * 128 + vbase + tv * 4]);
        accD[r][0] = d0.x; accD[r][1] = d0.y; accD[r][2] = d0.z; accD[r][3] = d0.w;
        accO[r][0] = accO[r][1] = accO[r][2] = accO[r][3] = 0.f;
      }
      for (int k = 0; k < 128; k++) {
        float2 kc = *(const float2*)(&sKT[k * 64 + ti * 2]);
        float2 qb = *(const float2*)(&sQT[k * 64 + ti * 2]);
        float4 sv = *(const float4*)(&sS[k * 32 + tv * 4]);
        accD[0][0] -= kc.x * sv.x; accD[0][1] -= kc.x * sv.y;
        accD[0][2] -= kc.x * sv.z; accD[0][3] -= kc.x * sv.w;
        accD[1][0] -= kc.y * sv.x; accD[1][1] -= kc.y * sv.y;
        accD[1][2] -= kc.y * sv.z; accD[1][3] -= kc.y * sv.w;
        accO[0][0] += qb.x * sv.x; accO[0][1] += qb.x * sv.y;
        accO[0][2] += qb.x * sv.z; accO[0][3] += qb.x * sv.w;
        accO[1][0] += qb.y * sv.x; accO[1][1] += qb.y * sv.y;
        accO[1][2] += qb.y * sv.z; accO[1][3] += qb.y * sv.w;
      }
      #pragma unroll
      for (int r = 0; r < 2; r++) {
        int i = ti * 2 + r;
        float4 dv = make_float4(accD[r][0], accD[r][1], accD[r][2], accD[r][3]);
        float4 ov = make_float4(accO[r][0], accO[r][1], accO[r][2], accO[r][3]);
        *(float4*)(&sD[i * 32 + tv * 4]) = dv;
        *(float4*)(&KcD[ch * NBIG + (size_t)i * 128 + vbase + tv * 4]) = dv;
        *(float4*)(&Oq_buf[ch * 8192 + (size_t)i * 128 + vbase + tv * 4]) = ov;
      }
    }
    __syncthreads();

    {
      float sc = __expf(GC - gG[s0 + si]);
      const float* kRow = Kn + ((size_t)(b * HK_ + hk) * S_ + s0 + si) * DK_ + skq * 32;
      #pragma unroll
      for (int u = 0; u < 8; u++) {
        float4 x = *(const float4*)(kRow + u * 4);
        x.x *= sc; x.y *= sc; x.z *= sc; x.w *= sc;
        int kg = skq * 8 + u;
        *(float4*)(&sKT[si * 128 + 4 * (kg ^ (si & 31))]) = x;
      }
    }
    __syncthreads();

    {
      float acc[4][4];
      #pragma unroll
      for (int r = 0; r < 4; r++)
        acc[r][0] = acc[r][1] = acc[r][2] = acc[r][3] = 0.f;
      for (int i = 0; i < 64; i++) {
        float4 d  = *(const float4*)(&sD[i * 32 + tv * 4]);
        float4 ka = *(const float4*)(&sKT[i * 128 + 4 * (tk ^ (i & 31))]);
        acc[0][0] += ka.x * d.x; acc[0][1] += ka.x * d.y;
        acc[0][2] += ka.x * d.z; acc[0][3] += ka.x * d.w;
        acc[1][0] += ka.y * d.x; acc[1][1] += ka.y * d.y;
        acc[1][2] += ka.y * d.z; acc[1][3] += ka.y * d.w;
        acc[2][0] += ka.z * d.x; acc[2][1] += ka.z * d.y;
        acc[2][2] += ka.z * d.z; acc[2][3] += ka.z * d.w;
        acc[3][0] += ka.w * d.x; acc[3][1] += ka.w * d.y;
        acc[3][2] += ka.w * d.z; acc[3][3] += ka.w * d.w;
      }
      #pragma unroll
      for (int r = 0; r < 4; r++) {
        int k = tk * 4 + r;
        float4 s = *(const float4*)(&sS[k * 32 + tv * 4]);
        s.x = s.x * eGC + acc[r][0]; s.y = s.y * eGC + acc[r][1];
        s.z = s.z * eGC + acc[r][2]; s.w = s.w * eGC + acc[r][3];
        *(float4*)(&sS[k * 32 + tv * 4]) = s;
      }
    }
    __syncthreads();
  }

  #pragma unroll
  for (int u = 0; u < 4; u++) {
    int idx = u * 256 + t;
    int k = idx >> 3;
    int v4 = (idx & 7) * 4;
    *(float4*)(&final_state[((size_t)bh * 128 + k) * 128 + vbase + v4]) =
        *(const float4*)(&sS[k * 32 + v4]);
  }
}

// ---------------------------------------------------------------------------
// phasec: O = Oq + M*D, RMS-norm + weight + silu(z) gate -> bf16 zg
// ---------------------------------------------------------------------------
__global__ __launch_bounds__(128) void phasec_kernel(
    const float* __restrict__ KcD, const float* __restrict__ Oq_buf,
    const float* __restrict__ M_buf, const float* __restrict__ norm_weight,
    const float* __restrict__ Cbig, ushort* __restrict__ zg_bf)
{
  __shared__ float sM[4096];
  __shared__ float red[2][2];
  int ch = blockIdx.x;
  int bh = ch / NC_, c = ch % NC_;
  int b = bh >> 5, hv = bh & 31;
  int s0 = c * CS_;
  int v = threadIdx.x;

  float Dr[64];
  #pragma unroll
  for (int j = 0; j < 64; j++) Dr[j] = KcD[(size_t)ch * NBIG + j * 128 + v];
  {
    const float4* src = (const float4*)(M_buf + (size_t)ch * 4096);
    #pragma unroll
    for (int u = 0; u < 8; u++) ((float4*)sM)[u * 128 + v] = src[u * 128 + v];
  }
  __syncthreads();
  float nw = norm_weight[v];

  for (int i = 0; i < 64; i++) {
    float o = Oq_buf[(size_t)ch * 8192 + i * 128 + v];
    const float4* mr = (const float4*)(sM + i * 64);
    #pragma unroll
    for (int j4 = 0; j4 < 16; j4++) {
      float4 m = mr[j4];
      o += m.x * Dr[4 * j4] + m.y * Dr[4 * j4 + 1] +
           m.z * Dr[4 * j4 + 2] + m.w * Dr[4 * j4 + 3];
    }
    float p = o * o;
    #pragma unroll
    for (int off = 32; off > 0; off >>= 1) p += __shfl_xor(p, off);
    if ((v & 63) == 0) red[i & 1][v >> 6] = p;
    __syncthreads();
    float var = (red[i & 1][0] + red[i & 1][1]) * (1.f / 128.f);
    float xn = o * rsqrtf(var + 1e-6f) * nw;
    float zv = Cbig[((size_t)(b * S_ + s0 + i)) * NBIG + 8192 + hv * DV_ + v];
    zg_bf[((size_t)(b * S_ + s0 + i)) * VALDIM_ + hv * DV_ + v] =
        f2bf_rne(xn * (zv / (1.f + __expf(-zv))));
  }
}

// ---------------------------------------------------------------------------
extern "C" void kernel_launch(void* const* d_in, const int* in_sizes, int n_in,
                              void* d_out, int out_size, void* d_ws, size_t ws_size,
                              hipStream_t stream)
{
  const float* hs          = (const float*)d_in[0];
  const float* conv_state  = (const float*)d_in[1];
  const float* rec_state   = (const float*)d_in[2];
  const float* W_qkv       = (const float*)d_in[3];
  const float* W_z         = (const float*)d_in[4];
  const float* W_b         = (const float*)d_in[5];
  const float* W_a         = (const float*)d_in[6];
  const float* conv_w      = (const float*)d_in[7];
  const float* dt_bias     = (const float*)d_in[8];
  const float* A_log       = (const float*)d_in[9];
  const float* norm_weight = (const float*)d_in[10];
  const float* W_out       = (const float*)d_in[11];

  float* out       = (float*)d_out;                      // (B,S,H)
  float* out_conv  = out + (size_t)B_ * S_ * H_;         // (B,C,3)
  float* out_state = out_conv + (size_t)B_ * CC_ * 3;    // (B,HV,DK,DV)

  float* ws = (float*)d_ws;
  float* Cbig = ws;                            // (2048, 12416) = 25,427,968
  float* KcD  = Cbig;
  float* D0p  = Cbig + (size_t)1024 * NBIG;
  float* g_buf    = ws + 25427968;
  float* beta_buf = ws + 25493504;
  float* G_buf    = ws + 25559040;
  float* Qn       = ws + 25624576;
  float* Kn       = ws + 29818880;
  float* Vb       = ws + 34013184;
  float* M_buf    = ws + 42401792;
  float* Oq_buf   = Vb;

  // Wcat_bf: (12544, 2048) ushorts = 12,845,056 float-slots
  ushort* Wcat_bf = (ushort*)(ws + 25427968);
  // hs_bf moved up past the padded Wcat; lives in Vb's dead window, ends at
  // 40,370,176 < M_buf (42,401,792). Total ws usage unchanged (46,596,096 f).
  ushort* hs_bf   = (ushort*)(ws + 38273024);
  ushort* zg_bf   = (ushort*)Qn;
  ushort* Wout_bf = (ushort*)Kn;

  const int M = B_ * S_;  // 2048

  // 0. converts
  f2bf_kernel<<<(M * H_) / 1024, 256, 0, stream>>>(hs, hs_bf, M * H_);
  wcat_kernel<<<(NBIGP * H_) / 1024, 256, 0, stream>>>(W_qkv, W_z, W_b, W_a, Wcat_bf);
  // 1. fused qkv|z|b|a GEMM -> Cbig (256x256 8-phase counted-vmcnt pipeline;
  //    B padded to 12544 rows, C stores guarded at col < 12416)
  gemm256_8ph<<<dim3(M / 256, NBIGP / 256), 512, 0, stream>>>(hs_bf, Wcat_bf, Cbig, NBIG, H_);
  // 2. conv_state_new output
  convstate_kernel<<<(B_ * CC_ * 3 + 255) / 256, 256, 0, stream>>>(Cbig, out_conv);
  // 3. conv+silu+l2norm -> Qn,Kn,Vb ; gates
  prep_qkv<<<dim3(64, S_, B_), 128, 0, stream>>>(Cbig, conv_state, conv_w, Qn, Kn, Vb);
  prep_gb<<<(B_ * HV_ * S_ + 255) / 256, 256, 0, stream>>>(Cbig, A_log, dt_bias, g_buf, beta_buf);
  // 4. per-chunk matrices
  cp_kernel<<<B_ * HV_ * NC_, 256, 0, stream>>>(Qn, Kn, Vb, g_buf, beta_buf,
                                                G_buf, M_buf, KcD, D0p);
  // 5. sequential chunk recurrence
  phaseb_kernel<<<B_ * HV_ * 4, 256, 0, stream>>>(rec_state, Qn, Kn, G_buf,
                                                  KcD, D0p, Oq_buf, out_state);
  // 6. W_out convert + intra-chunk output/RMS/gate -> bf16
  f2bf_kernel<<<(H_ * VALDIM_) / 1024, 256, 0, stream>>>(W_out, Wout_bf, H_ * VALDIM_);
  phasec_kernel<<<B_ * HV_ * NC_, 128, 0, stream>>>(KcD, Oq_buf, M_buf,
                                                    norm_weight, Cbig, zg_bf);
  // 7. output GEMM (128x128: only 64 tiles at 256 width -> keep old kernel)
  gemm_bf16_nt<<<dim3(M / 128, H_ / 128), 256, 0, stream>>>(zg_bf, Wout_bf, out, M, H_, VALDIM_);
}

// Round 2
// 942.238 us; speedup vs baseline: 1.0485x; 1.0113x over previous
//
#include <hip/hip_runtime.h>
#include <cstdint>
#include <cstddef>

#define B_ 2
#define S_ 1024
#define H_ 2048
#define HV_ 32
#define HK_ 16
#define DK_ 128
#define DV_ 128
#define CC_ 8192
#define KEYDIM_ 2048
#define VALDIM_ 4096
#define NC_ 16          // chunks
#define CS_ 64          // chunk size
#define NBIG 12416      // fused GEMM1 N (real, C pitch): 8192 qkv + 4096 z + 32 b + 32 a + 64 pad
#define NBIGP 12544     // padded to 49*256 for the 256-wide GEMM tile (B-matrix rows only)

typedef __attribute__((ext_vector_type(8))) short bf16x8;
typedef __attribute__((ext_vector_type(4))) float f32x4;

__device__ __forceinline__ ushort f2bf_rne(float x) {
  union { float f; uint32_t u; } c; c.f = x;
  uint32_t u = c.u + 0x7FFFu + ((c.u >> 16) & 1u);
  return (ushort)(u >> 16);
}

// async 16B global->LDS (DMA; LDS dest = wave-uniform base + lane*16)
__device__ __forceinline__ void gld16(const void* g, void* l) {
  __builtin_amdgcn_global_load_lds(
      (const __attribute__((address_space(1))) void*)g,
      (__attribute__((address_space(3))) void*)l, 16, 0, 0);
}

// ---------------------------------------------------------------------------
// fp32 -> bf16 convert (n multiple of 1024)
// ---------------------------------------------------------------------------
__global__ void f2bf_kernel(const float* __restrict__ in, ushort* __restrict__ out, int n) {
  int i = (blockIdx.x * 256 + threadIdx.x) * 4;
  if (i >= n) return;
  float4 v = *(const float4*)(in + i);
  ushort4 o;
  o.x = f2bf_rne(v.x); o.y = f2bf_rne(v.y);
  o.z = f2bf_rne(v.z); o.w = f2bf_rne(v.w);
  *(ushort4*)(out + i) = o;
}

// ---------------------------------------------------------------------------
// wcat: build concatenated bf16 weight (NBIGP, H): [W_qkv; W_z; W_b; W_a; 0]
// rows 12352..12543 are zero pad (last 128 rows exist only for tile alignment)
// ---------------------------------------------------------------------------
__global__ void wcat_kernel(const float* __restrict__ Wqkv, const float* __restrict__ Wz,
                            const float* __restrict__ Wb, const float* __restrict__ Wa,
                            ushort* __restrict__ out) {
  int i = (blockIdx.x * 256 + threadIdx.x) * 4;
  if (i >= NBIGP * H_) return;
  int n = i >> 11;           // / H_
  int k = i & (H_ - 1);
  float4 v = make_float4(0.f, 0.f, 0.f, 0.f);
  if (n < 8192)       v = *(const float4*)(Wqkv + (size_t)n * H_ + k);
  else if (n < 12288) v = *(const float4*)(Wz + (size_t)(n - 8192) * H_ + k);
  else if (n < 12320) v = *(const float4*)(Wb + (size_t)(n - 12288) * H_ + k);
  else if (n < 12352) v = *(const float4*)(Wa + (size_t)(n - 12320) * H_ + k);
  ushort4 o;
  o.x = f2bf_rne(v.x); o.y = f2bf_rne(v.y);
  o.z = f2bf_rne(v.z); o.w = f2bf_rne(v.w);
  *(ushort4*)(out + i) = o;
}

// ===========================================================================
// gemm256_8ph v2: bf16 MFMA GEMM (NT), 256x256 tile, BK=64, 8 waves (2Mx4N),
// 128 KiB LDS double-buffer, m201-faithful phase structure:
//   every phase = [ds_read quarter (published ONE PHASE EARLIER, so the read
//   latency hides under the vmcnt+barrier skew) -> vmcnt(4) -> barrier ->
//   stage 1 quarter of a FUTURE tile -> (compiler lgkm) -> setprio(1) ->
//   16 MFMA -> setprio(0) -> barrier].
// Quarter-sets: Q0=A-lo(rgS0), Q1=B-lo(rgS1), Q2=B-hi(rgS2), Q3=A-hi(rgS3).
// Issue map: ph0 stages Q1(t+1), ph1 Q2(t+1), ph2 Q3(t+1), ph3 Q0(t+2) —
//   Q0(t+2) goes into the CURRENT buffer's A-lo region, dead since ph0 and
//   >=3 barriers back. Every wait is vmcnt(4): publishes exactly the quarter
//   consumed next phase, with 3 phases of in-flight slack per load; vmcnt
//   never drains below 4 in the loop.
// Steady-state invariant at ph0 entry: outstanding = [Q2(t),Q3(t),Q0(t+1)]
//   = 6 loads; each VMW(4) drains exactly one quarter (2 loads); each stage
//   re-issues one (back to 6). Epilogue: wrapped dummy stages keep counts
//   uniform; final VMW(0) before the C-store drains them.
// LDS fragment-ordered (1 KiB lane-sequential segments) => 0 bank conflicts.
// C stores guarded at col < Ns (B rows >= Ns are zero pad).
// ===========================================================================
#define MEMF() asm volatile("" ::: "memory")
#define VMW(n) asm volatile("s_waitcnt vmcnt(" #n ")" ::: "memory")
#define BARR() do { __builtin_amdgcn_s_barrier(); MEMF(); } while (0)

#define ST(P, SHM, RG, o, kq) do {                                  \
    gld16((P) + (kq),      &SHM[o][((RG) * 2 + 0) * 512]);          \
    gld16((P) + (kq) + 32, &SHM[o][((RG) * 2 + 1) * 512]);          \
  } while (0)

#define LDA(ah, c) do { _Pragma("unroll")                                            \
    for (int i_ = 0; i_ < 4; i_++) { _Pragma("unroll")                               \
      for (int h_ = 0; h_ < 2; h_++)                                                 \
        aF[i_ * 2 + h_] = *(const bf16x8*)(                                          \
            &sAm[c][((wm * 8 + (ah) * 4 + i_) * 2 + h_) * 512 + lane * 8]); } } while (0)

#define LDB(dst, bh, c) do { _Pragma("unroll")                                       \
    for (int j_ = 0; j_ < 2; j_++) { _Pragma("unroll")                               \
      for (int h_ = 0; h_ < 2; h_++)                                                 \
        dst[j_ * 2 + h_] = *(const bf16x8*)(                                         \
            &sBm[c][((wn * 4 + (bh) * 2 + j_) * 2 + h_) * 512 + lane * 8]); } } while (0)

#define MM(ah, bh, bsrc) do {                                                        \
    __builtin_amdgcn_s_setprio(1);                                                   \
    _Pragma("unroll") for (int h_ = 0; h_ < 2; h_++)                                 \
    _Pragma("unroll") for (int i_ = 0; i_ < 4; i_++)                                 \
    _Pragma("unroll") for (int j_ = 0; j_ < 2; j_++)                                 \
      acc[(ah) * 4 + i_][(bh) * 2 + j_] = __builtin_amdgcn_mfma_f32_16x16x32_bf16(   \
          aF[i_ * 2 + h_], bsrc[j_ * 2 + h_], acc[(ah) * 4 + i_][(bh) * 2 + j_],     \
          0, 0, 0);                                                                  \
    __builtin_amdgcn_s_setprio(0);                                                   \
  } while (0)

__global__ __launch_bounds__(512, 2) void gemm256_8ph(
    const ushort* __restrict__ A, const ushort* __restrict__ B,
    float* __restrict__ C, int Ns, int K)
{
  __shared__ ushort sAm[2][16384];   // 2 bufs x 256 rows x 64 k (fragment-ordered)
  __shared__ ushort sBm[2][16384];

  const int t = threadIdx.x;
  const int wave = t >> 6, lane = t & 63;
  const int wm = wave >> 2, wn = wave & 3;
  const int l15 = lane & 15, l4 = lane >> 4;
  const int mt = blockIdx.x, nt = blockIdx.y;

  // per-wave row-groups (16 rows each) for the 4 stage-sets
  const int rgS0 = (wave & 3) + (wave >> 2) * 8;   // A rows {0-63,128-191}
  const int rgS3 = rgS0 + 4;                       // A rows {64-127,192-255}
  const int rgS1 = (wave & 1) + (wave >> 1) * 4;   // B rows, b-half 0
  const int rgS2 = rgS1 + 2;                       // B rows, b-half 1

  const ushort* aP0 = A + (size_t)(mt * 256 + rgS0 * 16 + l15) * K + l4 * 8;
  const ushort* aP1 = A + (size_t)(mt * 256 + rgS3 * 16 + l15) * K + l4 * 8;
  const ushort* bP0 = B + (size_t)(nt * 256 + rgS1 * 16 + l15) * K + l4 * 8;
  const ushort* bP1 = B + (size_t)(nt * 256 + rgS2 * 16 + l15) * K + l4 * 8;

  f32x4 acc[8][4];
  #pragma unroll
  for (int i = 0; i < 8; i++)
    #pragma unroll
    for (int j = 0; j < 4; j++)
      #pragma unroll
      for (int r = 0; r < 4; r++) acc[i][j][r] = 0.f;

  bf16x8 aF[8], bF0[4], bF1[4];

  // prologue: Q0..Q3 of tile 0 (buf 0), Q0 of tile 1 (buf 1); publish Q0,Q1(0)
  ST(aP0, sAm, rgS0, 0, 0); MEMF();    // Q0(0)
  ST(bP0, sBm, rgS1, 0, 0); MEMF();    // Q1(0)
  ST(bP1, sBm, rgS2, 0, 0); MEMF();    // Q2(0)
  ST(aP1, sAm, rgS3, 0, 0); MEMF();    // Q3(0)
  ST(aP0, sAm, rgS0, 1, 64); MEMF();   // Q0(1)   (K>=128 always here)
  VMW(6); BARR();                      // Q0(0),Q1(0) resident for all waves

  const int NT = K >> 6;
  for (int tt = 0; tt < NT; tt++) {
    const int c = tt & 1, o = c ^ 1;
    const int kq1 = (tt + 1 < NT) ? (tt + 1) << 6 : 0;  // wrap: dummy reload
    const int kq2 = (tt + 2 < NT) ? (tt + 2) << 6 : 0;
    // ---- phase 0: compute (a0,b0) ----
    LDA(0, c); LDB(bF0, 0, c);         // Q0(t),Q1(t): published last iter
    VMW(4); BARR();                    // publish Q2(t)
    ST(bP0, sBm, rgS1, o, kq1); MEMF();// stage Q1(t+1)
    MM(0, 0, bF0);
    BARR();
    // ---- phase 1: compute (a0,b1) ----
    LDB(bF1, 1, c);                    // Q2(t): published ph0
    VMW(4); BARR();                    // publish Q3(t)
    ST(bP1, sBm, rgS2, o, kq1); MEMF();// stage Q2(t+1)
    MM(0, 1, bF1);
    BARR();
    // ---- phase 2: compute (a1,b1) ----
    LDA(1, c);                         // Q3(t): published ph1
    VMW(4); BARR();                    // publish Q0(t+1)
    ST(aP1, sAm, rgS3, o, kq1); MEMF();// stage Q3(t+1)
    MM(1, 1, bF1);
    BARR();
    // ---- phase 3: compute (a1,b0), registers only ----
    VMW(4); BARR();                    // publish Q1(t+1)
    ST(aP0, sAm, rgS0, c, kq2); MEMF();// stage Q0(t+2) into buf c A-lo (dead)
    MM(1, 0, bF0);
    BARR();
  }
  VMW(0);  // drain wrapped dummy stages before epilogue / LDS retire

  #pragma unroll
  for (int mf = 0; mf < 8; mf++) {
    const int row0 = mt * 256 + wm * 128 + mf * 16 + l4 * 4;
    #pragma unroll
    for (int nf = 0; nf < 4; nf++) {
      const int col = nt * 256 + wn * 64 + nf * 16 + l15;
      if (col < Ns) {
        #pragma unroll
        for (int r = 0; r < 4; r++)
          C[(size_t)(row0 + r) * Ns + col] = acc[mf][nf][r];
      }
    }
  }
}

// ---------------------------------------------------------------------------
// Double-buffered stage of one BK=64 tile half-pair (8 gld16 per wave).
// Fragment-ordered segments: h*4096 + seg*512 ushorts; seg = 16 rows.
// (kept for the 128x128 kernel used by GEMM2)
// ---------------------------------------------------------------------------
__device__ __forceinline__ void stage_tile(
    const ushort* aS0, const ushort* aS1, const ushort* bS0, const ushort* bS1,
    ushort* ldsA, ushort* ldsB, int wave, int k0)
{
  #pragma unroll
  for (int h = 0; h < 2; h++) {
    gld16(aS0 + k0 + h * 32, ldsA + h * 4096 + (wave * 2 + 0) * 512);
    gld16(aS1 + k0 + h * 32, ldsA + h * 4096 + (wave * 2 + 1) * 512);
    gld16(bS0 + k0 + h * 32, ldsB + h * 4096 + (wave * 2 + 0) * 512);
    gld16(bS1 + k0 + h * 32, ldsB + h * 4096 + (wave * 2 + 1) * 512);
  }
}

// ---------------------------------------------------------------------------
// bf16 MFMA GEMM (NT): 128x128 tile, BK=64, double-buffered. Used for GEMM2
// (M=2048,N=2048: only 64 tiles at 256 width -> 128 tile keeps CUs busy).
// ---------------------------------------------------------------------------
__global__ __launch_bounds__(256) void gemm_bf16_nt(
    const ushort* __restrict__ A, const ushort* __restrict__ B,
    float* __restrict__ C, int M, int N, int K)
{
  __shared__ ushort sL[2][2][8192];   // [buf][A/B][2 halves x 8 segs x 512]
  int t = threadIdx.x;
  int wave = t >> 6, lane = t & 63;
  int wm = wave >> 1, wn = wave & 1;
  int lrow = lane & 15, quad = lane >> 4;
  int mt = blockIdx.x, nt = blockIdx.y;

  f32x4 acc[4][4];
  #pragma unroll
  for (int i = 0; i < 4; i++)
    #pragma unroll
    for (int j = 0; j < 4; j++)
      #pragma unroll
      for (int r = 0; r < 4; r++) acc[i][j][r] = 0.f;

  const ushort* aS0 = A + (size_t)(mt * 128 + (wave * 2 + 0) * 16 + lrow) * K + quad * 8;
  const ushort* aS1 = A + (size_t)(mt * 128 + (wave * 2 + 1) * 16 + lrow) * K + quad * 8;
  const ushort* bS0 = B + (size_t)(nt * 128 + (wave * 2 + 0) * 16 + lrow) * K + quad * 8;
  const ushort* bS1 = B + (size_t)(nt * 128 + (wave * 2 + 1) * 16 + lrow) * K + quad * 8;

  stage_tile(aS0, aS1, bS0, bS1, &sL[0][0][0], &sL[0][1][0], wave, 0);
  __syncthreads();

  const int NK = K >> 6;
  for (int it = 0; it < NK; it++) {
    if (it + 1 < NK)
      stage_tile(aS0, aS1, bS0, bS1,
                 &sL[(it + 1) & 1][0][0], &sL[(it + 1) & 1][1][0],
                 wave, (it + 1) * 64);
    const ushort* bufA = &sL[it & 1][0][0];
    const ushort* bufB = &sL[it & 1][1][0];
    #pragma unroll
    for (int h = 0; h < 2; h++) {
      bf16x8 af[4], bfr[4];
      #pragma unroll
      for (int i = 0; i < 4; i++)
        af[i] = *(const bf16x8*)(bufA + h * 4096 + (wm * 4 + i) * 512 + lane * 8);
      #pragma unroll
      for (int j = 0; j < 4; j++)
        bfr[j] = *(const bf16x8*)(bufB + h * 4096 + (wn * 4 + j) * 512 + lane * 8);
      #pragma unroll
      for (int i = 0; i < 4; i++)
        #pragma unroll
        for (int j = 0; j < 4; j++)
          acc[i][j] = __builtin_amdgcn_mfma_f32_16x16x32_bf16(af[i], bfr[j], acc[i][j], 0, 0, 0);
    }
    __syncthreads();
  }

  #pragma unroll
  for (int i = 0; i < 4; i++) {
    int m_base = mt * 128 + wm * 64 + i * 16 + quad * 4;
    #pragma unroll
    for (int j = 0; j < 4; j++) {
      int n = nt * 128 + wn * 64 + j * 16 + lrow;
      #pragma unroll
      for (int rr = 0; rr < 4; rr++)
        C[(size_t)(m_base + rr) * N + n] = acc[i][j][rr];
    }
  }
}

// ---------------------------------------------------------------------------
// conv_state_new[b][c][j] = mixed_qkv[b][S-3+j][c]  (from (B,S,NBIG) C-matrix)
// ---------------------------------------------------------------------------
__global__ void convstate_kernel(const float* __restrict__ Cbig,
                                 float* __restrict__ out)
{
  int idx = blockIdx.x * blockDim.x + threadIdx.x;
  if (idx >= B_ * CC_ * 3) return;
  int j = idx % 3;
  int c = (idx / 3) % CC_;
  int b = idx / (3 * CC_);
  out[idx] = Cbig[((size_t)(b * S_ + (S_ - 3 + j))) * NBIG + c];
}

// ---------------------------------------------------------------------------
// prep_qkv: conv(K=4)+silu; l2norm q/k heads. qkv read from C-matrix cols 0..8191
// ---------------------------------------------------------------------------
__global__ __launch_bounds__(128) void prep_qkv(
    const float* __restrict__ Cbig, const float* __restrict__ conv_state,
    const float* __restrict__ conv_w,
    float* __restrict__ Qn, float* __restrict__ Kn, float* __restrict__ Vb)
{
  int group = blockIdx.x, s = blockIdx.y, b = blockIdx.z;
  int t = threadIdx.x;
  int c = group * 128 + t;
  float acc = 0.f;
  #pragma unroll
  for (int kk = 0; kk < 4; kk++) {
    int sp = s - 3 + kk;
    float x = (sp < 0) ? conv_state[((size_t)(b * CC_ + c)) * 3 + (3 + sp)]
                       : Cbig[((size_t)(b * S_ + sp)) * NBIG + c];
    acc += conv_w[c * 4 + kk] * x;
  }
  float val = acc / (1.f + __expf(-acc));   // silu

  if (group < 32) {
    __shared__ float red2[2];
    float p = val * val;
    #pragma unroll
    for (int off = 32; off > 0; off >>= 1) p += __shfl_xor(p, off);
    if ((t & 63) == 0) red2[t >> 6] = p;
    __syncthreads();
    float r = rsqrtf(red2[0] + red2[1] + 1e-6f);
    if (group < 16) {
      r *= 0.08838834764831845f;  // 128^-0.5
      Qn[(((size_t)(b * HK_ + group)) * S_ + s) * DK_ + t] = val * r;
    } else {
      Kn[(((size_t)(b * HK_ + (group - 16))) * S_ + s) * DK_ + t] = val * r;
    }
  } else {
    Vb[(((size_t)(b * HV_ + (group - 32))) * S_ + s) * DV_ + t] = val;
  }
}

// ---------------------------------------------------------------------------
// prep_gb: g/beta from C-matrix cols 12288..12351
// ---------------------------------------------------------------------------
__global__ void prep_gb(const float* __restrict__ Cbig,
                        const float* __restrict__ A_log, const float* __restrict__ dt_bias,
                        float* __restrict__ g_buf, float* __restrict__ beta_buf)
{
  int idx = blockIdx.x * blockDim.x + threadIdx.x;
  if (idx >= B_ * HV_ * S_) return;
  int s = idx & (S_ - 1);
  int hv = (idx >> 10) & 31;
  int b = idx >> 15;
  float bv = Cbig[((size_t)(b * S_ + s)) * NBIG + 12288 + hv];
  float av = Cbig[((size_t)(b * S_ + s)) * NBIG + 12320 + hv];
  float x = av + dt_bias[hv];
  float sp = (x > 20.f) ? x : log1pf(__expf(x));
  g_buf[idx] = -__expf(A_log[hv]) * sp;
  beta_buf[idx] = 1.f / (1.f + __expf(-bv));
}

// ---------------------------------------------------------------------------
// cp_kernel: per (b,hv,chunk). G cumsum, M, A, Tinv, Kc, D0.
// ---------------------------------------------------------------------------
__device__ __forceinline__ int swf4(int r, int f) { return r * 32 + (f ^ (r & 31)); }
__device__ __forceinline__ int swf1(int r, int k) {
  return r * 128 + 4 * ((k >> 2) ^ (r & 31)) + (k & 3);
}

__global__ __launch_bounds__(256) void cp_kernel(
    const float* __restrict__ Qn, const float* __restrict__ Kn,
    const float* __restrict__ Vb,
    const float* __restrict__ g_buf, const float* __restrict__ beta_buf,
    float* __restrict__ G_buf, float* __restrict__ M_buf,
    float* __restrict__ KcD, float* __restrict__ D0p)
{
  __shared__ float sK[64 * 128];
  __shared__ float sX[32 * 128];
  __shared__ float sT[64 * 64];
  float* sG  = sT;
  float* sBe = sT + 64;
  float* sA  = sX;
  float* tTw = sX;
  float* tTb = sX;
  float4* sK4 = (float4*)sK;
  float4* sX4 = (float4*)sX;

  const int ch = blockIdx.x;
  const int bh = ch / NC_, c = ch % NC_;
  const int b = bh >> 5, hv = bh & 31, hk = hv >> 1;
  const int s0 = c * CS_;
  const int t = threadIdx.x;
  const size_t gOff = (size_t)bh * S_ + s0;

  float Gw0 = 0.f, Bw0 = 0.f;
  if (t < 64) {
    float gi = g_buf[gOff + t];
    Gw0 = gi;
    #pragma unroll
    for (int off = 1; off < 64; off <<= 1) {
      float o = __shfl_up(Gw0, off);
      if (t >= off) Gw0 += o;
    }
    G_buf[gOff + t] = Gw0;
    sG[t] = Gw0;
    Bw0 = beta_buf[gOff + t];
    sBe[t] = Bw0;
  }
  {
    const float4* src = (const float4*)(Kn + ((size_t)(b * HK_ + hk) * S_ + s0) * DK_);
    #pragma unroll
    for (int u = 0; u < 8; u++) {
      int idx = u * 256 + t;
      sK4[swf4(idx >> 5, idx & 31)] = src[idx];
    }
  }
  __syncthreads();

  const float4* qsrc = (const float4*)(Qn + ((size_t)(b * HK_ + hk) * S_ + s0) * DK_);
  {
    int ti2 = t >> 4, tj = t & 15;
    for (int h = 0; h < 2; h++) {
      #pragma unroll
      for (int u = 0; u < 4; u++) {
        int idx = u * 256 + t;
        sX4[swf4(idx >> 5, idx & 31)] = qsrc[h * 1024 + idx];
      }
      __syncthreads();
      float accM[2][4];
      #pragma unroll
      for (int a = 0; a < 2; a++)
        #pragma unroll
        for (int e = 0; e < 4; e++) accM[a][e] = 0.f;
      for (int k4 = 0; k4 < 32; k4++) {
        float4 qv[2], kv[4];
        qv[0] = sX4[swf4(ti2, k4)];
        qv[1] = sX4[swf4(ti2 + 16, k4)];
        #pragma unroll
        for (int e = 0; e < 4; e++) kv[e] = sK4[swf4(tj + 16 * e, k4)];
        #pragma unroll
        for (int a = 0; a < 2; a++)
          #pragma unroll
          for (int e = 0; e < 4; e++)
            accM[a][e] += qv[a].x * kv[e].x + qv[a].y * kv[e].y +
                          qv[a].z * kv[e].z + qv[a].w * kv[e].w;
      }
      #pragma unroll
      for (int a = 0; a < 2; a++) {
        int iG = h * 32 + ti2 + 16 * a;
        float Gi = sG[iG];
        #pragma unroll
        for (int e = 0; e < 4; e++) {
          int j = tj + 16 * e;
          float m = (j <= iG) ? __expf(Gi - sG[j]) * accM[a][e] : 0.f;
          M_buf[(size_t)ch * 4096 + iG * 64 + j] = m;
        }
      }
      __syncthreads();
    }
  }

  {
    int ti = t >> 4, tj = t & 15;
    float accA[4][4];
    #pragma unroll
    for (int a = 0; a < 4; a++)
      #pragma unroll
      for (int e = 0; e < 4; e++) accA[a][e] = 0.f;
    for (int k4 = 0; k4 < 32; k4++) {
      float4 ki[4], kj[4];
      #pragma unroll
      for (int e = 0; e < 4; e++) {
        ki[e] = sK4[swf4(ti + 16 * e, k4)];
        kj[e] = sK4[swf4(tj + 16 * e, k4)];
      }
      #pragma unroll
      for (int a = 0; a < 4; a++)
        #pragma unroll
        for (int e = 0; e < 4; e++)
          accA[a][e] += ki[a].x * kj[e].x + ki[a].y * kj[e].y +
                        ki[a].z * kj[e].z + ki[a].w * kj[e].w;
    }
    float resA[4][4];
    #pragma unroll
    for (int a = 0; a < 4; a++) {
      int i = ti + 16 * a;
      float Gi = sG[i], Bi = sBe[i];
      #pragma unroll
      for (int e = 0; e < 4; e++) {
        int j = tj + 16 * e;
        resA[a][e] = (j < i) ? Bi * __expf(Gi - sG[j]) * accA[a][e] : 0.f;
      }
    }
    __syncthreads();
    #pragma unroll
    for (int a = 0; a < 4; a++)
      #pragma unroll
      for (int e = 0; e < 4; e++)
        sA[(ti + 16 * a) * 64 + (tj + 16 * e)] = resA[a][e];
  }
  __syncthreads();

  if (t < 64) {
    sT[t] = (t == 0) ? 1.f : 0.f;
    for (int i = 1; i < 64; i++) {
      float acc = 0.f;
      for (int j = 0; j < i; j++) acc += sA[i * 64 + j] * sT[j * 64 + t];
      sT[i * 64 + t] = ((t == i) ? 1.f : 0.f) - acc;
    }
    float w = Bw0 * __expf(Gw0);
    for (int j = 0; j < 64; j++) {
      float wj = __shfl(w, j);
      tTw[j * 64 + t] = sT[t * 64 + j] * wj;
    }
  }
  __syncthreads();

  {
    int i04 = t >> 4, tk = t & 15;
    float accK[4][8];
    #pragma unroll
    for (int r = 0; r < 4; r++)
      #pragma unroll
      for (int u = 0; u < 8; u++) accK[r][u] = 0.f;
    for (int j = 0; j < 64; j++) {
      float4 tw = ((float4*)tTw)[j * 16 + i04];
      #pragma unroll
      for (int u = 0; u < 8; u++) {
        float kv = sK[swf1(j, tk + 16 * u)];
        accK[0][u] += tw.x * kv; accK[1][u] += tw.y * kv;
        accK[2][u] += tw.z * kv; accK[3][u] += tw.w * kv;
      }
    }
    size_t base = (size_t)ch * NBIG;
    #pragma unroll
    for (int r = 0; r < 4; r++)
      #pragma unroll
      for (int u = 0; u < 8; u++)
        KcD[base + (i04 * 4 + r) * 128 + tk + 16 * u] = accK[r][u];
  }
  __syncthreads();

  if (t < 64) {
    for (int j = 0; j < 64; j++) {
      float bj = __shfl(Bw0, j);
      tTb[j * 64 + t] = sT[t * 64 + j] * bj;
    }
  }
  {
    const float4* src = (const float4*)(Vb + ((size_t)bh * S_ + s0) * DV_);
    #pragma unroll
    for (int u = 0; u < 8; u++) {
      int idx = u * 256 + t;
      sK4[swf4(idx >> 5, idx & 31)] = src[idx];
    }
  }
  __syncthreads();

  {
    int i04 = t >> 4, tv_ = t & 15;
    float accD[4][8];
    #pragma unroll
    for (int r = 0; r < 4; r++)
      #pragma unroll
      for (int u = 0; u < 8; u++) accD[r][u] = 0.f;
    for (int j = 0; j < 64; j++) {
      float4 tb = ((float4*)tTb)[j * 16 + i04];
      #pragma unroll
      for (int u = 0; u < 8; u++) {
        float vv = sK[swf1(j, tv_ + 16 * u)];
        accD[0][u] += tb.x * vv; accD[1][u] += tb.y * vv;
        accD[2][u] += tb.z * vv; accD[3][u] += tb.w * vv;
      }
    }
    size_t base = (size_t)ch * NBIG;
    #pragma unroll
    for (int r = 0; r < 4; r++)
      #pragma unroll
      for (int u = 0; u < 8; u++)
        D0p[base + (i04 * 4 + r) * 128 + tv_ + 16 * u] = accD[r][u];
  }
}

// ---------------------------------------------------------------------------
// phaseb v4: 256 blocks, XCD-swizzled; Kd LDS layout XOR-swizzled.
// ---------------------------------------------------------------------------
__global__ __launch_bounds__(256) void phaseb_kernel(
    const float* __restrict__ rec_state, const float* __restrict__ Qn,
    const float* __restrict__ Kn, const float* __restrict__ G_buf,
    float* __restrict__ KcD, const float* __restrict__ D0p,
    float* __restrict__ Oq_buf, float* __restrict__ final_state)
{
  __shared__ float sS[128 * 32];    // state [k][v]
  __shared__ float sKT[128 * 64];   // Kc^T [k][i]; then Kd (swizzled) [i][k]
  __shared__ float sQT[128 * 64];   // Qb^T [k][i]
  __shared__ float sD[64 * 32];     // D [i][v]

  const int blk = blockIdx.x;       // xcd | vq<<3 | g<<5
  const int bh = (blk & 7) | ((blk >> 5) << 3);
  const int vq = (blk >> 3) & 3;
  const int b = bh >> 5, hv = bh & 31, hk = hv >> 1;
  const int t = threadIdx.x;
  const int vbase = vq * 32;
  const float* gG = G_buf + (size_t)bh * S_;

  #pragma unroll
  for (int u = 0; u < 4; u++) {
    int idx = u * 256 + t;
    int k = idx >> 3;
    int v4 = (idx & 7) * 4;
    *(float4*)(&sS[k * 32 + v4]) =
        *(const float4*)(&rec_state[((size_t)bh * 128 + k) * 128 + vbase + v4]);
  }
  __syncthreads();

  const int si = t & 63, skq = t >> 6;
  const int ti = t >> 3;
  const int tv = t & 7;
  const int tk = t >> 3;

  for (int c = 0; c < NC_; c++) {
    const size_t ch = (size_t)bh * NC_ + c;
    const int s0 = c * CS_;
    const float GC = gG[s0 + 63];
    const float eGC = __expf(GC);

    {
      float eGi = __expf(gG[s0 + si]);
      const float* kcRow = KcD + ch * NBIG + si * 128 + skq * 32;
      const float* qRow  = Qn + ((size_t)(b * HK_ + hk) * S_ + s0 + si) * DK_ + skq * 32;
      #pragma unroll
      for (int u = 0; u < 8; u++) {
        float4 kc = *(const float4*)(kcRow + u * 4);
        float4 qv = *(const float4*)(qRow + u * 4);
        int kk = skq * 32 + u * 4;
        sKT[(kk + 0) * 64 + si] = kc.x; sKT[(kk + 1) * 64 + si] = kc.y;
        sKT[(kk + 2) * 64 + si] = kc.z; sKT[(kk + 3) * 64 + si] = kc.w;
        sQT[(kk + 0) * 64 + si] = qv.x * eGi; sQT[(kk + 1) * 64 + si] = qv.y * eGi;
        sQT[(kk + 2) * 64 + si] = qv.z * eGi; sQT[(kk + 3) * 64 + si] = qv.w * eGi;
      }
    }
    __syncthreads();

    {
      float accD[2][4], accO[2][4];
      #pragma unroll
      for (int r = 0; r < 2; r++) {
        float4 d0 = *(const float4*)(&D0p[ch * NBIG + (size_t)(ti * 2 + r) * 128 + vbase + tv * 4]);
        accD[r][0] = d0.x; accD[r][1] = d0.y; accD[r][2] = d0.z; accD[r][3] = d0.w;
        accO[r][0] = accO[r][1] = accO[r][2] = accO[r][3] = 0.f;
      }
      for (int k = 0; k < 128; k++) {
        float2 kc = *(const float2*)(&sKT[k * 64 + ti * 2]);
        float2 qb = *(const float2*)(&sQT[k * 64 + ti * 2]);
        float4 sv = *(const float4*)(&sS[k * 32 + tv * 4]);
        accD[0][0] -= kc.x * sv.x; accD[0][1] -= kc.x * sv.y;
        accD[0][2] -= kc.x * sv.z; accD[0][3] -= kc.x * sv.w;
        accD[1][0] -= kc.y * sv.x; accD[1][1] -= kc.y * sv.y;
        accD[1][2] -= kc.y * sv.z; accD[1][3] -= kc.y * sv.w;
        accO[0][0] += qb.x * sv.x; accO[0][1] += qb.x * sv.y;
        accO[0][2] += qb.x * sv.z; accO[0][3] += qb.x * sv.w;
        accO[1][0] += qb.y * sv.x; accO[1][1] += qb.y * sv.y;
        accO[1][2] += qb.y * sv.z; accO[1][3] += qb.y * sv.w;
      }
      #pragma unroll
      for (int r = 0; r < 2; r++) {
        int i = ti * 2 + r;
        float4 dv = make_float4(accD[r][0], accD[r][1], accD[r][2], accD[r][3]);
        float4 ov = make_float4(accO[r][0], accO[r][1], accO[r][2], accO[r][3]);
        *(float4*)(&sD[i * 32 + tv * 4]) = dv;
        *(float4*)(&KcD[ch * NBIG + (size_t)i * 128 + vbase + tv * 4]) = dv;
        *(float4*)(&Oq_buf[ch * 8192 + (size_t)i * 128 + vbase + tv * 4]) = ov;
      }
    }
    __syncthreads();

    {
      float sc = __expf(GC - gG[s0 + si]);
      const float* kRow = Kn + ((size_t)(b * HK_ + hk) * S_ + s0 + si) * DK_ + skq * 32;
      #pragma unroll
      for (int u = 0; u < 8; u++) {
        float4 x = *(const float4*)(kRow + u * 4);
        x.x *= sc; x.y *= sc; x.z *= sc; x.w *= sc;
        int kg = skq * 8 + u;
        *(float4*)(&sKT[si * 128 + 4 * (kg ^ (si & 31))]) = x;
      }
    }
    __syncthreads();

    {
      float acc[4][4];
      #pragma unroll
      for (int r = 0; r < 4; r++)
        acc[r][0] = acc[r][1] = acc[r][2] = acc[r][3] = 0.f;
      for (int i = 0; i < 64; i++) {
        float4 d  = *(const float4*)(&sD[i * 32 + tv * 4]);
        float4 ka = *(const float4*)(&sKT[i * 128 + 4 * (tk ^ (i & 31))]);
        acc[0][0] += ka.x * d.x; acc[0][1] += ka.x * d.y;
        acc[0][2] += ka.x * d.z; acc[0][3] += ka.x * d.w;
        acc[1][0] += ka.y * d.x; acc[1][1] += ka.y * d.y;
        acc[1][2] += ka.y * d.z; acc[1][3] += ka.y * d.w;
        acc[2][0] += ka.z * d.x; acc[2][1] += ka.z * d.y;
        acc[2][2] += ka.z * d.z; acc[2][3] += ka.z * d.w;
        acc[3][0] += ka.w * d.x; acc[3][1] += ka.w * d.y;
        acc[3][2] += ka.w * d.z; acc[3][3] += ka.w * d.w;
      }
      #pragma unroll
      for (int r = 0; r < 4; r++) {
        int k = tk * 4 + r;
        float4 s = *(const float4*)(&sS[k * 32 + tv * 4]);
        s.x = s.x * eGC + acc[r][0]; s.y = s.y * eGC + acc[r][1];
        s.z = s.z * eGC + acc[r][2]; s.w = s.w * eGC + acc[r][3];
        *(float4*)(&sS[k * 32 + tv * 4]) = s;
      }
    }
    __syncthreads();
  }

  #pragma unroll
  for (int u = 0; u < 4; u++) {
    int idx = u * 256 + t;
    int k = idx >> 3;
    int v4 = (idx & 7) * 4;
    *(float4*)(&final_state[((size_t)bh * 128 + k) * 128 + vbase + v4]) =
        *(const float4*)(&sS[k * 32 + v4]);
  }
}

// ---------------------------------------------------------------------------
// phasec: O = Oq + M*D, RMS-norm + weight + silu(z) gate -> bf16 zg
// ---------------------------------------------------------------------------
__global__ __launch_bounds__(128) void phasec_kernel(
    const float* __restrict__ KcD, const float* __restrict__ Oq_buf,
    const float* __restrict__ M_buf, const float* __restrict__ norm_weight,
    const float* __restrict__ Cbig, ushort* __restrict__ zg_bf)
{
  __shared__ float sM[4096];
  __shared__ float red[2][2];
  int ch = blockIdx.x;
  int bh = ch / NC_, c = ch % NC_;
  int b = bh >> 5, hv = bh & 31;
  int s0 = c * CS_;
  int v = threadIdx.x;

  float Dr[64];
  #pragma unroll
  for (int j = 0; j < 64; j++) Dr[j] = KcD[(size_t)ch * NBIG + j * 128 + v];
  {
    const float4* src = (const float4*)(M_buf + (size_t)ch * 4096);
    #pragma unroll
    for (int u = 0; u < 8; u++) ((float4*)sM)[u * 128 + v] = src[u * 128 + v];
  }
  __syncthreads();
  float nw = norm_weight[v];

  for (int i = 0; i < 64; i++) {
    float o = Oq_buf[(size_t)ch * 8192 + i * 128 + v];
    const float4* mr = (const float4*)(sM + i * 64);
    #pragma unroll
    for (int j4 = 0; j4 < 16; j4++) {
      float4 m = mr[j4];
      o += m.x * Dr[4 * j4] + m.y * Dr[4 * j4 + 1] +
           m.z * Dr[4 * j4 + 2] + m.w * Dr[4 * j4 + 3];
    }
    float p = o * o;
    #pragma unroll
    for (int off = 32; off > 0; off >>= 1) p += __shfl_xor(p, off);
    if ((v & 63) == 0) red[i & 1][v >> 6] = p;
    __syncthreads();
    float var = (red[i & 1][0] + red[i & 1][1]) * (1.f / 128.f);
    float xn = o * rsqrtf(var + 1e-6f) * nw;
    float zv = Cbig[((size_t)(b * S_ + s0 + i)) * NBIG + 8192 + hv * DV_ + v];
    zg_bf[((size_t)(b * S_ + s0 + i)) * VALDIM_ + hv * DV_ + v] =
        f2bf_rne(xn * (zv / (1.f + __expf(-zv))));
  }
}

// ---------------------------------------------------------------------------
extern "C" void kernel_launch(void* const* d_in, const int* in_sizes, int n_in,
                              void* d_out, int out_size, void* d_ws, size_t ws_size,
                              hipStream_t stream)
{
  const float* hs          = (const float*)d_in[0];
  const float* conv_state  = (const float*)d_in[1];
  const float* rec_state   = (const float*)d_in[2];
  const float* W_qkv       = (const float*)d_in[3];
  const float* W_z         = (const float*)d_in[4];
  const float* W_b         = (const float*)d_in[5];
  const float* W_a         = (const float*)d_in[6];
  const float* conv_w      = (const float*)d_in[7];
  const float* dt_bias     = (const float*)d_in[8];
  const float* A_log       = (const float*)d_in[9];
  const float* norm_weight = (const float*)d_in[10];
  const float* W_out       = (const float*)d_in[11];

  float* out       = (float*)d_out;                      // (B,S,H)
  float* out_conv  = out + (size_t)B_ * S_ * H_;         // (B,C,3)
  float* out_state = out_conv + (size_t)B_ * CC_ * 3;    // (B,HV,DK,DV)

  float* ws = (float*)d_ws;
  float* Cbig = ws;                            // (2048, 12416) = 25,427,968
  float* KcD  = Cbig;
  float* D0p  = Cbig + (size_t)1024 * NBIG;
  float* g_buf    = ws + 25427968;
  float* beta_buf = ws + 25493504;
  float* G_buf    = ws + 25559040;
  float* Qn       = ws + 25624576;
  float* Kn       = ws + 29818880;
  float* Vb       = ws + 34013184;
  float* M_buf    = ws + 42401792;
  float* Oq_buf   = Vb;

  // Wcat_bf: (12544, 2048) ushorts = 12,845,056 float-slots
  ushort* Wcat_bf = (ushort*)(ws + 25427968);
  // hs_bf past the padded Wcat; lives in Vb's dead window, ends at
  // 40,370,176 < M_buf (42,401,792). Total ws usage unchanged (46,596,096 f).
  ushort* hs_bf   = (ushort*)(ws + 38273024);
  ushort* zg_bf   = (ushort*)Qn;
  ushort* Wout_bf = (ushort*)Kn;

  const int M = B_ * S_;  // 2048

  // 0. converts
  f2bf_kernel<<<(M * H_) / 1024, 256, 0, stream>>>(hs, hs_bf, M * H_);
  wcat_kernel<<<(NBIGP * H_) / 1024, 256, 0, stream>>>(W_qkv, W_z, W_b, W_a, Wcat_bf);
  // 1. fused qkv|z|b|a GEMM -> Cbig (256x256, pre-barrier reads + isolated
  //    MFMA clusters + uniform vmcnt(4) quarter pipeline)
  gemm256_8ph<<<dim3(M / 256, NBIGP / 256), 512, 0, stream>>>(hs_bf, Wcat_bf, Cbig, NBIG, H_);
  // 2. conv_state_new output
  convstate_kernel<<<(B_ * CC_ * 3 + 255) / 256, 256, 0, stream>>>(Cbig, out_conv);
  // 3. conv+silu+l2norm -> Qn,Kn,Vb ; gates
  prep_qkv<<<dim3(64, S_, B_), 128, 0, stream>>>(Cbig, conv_state, conv_w, Qn, Kn, Vb);
  prep_gb<<<(B_ * HV_ * S_ + 255) / 256, 256, 0, stream>>>(Cbig, A_log, dt_bias, g_buf, beta_buf);
  // 4. per-chunk matrices
  cp_kernel<<<B_ * HV_ * NC_, 256, 0, stream>>>(Qn, Kn, Vb, g_buf, beta_buf,
                                                G_buf, M_buf, KcD, D0p);
  // 5. sequential chunk recurrence
  phaseb_kernel<<<B_ * HV_ * 4, 256, 0, stream>>>(rec_state, Qn, Kn, G_buf,
                                                  KcD, D0p, Oq_buf, out_state);
  // 6. W_out convert + intra-chunk output/RMS/gate -> bf16
  f2bf_kernel<<<(H_ * VALDIM_) / 1024, 256, 0, stream>>>(W_out, Wout_bf, H_ * VALDIM_);
  phasec_kernel<<<B_ * HV_ * NC_, 128, 0, stream>>>(KcD, Oq_buf, M_buf,
                                                    norm_weight, Cbig, zg_bf);
  // 7. output GEMM (128x128: only 64 tiles at 256 width -> keep old kernel)
  gemm_bf16_nt<<<dim3(M / 128, H_ / 128), 256, 0, stream>>>(zg_bf, Wout_bf, out, M, H_, VALDIM_);
}

// Round 3
// 916.719 us; speedup vs baseline: 1.0777x; 1.0278x over previous
//
#include <hip/hip_runtime.h>
#include <cstdint>
#include <cstddef>

#define B_ 2
#define S_ 1024
#define H_ 2048
#define HV_ 32
#define HK_ 16
#define DK_ 128
#define DV_ 128
#define CC_ 8192
#define KEYDIM_ 2048
#define VALDIM_ 4096
#define NC_ 16          // chunks
#define CS_ 64          // chunk size
#define NBIG 12416      // fused GEMM1 N (real, C pitch): 8192 qkv + 4096 z + 32 b + 32 a + 64 pad
#define NBIGP 12544     // padded to 49*256 for the 256-wide GEMM tile (B-matrix rows only)

typedef __attribute__((ext_vector_type(8))) short bf16x8;
typedef __attribute__((ext_vector_type(4))) float f32x4;

__device__ __forceinline__ ushort f2bf_rne(float x) {
  union { float f; uint32_t u; } c; c.f = x;
  uint32_t u = c.u + 0x7FFFu + ((c.u >> 16) & 1u);
  return (ushort)(u >> 16);
}

// async 16B global->LDS (DMA; LDS dest = wave-uniform base + lane*16)
__device__ __forceinline__ void gld16(const void* g, void* l) {
  __builtin_amdgcn_global_load_lds(
      (const __attribute__((address_space(1))) void*)g,
      (__attribute__((address_space(3))) void*)l, 16, 0, 0);
}

// ---------------------------------------------------------------------------
// fp32 -> bf16 convert (n multiple of 1024)
// ---------------------------------------------------------------------------
__global__ void f2bf_kernel(const float* __restrict__ in, ushort* __restrict__ out, int n) {
  int i = (blockIdx.x * 256 + threadIdx.x) * 4;
  if (i >= n) return;
  float4 v = *(const float4*)(in + i);
  ushort4 o;
  o.x = f2bf_rne(v.x); o.y = f2bf_rne(v.y);
  o.z = f2bf_rne(v.z); o.w = f2bf_rne(v.w);
  *(ushort4*)(out + i) = o;
}

// ---------------------------------------------------------------------------
// wcat: build concatenated bf16 weight (NBIGP, H): [W_qkv; W_z; W_b; W_a; 0]
// rows 12352..12543 are zero pad (last 128 rows exist only for tile alignment)
// ---------------------------------------------------------------------------
__global__ void wcat_kernel(const float* __restrict__ Wqkv, const float* __restrict__ Wz,
                            const float* __restrict__ Wb, const float* __restrict__ Wa,
                            ushort* __restrict__ out) {
  int i = (blockIdx.x * 256 + threadIdx.x) * 4;
  if (i >= NBIGP * H_) return;
  int n = i >> 11;           // / H_
  int k = i & (H_ - 1);
  float4 v = make_float4(0.f, 0.f, 0.f, 0.f);
  if (n < 8192)       v = *(const float4*)(Wqkv + (size_t)n * H_ + k);
  else if (n < 12288) v = *(const float4*)(Wz + (size_t)(n - 8192) * H_ + k);
  else if (n < 12320) v = *(const float4*)(Wb + (size_t)(n - 12288) * H_ + k);
  else if (n < 12352) v = *(const float4*)(Wa + (size_t)(n - 12320) * H_ + k);
  ushort4 o;
  o.x = f2bf_rne(v.x); o.y = f2bf_rne(v.y);
  o.z = f2bf_rne(v.z); o.w = f2bf_rne(v.w);
  *(ushort4*)(out + i) = o;
}

// ===========================================================================
// gemm256_8ph v2: bf16 MFMA GEMM (NT), 256x256 tile, BK=64, 8 waves (2Mx4N),
// 128 KiB LDS double-buffer; pre-barrier ds_reads, isolated MFMA clusters,
// uniform vmcnt(4) quarter pipeline. (unchanged from round 1)
// ===========================================================================
#define MEMF() asm volatile("" ::: "memory")
#define VMW(n) asm volatile("s_waitcnt vmcnt(" #n ")" ::: "memory")
#define BARR() do { __builtin_amdgcn_s_barrier(); MEMF(); } while (0)

#define ST(P, SHM, RG, o, kq) do {                                  \
    gld16((P) + (kq),      &SHM[o][((RG) * 2 + 0) * 512]);          \
    gld16((P) + (kq) + 32, &SHM[o][((RG) * 2 + 1) * 512]);          \
  } while (0)

#define LDA(ah, c) do { _Pragma("unroll")                                            \
    for (int i_ = 0; i_ < 4; i_++) { _Pragma("unroll")                               \
      for (int h_ = 0; h_ < 2; h_++)                                                 \
        aF[i_ * 2 + h_] = *(const bf16x8*)(                                          \
            &sAm[c][((wm * 8 + (ah) * 4 + i_) * 2 + h_) * 512 + lane * 8]); } } while (0)

#define LDB(dst, bh, c) do { _Pragma("unroll")                                       \
    for (int j_ = 0; j_ < 2; j_++) { _Pragma("unroll")                               \
      for (int h_ = 0; h_ < 2; h_++)                                                 \
        dst[j_ * 2 + h_] = *(const bf16x8*)(                                         \
            &sBm[c][((wn * 4 + (bh) * 2 + j_) * 2 + h_) * 512 + lane * 8]); } } while (0)

#define MM(ah, bh, bsrc) do {                                                        \
    __builtin_amdgcn_s_setprio(1);                                                   \
    _Pragma("unroll") for (int h_ = 0; h_ < 2; h_++)                                 \
    _Pragma("unroll") for (int i_ = 0; i_ < 4; i_++)                                 \
    _Pragma("unroll") for (int j_ = 0; j_ < 2; j_++)                                 \
      acc[(ah) * 4 + i_][(bh) * 2 + j_] = __builtin_amdgcn_mfma_f32_16x16x32_bf16(   \
          aF[i_ * 2 + h_], bsrc[j_ * 2 + h_], acc[(ah) * 4 + i_][(bh) * 2 + j_],     \
          0, 0, 0);                                                                  \
    __builtin_amdgcn_s_setprio(0);                                                   \
  } while (0)

__global__ __launch_bounds__(512, 2) void gemm256_8ph(
    const ushort* __restrict__ A, const ushort* __restrict__ B,
    float* __restrict__ C, int Ns, int K)
{
  __shared__ ushort sAm[2][16384];   // 2 bufs x 256 rows x 64 k (fragment-ordered)
  __shared__ ushort sBm[2][16384];

  const int t = threadIdx.x;
  const int wave = t >> 6, lane = t & 63;
  const int wm = wave >> 2, wn = wave & 3;
  const int l15 = lane & 15, l4 = lane >> 4;
  const int mt = blockIdx.x, nt = blockIdx.y;

  // per-wave row-groups (16 rows each) for the 4 stage-sets
  const int rgS0 = (wave & 3) + (wave >> 2) * 8;   // A rows {0-63,128-191}
  const int rgS3 = rgS0 + 4;                       // A rows {64-127,192-255}
  const int rgS1 = (wave & 1) + (wave >> 1) * 4;   // B rows, b-half 0
  const int rgS2 = rgS1 + 2;                       // B rows, b-half 1

  const ushort* aP0 = A + (size_t)(mt * 256 + rgS0 * 16 + l15) * K + l4 * 8;
  const ushort* aP1 = A + (size_t)(mt * 256 + rgS3 * 16 + l15) * K + l4 * 8;
  const ushort* bP0 = B + (size_t)(nt * 256 + rgS1 * 16 + l15) * K + l4 * 8;
  const ushort* bP1 = B + (size_t)(nt * 256 + rgS2 * 16 + l15) * K + l4 * 8;

  f32x4 acc[8][4];
  #pragma unroll
  for (int i = 0; i < 8; i++)
    #pragma unroll
    for (int j = 0; j < 4; j++)
      #pragma unroll
      for (int r = 0; r < 4; r++) acc[i][j][r] = 0.f;

  bf16x8 aF[8], bF0[4], bF1[4];

  // prologue: Q0..Q3 of tile 0 (buf 0), Q0 of tile 1 (buf 1); publish Q0,Q1(0)
  ST(aP0, sAm, rgS0, 0, 0); MEMF();    // Q0(0)
  ST(bP0, sBm, rgS1, 0, 0); MEMF();    // Q1(0)
  ST(bP1, sBm, rgS2, 0, 0); MEMF();    // Q2(0)
  ST(aP1, sAm, rgS3, 0, 0); MEMF();    // Q3(0)
  ST(aP0, sAm, rgS0, 1, 64); MEMF();   // Q0(1)   (K>=128 always here)
  VMW(6); BARR();                      // Q0(0),Q1(0) resident for all waves

  const int NT = K >> 6;
  for (int tt = 0; tt < NT; tt++) {
    const int c = tt & 1, o = c ^ 1;
    const int kq1 = (tt + 1 < NT) ? (tt + 1) << 6 : 0;  // wrap: dummy reload
    const int kq2 = (tt + 2 < NT) ? (tt + 2) << 6 : 0;
    // ---- phase 0: compute (a0,b0) ----
    LDA(0, c); LDB(bF0, 0, c);         // Q0(t),Q1(t): published last iter
    VMW(4); BARR();                    // publish Q2(t)
    ST(bP0, sBm, rgS1, o, kq1); MEMF();// stage Q1(t+1)
    MM(0, 0, bF0);
    BARR();
    // ---- phase 1: compute (a0,b1) ----
    LDB(bF1, 1, c);                    // Q2(t): published ph0
    VMW(4); BARR();                    // publish Q3(t)
    ST(bP1, sBm, rgS2, o, kq1); MEMF();// stage Q2(t+1)
    MM(0, 1, bF1);
    BARR();
    // ---- phase 2: compute (a1,b1) ----
    LDA(1, c);                         // Q3(t): published ph1
    VMW(4); BARR();                    // publish Q0(t+1)
    ST(aP1, sAm, rgS3, o, kq1); MEMF();// stage Q3(t+1)
    MM(1, 1, bF1);
    BARR();
    // ---- phase 3: compute (a1,b0), registers only ----
    VMW(4); BARR();                    // publish Q1(t+1)
    ST(aP0, sAm, rgS0, c, kq2); MEMF();// stage Q0(t+2) into buf c A-lo (dead)
    MM(1, 0, bF0);
    BARR();
  }
  VMW(0);  // drain wrapped dummy stages before epilogue / LDS retire

  #pragma unroll
  for (int mf = 0; mf < 8; mf++) {
    const int row0 = mt * 256 + wm * 128 + mf * 16 + l4 * 4;
    #pragma unroll
    for (int nf = 0; nf < 4; nf++) {
      const int col = nt * 256 + wn * 64 + nf * 16 + l15;
      if (col < Ns) {
        #pragma unroll
        for (int r = 0; r < 4; r++)
          C[(size_t)(row0 + r) * Ns + col] = acc[mf][nf][r];
      }
    }
  }
}

// ---------------------------------------------------------------------------
// Double-buffered stage of one BK=64 tile half-pair (8 gld16 per wave).
// Fragment-ordered segments: h*4096 + seg*512 ushorts; seg = 16 rows.
// (kept for the 128x128 kernel used by GEMM2)
// ---------------------------------------------------------------------------
__device__ __forceinline__ void stage_tile(
    const ushort* aS0, const ushort* aS1, const ushort* bS0, const ushort* bS1,
    ushort* ldsA, ushort* ldsB, int wave, int k0)
{
  #pragma unroll
  for (int h = 0; h < 2; h++) {
    gld16(aS0 + k0 + h * 32, ldsA + h * 4096 + (wave * 2 + 0) * 512);
    gld16(aS1 + k0 + h * 32, ldsA + h * 4096 + (wave * 2 + 1) * 512);
    gld16(bS0 + k0 + h * 32, ldsB + h * 4096 + (wave * 2 + 0) * 512);
    gld16(bS1 + k0 + h * 32, ldsB + h * 4096 + (wave * 2 + 1) * 512);
  }
}

// ---------------------------------------------------------------------------
// bf16 MFMA GEMM (NT): 128x128 tile, BK=64, double-buffered. Used for GEMM2
// (M=2048,N=2048: only 64 tiles at 256 width -> 128 tile keeps CUs busy).
// ---------------------------------------------------------------------------
__global__ __launch_bounds__(256) void gemm_bf16_nt(
    const ushort* __restrict__ A, const ushort* __restrict__ B,
    float* __restrict__ C, int M, int N, int K)
{
  __shared__ ushort sL[2][2][8192];   // [buf][A/B][2 halves x 8 segs x 512]
  int t = threadIdx.x;
  int wave = t >> 6, lane = t & 63;
  int wm = wave >> 1, wn = wave & 1;
  int lrow = lane & 15, quad = lane >> 4;
  int mt = blockIdx.x, nt = blockIdx.y;

  f32x4 acc[4][4];
  #pragma unroll
  for (int i = 0; i < 4; i++)
    #pragma unroll
    for (int j = 0; j < 4; j++)
      #pragma unroll
      for (int r = 0; r < 4; r++) acc[i][j][r] = 0.f;

  const ushort* aS0 = A + (size_t)(mt * 128 + (wave * 2 + 0) * 16 + lrow) * K + quad * 8;
  const ushort* aS1 = A + (size_t)(mt * 128 + (wave * 2 + 1) * 16 + lrow) * K + quad * 8;
  const ushort* bS0 = B + (size_t)(nt * 128 + (wave * 2 + 0) * 16 + lrow) * K + quad * 8;
  const ushort* bS1 = B + (size_t)(nt * 128 + (wave * 2 + 1) * 16 + lrow) * K + quad * 8;

  stage_tile(aS0, aS1, bS0, bS1, &sL[0][0][0], &sL[0][1][0], wave, 0);
  __syncthreads();

  const int NK = K >> 6;
  for (int it = 0; it < NK; it++) {
    if (it + 1 < NK)
      stage_tile(aS0, aS1, bS0, bS1,
                 &sL[(it + 1) & 1][0][0], &sL[(it + 1) & 1][1][0],
                 wave, (it + 1) * 64);
    const ushort* bufA = &sL[it & 1][0][0];
    const ushort* bufB = &sL[it & 1][1][0];
    #pragma unroll
    for (int h = 0; h < 2; h++) {
      bf16x8 af[4], bfr[4];
      #pragma unroll
      for (int i = 0; i < 4; i++)
        af[i] = *(const bf16x8*)(bufA + h * 4096 + (wm * 4 + i) * 512 + lane * 8);
      #pragma unroll
      for (int j = 0; j < 4; j++)
        bfr[j] = *(const bf16x8*)(bufB + h * 4096 + (wn * 4 + j) * 512 + lane * 8);
      #pragma unroll
      for (int i = 0; i < 4; i++)
        #pragma unroll
        for (int j = 0; j < 4; j++)
          acc[i][j] = __builtin_amdgcn_mfma_f32_16x16x32_bf16(af[i], bfr[j], acc[i][j], 0, 0, 0);
    }
    __syncthreads();
  }

  #pragma unroll
  for (int i = 0; i < 4; i++) {
    int m_base = mt * 128 + wm * 64 + i * 16 + quad * 4;
    #pragma unroll
    for (int j = 0; j < 4; j++) {
      int n = nt * 128 + wn * 64 + j * 16 + lrow;
      #pragma unroll
      for (int rr = 0; rr < 4; rr++)
        C[(size_t)(m_base + rr) * N + n] = acc[i][j][rr];
    }
  }
}

// ---------------------------------------------------------------------------
// conv_state_new[b][c][j] = mixed_qkv[b][S-3+j][c]  (from (B,S,NBIG) C-matrix)
// ---------------------------------------------------------------------------
__global__ void convstate_kernel(const float* __restrict__ Cbig,
                                 float* __restrict__ out)
{
  int idx = blockIdx.x * blockDim.x + threadIdx.x;
  if (idx >= B_ * CC_ * 3) return;
  int j = idx % 3;
  int c = (idx / 3) % CC_;
  int b = idx / (3 * CC_);
  out[idx] = Cbig[((size_t)(b * S_ + (S_ - 3 + j))) * NBIG + c];
}

// ---------------------------------------------------------------------------
// prep_qkv: conv(K=4)+silu; l2norm q/k heads. qkv read from C-matrix cols 0..8191
// ---------------------------------------------------------------------------
__global__ __launch_bounds__(128) void prep_qkv(
    const float* __restrict__ Cbig, const float* __restrict__ conv_state,
    const float* __restrict__ conv_w,
    float* __restrict__ Qn, float* __restrict__ Kn, float* __restrict__ Vb)
{
  int group = blockIdx.x, s = blockIdx.y, b = blockIdx.z;
  int t = threadIdx.x;
  int c = group * 128 + t;
  float acc = 0.f;
  #pragma unroll
  for (int kk = 0; kk < 4; kk++) {
    int sp = s - 3 + kk;
    float x = (sp < 0) ? conv_state[((size_t)(b * CC_ + c)) * 3 + (3 + sp)]
                       : Cbig[((size_t)(b * S_ + sp)) * NBIG + c];
    acc += conv_w[c * 4 + kk] * x;
  }
  float val = acc / (1.f + __expf(-acc));   // silu

  if (group < 32) {
    __shared__ float red2[2];
    float p = val * val;
    #pragma unroll
    for (int off = 32; off > 0; off >>= 1) p += __shfl_xor(p, off);
    if ((t & 63) == 0) red2[t >> 6] = p;
    __syncthreads();
    float r = rsqrtf(red2[0] + red2[1] + 1e-6f);
    if (group < 16) {
      r *= 0.08838834764831845f;  // 128^-0.5
      Qn[(((size_t)(b * HK_ + group)) * S_ + s) * DK_ + t] = val * r;
    } else {
      Kn[(((size_t)(b * HK_ + (group - 16))) * S_ + s) * DK_ + t] = val * r;
    }
  } else {
    Vb[(((size_t)(b * HV_ + (group - 32))) * S_ + s) * DV_ + t] = val;
  }
}

// ---------------------------------------------------------------------------
// prep_gb: g/beta from C-matrix cols 12288..12351
// ---------------------------------------------------------------------------
__global__ void prep_gb(const float* __restrict__ Cbig,
                        const float* __restrict__ A_log, const float* __restrict__ dt_bias,
                        float* __restrict__ g_buf, float* __restrict__ beta_buf)
{
  int idx = blockIdx.x * blockDim.x + threadIdx.x;
  if (idx >= B_ * HV_ * S_) return;
  int s = idx & (S_ - 1);
  int hv = (idx >> 10) & 31;
  int b = idx >> 15;
  float bv = Cbig[((size_t)(b * S_ + s)) * NBIG + 12288 + hv];
  float av = Cbig[((size_t)(b * S_ + s)) * NBIG + 12320 + hv];
  float x = av + dt_bias[hv];
  float sp = (x > 20.f) ? x : log1pf(__expf(x));
  g_buf[idx] = -__expf(A_log[hv]) * sp;
  beta_buf[idx] = 1.f / (1.f + __expf(-bv));
}

// ---------------------------------------------------------------------------
// cp_kernel: per (b,hv,chunk). G cumsum, M, A, Tinv, Kc, D0.
// ---------------------------------------------------------------------------
__device__ __forceinline__ int swf4(int r, int f) { return r * 32 + (f ^ (r & 31)); }
__device__ __forceinline__ int swf1(int r, int k) {
  return r * 128 + 4 * ((k >> 2) ^ (r & 31)) + (k & 3);
}

__global__ __launch_bounds__(256) void cp_kernel(
    const float* __restrict__ Qn, const float* __restrict__ Kn,
    const float* __restrict__ Vb,
    const float* __restrict__ g_buf, const float* __restrict__ beta_buf,
    float* __restrict__ G_buf, float* __restrict__ M_buf,
    float* __restrict__ KcD, float* __restrict__ D0p)
{
  __shared__ float sK[64 * 128];
  __shared__ float sX[32 * 128];
  __shared__ float sT[64 * 64];
  float* sG  = sT;
  float* sBe = sT + 64;
  float* sA  = sX;
  float* tTw = sX;
  float* tTb = sX;
  float4* sK4 = (float4*)sK;
  float4* sX4 = (float4*)sX;

  const int ch = blockIdx.x;
  const int bh = ch / NC_, c = ch % NC_;
  const int b = bh >> 5, hv = bh & 31, hk = hv >> 1;
  const int s0 = c * CS_;
  const int t = threadIdx.x;
  const size_t gOff = (size_t)bh * S_ + s0;

  float Gw0 = 0.f, Bw0 = 0.f;
  if (t < 64) {
    float gi = g_buf[gOff + t];
    Gw0 = gi;
    #pragma unroll
    for (int off = 1; off < 64; off <<= 1) {
      float o = __shfl_up(Gw0, off);
      if (t >= off) Gw0 += o;
    }
    G_buf[gOff + t] = Gw0;
    sG[t] = Gw0;
    Bw0 = beta_buf[gOff + t];
    sBe[t] = Bw0;
  }
  {
    const float4* src = (const float4*)(Kn + ((size_t)(b * HK_ + hk) * S_ + s0) * DK_);
    #pragma unroll
    for (int u = 0; u < 8; u++) {
      int idx = u * 256 + t;
      sK4[swf4(idx >> 5, idx & 31)] = src[idx];
    }
  }
  __syncthreads();

  const float4* qsrc = (const float4*)(Qn + ((size_t)(b * HK_ + hk) * S_ + s0) * DK_);
  {
    int ti2 = t >> 4, tj = t & 15;
    for (int h = 0; h < 2; h++) {
      #pragma unroll
      for (int u = 0; u < 4; u++) {
        int idx = u * 256 + t;
        sX4[swf4(idx >> 5, idx & 31)] = qsrc[h * 1024 + idx];
      }
      __syncthreads();
      float accM[2][4];
      #pragma unroll
      for (int a = 0; a < 2; a++)
        #pragma unroll
        for (int e = 0; e < 4; e++) accM[a][e] = 0.f;
      for (int k4 = 0; k4 < 32; k4++) {
        float4 qv[2], kv[4];
        qv[0] = sX4[swf4(ti2, k4)];
        qv[1] = sX4[swf4(ti2 + 16, k4)];
        #pragma unroll
        for (int e = 0; e < 4; e++) kv[e] = sK4[swf4(tj + 16 * e, k4)];
        #pragma unroll
        for (int a = 0; a < 2; a++)
          #pragma unroll
          for (int e = 0; e < 4; e++)
            accM[a][e] += qv[a].x * kv[e].x + qv[a].y * kv[e].y +
                          qv[a].z * kv[e].z + qv[a].w * kv[e].w;
      }
      #pragma unroll
      for (int a = 0; a < 2; a++) {
        int iG = h * 32 + ti2 + 16 * a;
        float Gi = sG[iG];
        #pragma unroll
        for (int e = 0; e < 4; e++) {
          int j = tj + 16 * e;
          float m = (j <= iG) ? __expf(Gi - sG[j]) * accM[a][e] : 0.f;
          M_buf[(size_t)ch * 4096 + iG * 64 + j] = m;
        }
      }
      __syncthreads();
    }
  }

  {
    int ti = t >> 4, tj = t & 15;
    float accA[4][4];
    #pragma unroll
    for (int a = 0; a < 4; a++)
      #pragma unroll
      for (int e = 0; e < 4; e++) accA[a][e] = 0.f;
    for (int k4 = 0; k4 < 32; k4++) {
      float4 ki[4], kj[4];
      #pragma unroll
      for (int e = 0; e < 4; e++) {
        ki[e] = sK4[swf4(ti + 16 * e, k4)];
        kj[e] = sK4[swf4(tj + 16 * e, k4)];
      }
      #pragma unroll
      for (int a = 0; a < 4; a++)
        #pragma unroll
        for (int e = 0; e < 4; e++)
          accA[a][e] += ki[a].x * kj[e].x + ki[a].y * kj[e].y +
                        ki[a].z * kj[e].z + ki[a].w * kj[e].w;
    }
    float resA[4][4];
    #pragma unroll
    for (int a = 0; a < 4; a++) {
      int i = ti + 16 * a;
      float Gi = sG[i], Bi = sBe[i];
      #pragma unroll
      for (int e = 0; e < 4; e++) {
        int j = tj + 16 * e;
        resA[a][e] = (j < i) ? Bi * __expf(Gi - sG[j]) * accA[a][e] : 0.f;
      }
    }
    __syncthreads();
    #pragma unroll
    for (int a = 0; a < 4; a++)
      #pragma unroll
      for (int e = 0; e < 4; e++)
        sA[(ti + 16 * a) * 64 + (tj + 16 * e)] = resA[a][e];
  }
  __syncthreads();

  if (t < 64) {
    sT[t] = (t == 0) ? 1.f : 0.f;
    for (int i = 1; i < 64; i++) {
      float acc = 0.f;
      for (int j = 0; j < i; j++) acc += sA[i * 64 + j] * sT[j * 64 + t];
      sT[i * 64 + t] = ((t == i) ? 1.f : 0.f) - acc;
    }
    float w = Bw0 * __expf(Gw0);
    for (int j = 0; j < 64; j++) {
      float wj = __shfl(w, j);
      tTw[j * 64 + t] = sT[t * 64 + j] * wj;
    }
  }
  __syncthreads();

  {
    int i04 = t >> 4, tk = t & 15;
    float accK[4][8];
    #pragma unroll
    for (int r = 0; r < 4; r++)
      #pragma unroll
      for (int u = 0; u < 8; u++) accK[r][u] = 0.f;
    for (int j = 0; j < 64; j++) {
      float4 tw = ((float4*)tTw)[j * 16 + i04];
      #pragma unroll
      for (int u = 0; u < 8; u++) {
        float kv = sK[swf1(j, tk + 16 * u)];
        accK[0][u] += tw.x * kv; accK[1][u] += tw.y * kv;
        accK[2][u] += tw.z * kv; accK[3][u] += tw.w * kv;
      }
    }
    size_t base = (size_t)ch * NBIG;
    #pragma unroll
    for (int r = 0; r < 4; r++)
      #pragma unroll
      for (int u = 0; u < 8; u++)
        KcD[base + (i04 * 4 + r) * 128 + tk + 16 * u] = accK[r][u];
  }
  __syncthreads();

  if (t < 64) {
    for (int j = 0; j < 64; j++) {
      float bj = __shfl(Bw0, j);
      tTb[j * 64 + t] = sT[t * 64 + j] * bj;
    }
  }
  {
    const float4* src = (const float4*)(Vb + ((size_t)bh * S_ + s0) * DV_);
    #pragma unroll
    for (int u = 0; u < 8; u++) {
      int idx = u * 256 + t;
      sK4[swf4(idx >> 5, idx & 31)] = src[idx];
    }
  }
  __syncthreads();

  {
    int i04 = t >> 4, tv_ = t & 15;
    float accD[4][8];
    #pragma unroll
    for (int r = 0; r < 4; r++)
      #pragma unroll
      for (int u = 0; u < 8; u++) accD[r][u] = 0.f;
    for (int j = 0; j < 64; j++) {
      float4 tb = ((float4*)tTb)[j * 16 + i04];
      #pragma unroll
      for (int u = 0; u < 8; u++) {
        float vv = sK[swf1(j, tv_ + 16 * u)];
        accD[0][u] += tb.x * vv; accD[1][u] += tb.y * vv;
        accD[2][u] += tb.z * vv; accD[3][u] += tb.w * vv;
      }
    }
    size_t base = (size_t)ch * NBIG;
    #pragma unroll
    for (int r = 0; r < 4; r++)
      #pragma unroll
      for (int u = 0; u < 8; u++)
        D0p[base + (i04 * 4 + r) * 128 + tv_ + 16 * u] = accD[r][u];
  }
}

// ---------------------------------------------------------------------------
// phaseb v5: 256 blocks x 512 threads (8 waves = 2/SIMD for latency hiding).
// Phase B k-loop split across two 4-wave groups (k<64 | k>=64) with an LDS
// partial reduction; phase D: 2 k-rows/thread, full i-sum (no reduction).
// ---------------------------------------------------------------------------
__global__ __launch_bounds__(512) void phaseb_kernel(
    const float* __restrict__ rec_state, const float* __restrict__ Qn,
    const float* __restrict__ Kn, const float* __restrict__ G_buf,
    float* __restrict__ KcD, const float* __restrict__ D0p,
    float* __restrict__ Oq_buf, float* __restrict__ final_state)
{
  __shared__ float sS[128 * 32];    // state [k][v]
  __shared__ float sKT[128 * 64];   // Kc^T [k][i]; then Kd (swizzled) [i][k]
  __shared__ float sQT[128 * 64];   // Qb^T [k][i]
  __shared__ float sD[64 * 32];     // D [i][v]
  __shared__ float sR[2][64 * 32];  // k-group-1 partials: [0]=D, [1]=O

  const int blk = blockIdx.x;       // xcd | vq<<3 | g<<5
  const int bh = (blk & 7) | ((blk >> 5) << 3);
  const int vq = (blk >> 3) & 3;
  const int b = bh >> 5, hv = bh & 31, hk = hv >> 1;
  const int t = threadIdx.x;
  const int vbase = vq * 32;
  const float* gG = G_buf + (size_t)bh * S_;

  #pragma unroll
  for (int u = 0; u < 2; u++) {
    int idx = u * 512 + t;
    int k = idx >> 3;
    int v4 = (idx & 7) * 4;
    *(float4*)(&sS[k * 32 + v4]) =
        *(const float4*)(&rec_state[((size_t)bh * 128 + k) * 128 + vbase + v4]);
  }
  __syncthreads();

  const int si = t & 63, skq = t >> 6;   // stage: row si, k-block skq (16 k)
  const int kg = t >> 8;                 // phase-B k-group (wave-uniform)
  const int tt = t & 255;
  const int ti = tt >> 3, tv = t & 7;    // phase-B: 2 i-rows, 4 v
  const int tp = t >> 3;                 // phase-D: k-pair in [0,64)

  for (int c = 0; c < NC_; c++) {
    const size_t ch = (size_t)bh * NC_ + c;
    const int s0 = c * CS_;
    const float GC = gG[s0 + 63];
    const float eGC = __expf(GC);

    // phase A: stage Kc^T [k][i] and Qb^T [k][i] (16 k per thread)
    {
      float eGi = __expf(gG[s0 + si]);
      const float* kcRow = KcD + ch * NBIG + si * 128 + skq * 16;
      const float* qRow  = Qn + ((size_t)(b * HK_ + hk) * S_ + s0 + si) * DK_ + skq * 16;
      #pragma unroll
      for (int u = 0; u < 4; u++) {
        float4 kc = *(const float4*)(kcRow + u * 4);
        float4 qv = *(const float4*)(qRow + u * 4);
        int kk = skq * 16 + u * 4;
        sKT[(kk + 0) * 64 + si] = kc.x; sKT[(kk + 1) * 64 + si] = kc.y;
        sKT[(kk + 2) * 64 + si] = kc.z; sKT[(kk + 3) * 64 + si] = kc.w;
        sQT[(kk + 0) * 64 + si] = qv.x * eGi; sQT[(kk + 1) * 64 + si] = qv.y * eGi;
        sQT[(kk + 2) * 64 + si] = qv.z * eGi; sQT[(kk + 3) * 64 + si] = qv.w * eGi;
      }
    }
    __syncthreads();

    // phase B: D/O partials over k in [kg*64, kg*64+64)
    {
      float accD[2][4], accO[2][4];
      #pragma unroll
      for (int r = 0; r < 2; r++) {
        accO[r][0] = accO[r][1] = accO[r][2] = accO[r][3] = 0.f;
        accD[r][0] = accD[r][1] = accD[r][2] = accD[r][3] = 0.f;
      }
      if (kg == 0) {
        #pragma unroll
        for (int r = 0; r < 2; r++) {
          float4 d0 = *(const float4*)(&D0p[ch * NBIG + (size_t)(ti * 2 + r) * 128 + vbase + tv * 4]);
          accD[r][0] = d0.x; accD[r][1] = d0.y; accD[r][2] = d0.z; accD[r][3] = d0.w;
        }
      }
      const int k0 = kg << 6;
      for (int k = k0; k < k0 + 64; k++) {
        float2 kc = *(const float2*)(&sKT[k * 64 + ti * 2]);
        float2 qb = *(const float2*)(&sQT[k * 64 + ti * 2]);
        float4 sv = *(const float4*)(&sS[k * 32 + tv * 4]);
        accD[0][0] -= kc.x * sv.x; accD[0][1] -= kc.x * sv.y;
        accD[0][2] -= kc.x * sv.z; accD[0][3] -= kc.x * sv.w;
        accD[1][0] -= kc.y * sv.x; accD[1][1] -= kc.y * sv.y;
        accD[1][2] -= kc.y * sv.z; accD[1][3] -= kc.y * sv.w;
        accO[0][0] += qb.x * sv.x; accO[0][1] += qb.x * sv.y;
        accO[0][2] += qb.x * sv.z; accO[0][3] += qb.x * sv.w;
        accO[1][0] += qb.y * sv.x; accO[1][1] += qb.y * sv.y;
        accO[1][2] += qb.y * sv.z; accO[1][3] += qb.y * sv.w;
      }
      if (kg == 1) {
        #pragma unroll
        for (int r = 0; r < 2; r++) {
          int i = ti * 2 + r;
          *(float4*)(&sR[0][i * 32 + tv * 4]) =
              make_float4(accD[r][0], accD[r][1], accD[r][2], accD[r][3]);
          *(float4*)(&sR[1][i * 32 + tv * 4]) =
              make_float4(accO[r][0], accO[r][1], accO[r][2], accO[r][3]);
        }
      }
      __syncthreads();   // sKT/sQT reads done; sR partials visible
      if (kg == 0) {
        #pragma unroll
        for (int r = 0; r < 2; r++) {
          int i = ti * 2 + r;
          float4 pD = *(const float4*)(&sR[0][i * 32 + tv * 4]);
          float4 pO = *(const float4*)(&sR[1][i * 32 + tv * 4]);
          float4 dv = make_float4(accD[r][0] + pD.x, accD[r][1] + pD.y,
                                  accD[r][2] + pD.z, accD[r][3] + pD.w);
          float4 ov = make_float4(accO[r][0] + pO.x, accO[r][1] + pO.y,
                                  accO[r][2] + pO.z, accO[r][3] + pO.w);
          *(float4*)(&sD[i * 32 + tv * 4]) = dv;
          *(float4*)(&KcD[ch * NBIG + (size_t)i * 128 + vbase + tv * 4]) = dv;
          *(float4*)(&Oq_buf[ch * 8192 + (size_t)i * 128 + vbase + tv * 4]) = ov;
        }
      }
    }

    // phase C: stage Kd (scaled, swizzled) into sKT (safe: sKT no longer read)
    {
      float sc = __expf(GC - gG[s0 + si]);
      const float* kRow = Kn + ((size_t)(b * HK_ + hk) * S_ + s0 + si) * DK_ + skq * 16;
      #pragma unroll
      for (int u = 0; u < 4; u++) {
        float4 x = *(const float4*)(kRow + u * 4);
        x.x *= sc; x.y *= sc; x.z *= sc; x.w *= sc;
        int kgr = skq * 4 + u;
        *(float4*)(&sKT[si * 128 + 4 * (kgr ^ (si & 31))]) = x;
      }
    }
    __syncthreads();   // sD final + Kd staged

    // phase D: state update, 2 k-rows per thread, full i-sum
    {
      float acc[2][4];
      acc[0][0] = acc[0][1] = acc[0][2] = acc[0][3] = 0.f;
      acc[1][0] = acc[1][1] = acc[1][2] = acc[1][3] = 0.f;
      const int kgr = tp >> 1, kh = (tp & 1) * 2;
      for (int i = 0; i < 64; i++) {
        float4 d  = *(const float4*)(&sD[i * 32 + tv * 4]);
        float2 ka = *(const float2*)(&sKT[i * 128 + 4 * (kgr ^ (i & 31)) + kh]);
        acc[0][0] += ka.x * d.x; acc[0][1] += ka.x * d.y;
        acc[0][2] += ka.x * d.z; acc[0][3] += ka.x * d.w;
        acc[1][0] += ka.y * d.x; acc[1][1] += ka.y * d.y;
        acc[1][2] += ka.y * d.z; acc[1][3] += ka.y * d.w;
      }
      #pragma unroll
      for (int r = 0; r < 2; r++) {
        int k = tp * 2 + r;
        float4 s = *(const float4*)(&sS[k * 32 + tv * 4]);
        s.x = s.x * eGC + acc[r][0]; s.y = s.y * eGC + acc[r][1];
        s.z = s.z * eGC + acc[r][2]; s.w = s.w * eGC + acc[r][3];
        *(float4*)(&sS[k * 32 + tv * 4]) = s;
      }
    }
    __syncthreads();
  }

  #pragma unroll
  for (int u = 0; u < 2; u++) {
    int idx = u * 512 + t;
    int k = idx >> 3;
    int v4 = (idx & 7) * 4;
    *(float4*)(&final_state[((size_t)bh * 128 + k) * 128 + vbase + v4]) =
        *(const float4*)(&sS[k * 32 + v4]);
  }
}

// ---------------------------------------------------------------------------
// phasec: O = Oq + M*D, RMS-norm + weight + silu(z) gate -> bf16 zg
// ---------------------------------------------------------------------------
__global__ __launch_bounds__(128) void phasec_kernel(
    const float* __restrict__ KcD, const float* __restrict__ Oq_buf,
    const float* __restrict__ M_buf, const float* __restrict__ norm_weight,
    const float* __restrict__ Cbig, ushort* __restrict__ zg_bf)
{
  __shared__ float sM[4096];
  __shared__ float red[2][2];
  int ch = blockIdx.x;
  int bh = ch / NC_, c = ch % NC_;
  int b = bh >> 5, hv = bh & 31;
  int s0 = c * CS_;
  int v = threadIdx.x;

  float Dr[64];
  #pragma unroll
  for (int j = 0; j < 64; j++) Dr[j] = KcD[(size_t)ch * NBIG + j * 128 + v];
  {
    const float4* src = (const float4*)(M_buf + (size_t)ch * 4096);
    #pragma unroll
    for (int u = 0; u < 8; u++) ((float4*)sM)[u * 128 + v] = src[u * 128 + v];
  }
  __syncthreads();
  float nw = norm_weight[v];

  for (int i = 0; i < 64; i++) {
    float o = Oq_buf[(size_t)ch * 8192 + i * 128 + v];
    const float4* mr = (const float4*)(sM + i * 64);
    #pragma unroll
    for (int j4 = 0; j4 < 16; j4++) {
      float4 m = mr[j4];
      o += m.x * Dr[4 * j4] + m.y * Dr[4 * j4 + 1] +
           m.z * Dr[4 * j4 + 2] + m.w * Dr[4 * j4 + 3];
    }
    float p = o * o;
    #pragma unroll
    for (int off = 32; off > 0; off >>= 1) p += __shfl_xor(p, off);
    if ((v & 63) == 0) red[i & 1][v >> 6] = p;
    __syncthreads();
    float var = (red[i & 1][0] + red[i & 1][1]) * (1.f / 128.f);
    float xn = o * rsqrtf(var + 1e-6f) * nw;
    float zv = Cbig[((size_t)(b * S_ + s0 + i)) * NBIG + 8192 + hv * DV_ + v];
    zg_bf[((size_t)(b * S_ + s0 + i)) * VALDIM_ + hv * DV_ + v] =
        f2bf_rne(xn * (zv / (1.f + __expf(-zv))));
  }
}

// ---------------------------------------------------------------------------
extern "C" void kernel_launch(void* const* d_in, const int* in_sizes, int n_in,
                              void* d_out, int out_size, void* d_ws, size_t ws_size,
                              hipStream_t stream)
{
  const float* hs          = (const float*)d_in[0];
  const float* conv_state  = (const float*)d_in[1];
  const float* rec_state   = (const float*)d_in[2];
  const float* W_qkv       = (const float*)d_in[3];
  const float* W_z         = (const float*)d_in[4];
  const float* W_b         = (const float*)d_in[5];
  const float* W_a         = (const float*)d_in[6];
  const float* conv_w      = (const float*)d_in[7];
  const float* dt_bias     = (const float*)d_in[8];
  const float* A_log       = (const float*)d_in[9];
  const float* norm_weight = (const float*)d_in[10];
  const float* W_out       = (const float*)d_in[11];

  float* out       = (float*)d_out;                      // (B,S,H)
  float* out_conv  = out + (size_t)B_ * S_ * H_;         // (B,C,3)
  float* out_state = out_conv + (size_t)B_ * CC_ * 3;    // (B,HV,DK,DV)

  float* ws = (float*)d_ws;
  float* Cbig = ws;                            // (2048, 12416) = 25,427,968
  float* KcD  = Cbig;
  float* D0p  = Cbig + (size_t)1024 * NBIG;
  float* g_buf    = ws + 25427968;
  float* beta_buf = ws + 25493504;
  float* G_buf    = ws + 25559040;
  float* Qn       = ws + 25624576;
  float* Kn       = ws + 29818880;
  float* Vb       = ws + 34013184;
  float* M_buf    = ws + 42401792;
  float* Oq_buf   = Vb;

  // Wcat_bf: (12544, 2048) ushorts = 12,845,056 float-slots
  ushort* Wcat_bf = (ushort*)(ws + 25427968);
  // hs_bf past the padded Wcat; lives in Vb's dead window, ends at
  // 40,370,176 < M_buf (42,401,792). Total ws usage unchanged (46,596,096 f).
  ushort* hs_bf   = (ushort*)(ws + 38273024);
  ushort* zg_bf   = (ushort*)Qn;
  ushort* Wout_bf = (ushort*)Kn;

  const int M = B_ * S_;  // 2048

  // 0. converts
  f2bf_kernel<<<(M * H_) / 1024, 256, 0, stream>>>(hs, hs_bf, M * H_);
  wcat_kernel<<<(NBIGP * H_) / 1024, 256, 0, stream>>>(W_qkv, W_z, W_b, W_a, Wcat_bf);
  // 1. fused qkv|z|b|a GEMM -> Cbig (256x256, pre-barrier reads + isolated
  //    MFMA clusters + uniform vmcnt(4) quarter pipeline)
  gemm256_8ph<<<dim3(M / 256, NBIGP / 256), 512, 0, stream>>>(hs_bf, Wcat_bf, Cbig, NBIG, H_);
  // 2. conv_state_new output
  convstate_kernel<<<(B_ * CC_ * 3 + 255) / 256, 256, 0, stream>>>(Cbig, out_conv);
  // 3. conv+silu+l2norm -> Qn,Kn,Vb ; gates
  prep_qkv<<<dim3(64, S_, B_), 128, 0, stream>>>(Cbig, conv_state, conv_w, Qn, Kn, Vb);
  prep_gb<<<(B_ * HV_ * S_ + 255) / 256, 256, 0, stream>>>(Cbig, A_log, dt_bias, g_buf, beta_buf);
  // 4. per-chunk matrices
  cp_kernel<<<B_ * HV_ * NC_, 256, 0, stream>>>(Qn, Kn, Vb, g_buf, beta_buf,
                                                G_buf, M_buf, KcD, D0p);
  // 5. sequential chunk recurrence (512 thr: 2 waves/SIMD latency hiding)
  phaseb_kernel<<<B_ * HV_ * 4, 512, 0, stream>>>(rec_state, Qn, Kn, G_buf,
                                                  KcD, D0p, Oq_buf, out_state);
  // 6. W_out convert + intra-chunk output/RMS/gate -> bf16
  f2bf_kernel<<<(H_ * VALDIM_) / 1024, 256, 0, stream>>>(W_out, Wout_bf, H_ * VALDIM_);
  phasec_kernel<<<B_ * HV_ * NC_, 128, 0, stream>>>(KcD, Oq_buf, M_buf,
                                                    norm_weight, Cbig, zg_bf);
  // 7. output GEMM (128x128: only 64 tiles at 256 width -> keep old kernel)
  gemm_bf16_nt<<<dim3(M / 128, H_ / 128), 256, 0, stream>>>(zg_bf, Wout_bf, out, M, H_, VALDIM_);
}

// Round 4
// 882.704 us; speedup vs baseline: 1.1192x; 1.0385x over previous
//
#include <hip/hip_runtime.h>
#include <cstdint>
#include <cstddef>

#define B_ 2
#define S_ 1024
#define H_ 2048
#define HV_ 32
#define HK_ 16
#define DK_ 128
#define DV_ 128
#define CC_ 8192
#define KEYDIM_ 2048
#define VALDIM_ 4096
#define NC_ 16          // chunks
#define CS_ 64          // chunk size
#define NBIG 12416      // fused GEMM1 N (real, C pitch): 8192 qkv + 4096 z + 32 b + 32 a + 64 pad
#define NBIGP 12544     // padded to 49*256 for the 256-wide GEMM tile (B-matrix rows only)

typedef __attribute__((ext_vector_type(8))) short bf16x8;
typedef __attribute__((ext_vector_type(4))) float f32x4;

__device__ __forceinline__ ushort f2bf_rne(float x) {
  union { float f; uint32_t u; } c; c.f = x;
  uint32_t u = c.u + 0x7FFFu + ((c.u >> 16) & 1u);
  return (ushort)(u >> 16);
}

// async 16B global->LDS (DMA; LDS dest = wave-uniform base + lane*16)
__device__ __forceinline__ void gld16(const void* g, void* l) {
  __builtin_amdgcn_global_load_lds(
      (const __attribute__((address_space(1))) void*)g,
      (__attribute__((address_space(3))) void*)l, 16, 0, 0);
}

// ---------------------------------------------------------------------------
// fp32 -> bf16 convert (n multiple of 1024)
// ---------------------------------------------------------------------------
__global__ void f2bf_kernel(const float* __restrict__ in, ushort* __restrict__ out, int n) {
  int i = (blockIdx.x * 256 + threadIdx.x) * 4;
  if (i >= n) return;
  float4 v = *(const float4*)(in + i);
  ushort4 o;
  o.x = f2bf_rne(v.x); o.y = f2bf_rne(v.y);
  o.z = f2bf_rne(v.z); o.w = f2bf_rne(v.w);
  *(ushort4*)(out + i) = o;
}

// ---------------------------------------------------------------------------
// wcat: build concatenated bf16 weight (NBIGP, H): [W_qkv; W_z; W_b; W_a; 0]
// rows 12352..12543 are zero pad (last 128 rows exist only for tile alignment)
// ---------------------------------------------------------------------------
__global__ void wcat_kernel(const float* __restrict__ Wqkv, const float* __restrict__ Wz,
                            const float* __restrict__ Wb, const float* __restrict__ Wa,
                            ushort* __restrict__ out) {
  int i = (blockIdx.x * 256 + threadIdx.x) * 4;
  if (i >= NBIGP * H_) return;
  int n = i >> 11;           // / H_
  int k = i & (H_ - 1);
  float4 v = make_float4(0.f, 0.f, 0.f, 0.f);
  if (n < 8192)       v = *(const float4*)(Wqkv + (size_t)n * H_ + k);
  else if (n < 12288) v = *(const float4*)(Wz + (size_t)(n - 8192) * H_ + k);
  else if (n < 12320) v = *(const float4*)(Wb + (size_t)(n - 12288) * H_ + k);
  else if (n < 12352) v = *(const float4*)(Wa + (size_t)(n - 12320) * H_ + k);
  ushort4 o;
  o.x = f2bf_rne(v.x); o.y = f2bf_rne(v.y);
  o.z = f2bf_rne(v.z); o.w = f2bf_rne(v.w);
  *(ushort4*)(out + i) = o;
}

// ===========================================================================
// gemm256_8ph v3: bf16 MFMA GEMM (NT), 256x256 tile, BK=64, 8 waves (2Mx4N),
// 128 KiB LDS double-buffer. K-SPLIT EVEN PHASES (m201 skeleton):
//   2 phases per K-tile, one per k-half h in {0,1}. Every phase:
//     [12 ds_read_b128 (ALL a/b frags of (t,h): 8 A + 4 B — perfectly even)
//      -> 4 gld16 stage of (t+1,h)
//      -> lgkmcnt(8) partial (read tails span the barrier)
//      -> s_barrier -> lgkmcnt(0) -> sched_barrier
//      -> setprio(1) -> 32 MFMA (8i x 4j, all-independent) -> setprio(0)
//      -> vmcnt(4) (publish next phase's half) -> s_barrier]
//   Per-phase resource balance per CU: LDS ~96 reads (~1150 cyc) vs MFMA
//   256 (~1240 cyc) — max() instead of the old 12/4/8/0 read imbalance.
//   4 barriers/K-tile (was 8). vmcnt ledger: steady 8 outstanding at phase
//   entry, VMW(4) drains the oldest half (1-phase ~1300cyc slack > 900cyc
//   HBM latency); never drains below 4 in the loop. Accumulation order
//   across h identical to v2 -> bit-identical C.
// LDS fragment-ordered (1 KiB lane-sequential segments) => 0 bank conflicts.
// C stores guarded at col < Ns (B rows >= Ns are zero pad).
// ===========================================================================
#define MEMF() asm volatile("" ::: "memory")
#define VMW(n) asm volatile("s_waitcnt vmcnt(" #n ")" ::: "memory")
#define LGKM(n) asm volatile("s_waitcnt lgkmcnt(" #n ")" ::: "memory")
#define BARR() do { __builtin_amdgcn_s_barrier(); MEMF(); } while (0)

__global__ __launch_bounds__(512, 2) void gemm256_8ph(
    const ushort* __restrict__ A, const ushort* __restrict__ B,
    float* __restrict__ C, int Ns, int K)
{
  __shared__ ushort sAm[2][16384];   // 2 bufs x 256 rows x 64 k (fragment-ordered)
  __shared__ ushort sBm[2][16384];

  const int t = threadIdx.x;
  const int wave = t >> 6, lane = t & 63;
  const int wm = wave >> 2, wn = wave & 3;
  const int l15 = lane & 15, l4 = lane >> 4;
  const int mt = blockIdx.x, nt = blockIdx.y;

  // per-wave row-groups (16 rows each) for staging
  const int rgS0 = (wave & 3) + (wave >> 2) * 8;   // A rows {0-63,128-191}
  const int rgS3 = rgS0 + 4;                       // A rows {64-127,192-255}
  const int rgS1 = (wave & 1) + (wave >> 1) * 4;   // B rows, b-half 0
  const int rgS2 = rgS1 + 2;                       // B rows, b-half 1

  const ushort* aP0 = A + (size_t)(mt * 256 + rgS0 * 16 + l15) * K + l4 * 8;
  const ushort* aP1 = A + (size_t)(mt * 256 + rgS3 * 16 + l15) * K + l4 * 8;
  const ushort* bP0 = B + (size_t)(nt * 256 + rgS1 * 16 + l15) * K + l4 * 8;
  const ushort* bP1 = B + (size_t)(nt * 256 + rgS2 * 16 + l15) * K + l4 * 8;

  f32x4 acc[8][4];
  #pragma unroll
  for (int i = 0; i < 8; i++)
    #pragma unroll
    for (int j = 0; j < 4; j++)
      #pragma unroll
      for (int r = 0; r < 4; r++) acc[i][j][r] = 0.f;

  bf16x8 aF[8], bF[4];

  // prologue: stage both halves of tile 0 into buf 0; publish h0
  gld16(aP0,      &sAm[0][(rgS0 * 2 + 0) * 512]);
  gld16(aP1,      &sAm[0][(rgS3 * 2 + 0) * 512]);
  gld16(bP0,      &sBm[0][(rgS1 * 2 + 0) * 512]);
  gld16(bP1,      &sBm[0][(rgS2 * 2 + 0) * 512]);
  MEMF();
  gld16(aP0 + 32, &sAm[0][(rgS0 * 2 + 1) * 512]);
  gld16(aP1 + 32, &sAm[0][(rgS3 * 2 + 1) * 512]);
  gld16(bP0 + 32, &sBm[0][(rgS1 * 2 + 1) * 512]);
  gld16(bP1 + 32, &sBm[0][(rgS2 * 2 + 1) * 512]);
  MEMF();
  VMW(4); BARR();                      // (0,h0) resident for all waves

  const int NT = K >> 6;
  for (int tt = 0; tt < NT; tt++) {
    const int c = tt & 1, o = c ^ 1;
    const int kq = (tt + 1 < NT) ? (tt + 1) << 6 : 0;  // wrap: dummy reload
    #pragma unroll
    for (int h = 0; h < 2; h++) {
      // 12 ds_reads: all frags of (tt,h) — even per phase
      #pragma unroll
      for (int i = 0; i < 8; i++)
        aF[i] = *(const bf16x8*)(&sAm[c][((wm * 8 + i) * 2 + h) * 512 + lane * 8]);
      #pragma unroll
      for (int j = 0; j < 4; j++)
        bF[j] = *(const bf16x8*)(&sBm[c][((wn * 4 + j) * 2 + h) * 512 + lane * 8]);
      MEMF();
      // stage (tt+1, h) into buf o (4 gld16)
      gld16(aP0 + kq + h * 32, &sAm[o][(rgS0 * 2 + h) * 512]);
      gld16(aP1 + kq + h * 32, &sAm[o][(rgS3 * 2 + h) * 512]);
      gld16(bP0 + kq + h * 32, &sBm[o][(rgS1 * 2 + h) * 512]);
      gld16(bP1 + kq + h * 32, &sBm[o][(rgS2 * 2 + h) * 512]);
      MEMF();
      LGKM(8);                          // partial: read tails span the barrier
      BARR();
      LGKM(0);
      __builtin_amdgcn_sched_barrier(0);
      __builtin_amdgcn_s_setprio(1);
      #pragma unroll
      for (int i = 0; i < 8; i++)
        #pragma unroll
        for (int j = 0; j < 4; j++)
          acc[i][j] = __builtin_amdgcn_mfma_f32_16x16x32_bf16(aF[i], bF[j], acc[i][j], 0, 0, 0);
      __builtin_amdgcn_s_setprio(0);
      VMW(4);                           // publish next phase's half
      BARR();
    }
  }
  VMW(0);  // drain wrapped dummy stages before epilogue

  #pragma unroll
  for (int mf = 0; mf < 8; mf++) {
    const int row0 = mt * 256 + wm * 128 + mf * 16 + l4 * 4;
    #pragma unroll
    for (int nf = 0; nf < 4; nf++) {
      const int col = nt * 256 + wn * 64 + nf * 16 + l15;
      if (col < Ns) {
        #pragma unroll
        for (int r = 0; r < 4; r++)
          C[(size_t)(row0 + r) * Ns + col] = acc[mf][nf][r];
      }
    }
  }
}

// ---------------------------------------------------------------------------
// Double-buffered stage of one BK=64 tile half-pair (8 gld16 per wave).
// Fragment-ordered segments: h*4096 + seg*512 ushorts; seg = 16 rows.
// (kept for the 128x128 kernel used by GEMM2)
// ---------------------------------------------------------------------------
__device__ __forceinline__ void stage_tile(
    const ushort* aS0, const ushort* aS1, const ushort* bS0, const ushort* bS1,
    ushort* ldsA, ushort* ldsB, int wave, int k0)
{
  #pragma unroll
  for (int h = 0; h < 2; h++) {
    gld16(aS0 + k0 + h * 32, ldsA + h * 4096 + (wave * 2 + 0) * 512);
    gld16(aS1 + k0 + h * 32, ldsA + h * 4096 + (wave * 2 + 1) * 512);
    gld16(bS0 + k0 + h * 32, ldsB + h * 4096 + (wave * 2 + 0) * 512);
    gld16(bS1 + k0 + h * 32, ldsB + h * 4096 + (wave * 2 + 1) * 512);
  }
}

// ---------------------------------------------------------------------------
// bf16 MFMA GEMM (NT): 128x128 tile, BK=64, double-buffered. Used for GEMM2
// (M=2048,N=2048: only 64 tiles at 256 width -> 128 tile keeps CUs busy).
// ---------------------------------------------------------------------------
__global__ __launch_bounds__(256) void gemm_bf16_nt(
    const ushort* __restrict__ A, const ushort* __restrict__ B,
    float* __restrict__ C, int M, int N, int K)
{
  __shared__ ushort sL[2][2][8192];   // [buf][A/B][2 halves x 8 segs x 512]
  int t = threadIdx.x;
  int wave = t >> 6, lane = t & 63;
  int wm = wave >> 1, wn = wave & 1;
  int lrow = lane & 15, quad = lane >> 4;
  int mt = blockIdx.x, nt = blockIdx.y;

  f32x4 acc[4][4];
  #pragma unroll
  for (int i = 0; i < 4; i++)
    #pragma unroll
    for (int j = 0; j < 4; j++)
      #pragma unroll
      for (int r = 0; r < 4; r++) acc[i][j][r] = 0.f;

  const ushort* aS0 = A + (size_t)(mt * 128 + (wave * 2 + 0) * 16 + lrow) * K + quad * 8;
  const ushort* aS1 = A + (size_t)(mt * 128 + (wave * 2 + 1) * 16 + lrow) * K + quad * 8;
  const ushort* bS0 = B + (size_t)(nt * 128 + (wave * 2 + 0) * 16 + lrow) * K + quad * 8;
  const ushort* bS1 = B + (size_t)(nt * 128 + (wave * 2 + 1) * 16 + lrow) * K + quad * 8;

  stage_tile(aS0, aS1, bS0, bS1, &sL[0][0][0], &sL[0][1][0], wave, 0);
  __syncthreads();

  const int NK = K >> 6;
  for (int it = 0; it < NK; it++) {
    if (it + 1 < NK)
      stage_tile(aS0, aS1, bS0, bS1,
                 &sL[(it + 1) & 1][0][0], &sL[(it + 1) & 1][1][0],
                 wave, (it + 1) * 64);
    const ushort* bufA = &sL[it & 1][0][0];
    const ushort* bufB = &sL[it & 1][1][0];
    #pragma unroll
    for (int h = 0; h < 2; h++) {
      bf16x8 af[4], bfr[4];
      #pragma unroll
      for (int i = 0; i < 4; i++)
        af[i] = *(const bf16x8*)(bufA + h * 4096 + (wm * 4 + i) * 512 + lane * 8);
      #pragma unroll
      for (int j = 0; j < 4; j++)
        bfr[j] = *(const bf16x8*)(bufB + h * 4096 + (wn * 4 + j) * 512 + lane * 8);
      #pragma unroll
      for (int i = 0; i < 4; i++)
        #pragma unroll
        for (int j = 0; j < 4; j++)
          acc[i][j] = __builtin_amdgcn_mfma_f32_16x16x32_bf16(af[i], bfr[j], acc[i][j], 0, 0, 0);
    }
    __syncthreads();
  }

  #pragma unroll
  for (int i = 0; i < 4; i++) {
    int m_base = mt * 128 + wm * 64 + i * 16 + quad * 4;
    #pragma unroll
    for (int j = 0; j < 4; j++) {
      int n = nt * 128 + wn * 64 + j * 16 + lrow;
      #pragma unroll
      for (int rr = 0; rr < 4; rr++)
        C[(size_t)(m_base + rr) * N + n] = acc[i][j][rr];
    }
  }
}

// ---------------------------------------------------------------------------
// conv_state_new[b][c][j] = mixed_qkv[b][S-3+j][c]  (from (B,S,NBIG) C-matrix)
// ---------------------------------------------------------------------------
__global__ void convstate_kernel(const float* __restrict__ Cbig,
                                 float* __restrict__ out)
{
  int idx = blockIdx.x * blockDim.x + threadIdx.x;
  if (idx >= B_ * CC_ * 3) return;
  int j = idx % 3;
  int c = (idx / 3) % CC_;
  int b = idx / (3 * CC_);
  out[idx] = Cbig[((size_t)(b * S_ + (S_ - 3 + j))) * NBIG + c];
}

// ---------------------------------------------------------------------------
// prep_qkv: conv(K=4)+silu; l2norm q/k heads. qkv read from C-matrix cols 0..8191
// ---------------------------------------------------------------------------
__global__ __launch_bounds__(128) void prep_qkv(
    const float* __restrict__ Cbig, const float* __restrict__ conv_state,
    const float* __restrict__ conv_w,
    float* __restrict__ Qn, float* __restrict__ Kn, float* __restrict__ Vb)
{
  int group = blockIdx.x, s = blockIdx.y, b = blockIdx.z;
  int t = threadIdx.x;
  int c = group * 128 + t;
  float acc = 0.f;
  #pragma unroll
  for (int kk = 0; kk < 4; kk++) {
    int sp = s - 3 + kk;
    float x = (sp < 0) ? conv_state[((size_t)(b * CC_ + c)) * 3 + (3 + sp)]
                       : Cbig[((size_t)(b * S_ + sp)) * NBIG + c];
    acc += conv_w[c * 4 + kk] * x;
  }
  float val = acc / (1.f + __expf(-acc));   // silu

  if (group < 32) {
    __shared__ float red2[2];
    float p = val * val;
    #pragma unroll
    for (int off = 32; off > 0; off >>= 1) p += __shfl_xor(p, off);
    if ((t & 63) == 0) red2[t >> 6] = p;
    __syncthreads();
    float r = rsqrtf(red2[0] + red2[1] + 1e-6f);
    if (group < 16) {
      r *= 0.08838834764831845f;  // 128^-0.5
      Qn[(((size_t)(b * HK_ + group)) * S_ + s) * DK_ + t] = val * r;
    } else {
      Kn[(((size_t)(b * HK_ + (group - 16))) * S_ + s) * DK_ + t] = val * r;
    }
  } else {
    Vb[(((size_t)(b * HV_ + (group - 32))) * S_ + s) * DV_ + t] = val;
  }
}

// ---------------------------------------------------------------------------
// prep_gb: g/beta from C-matrix cols 12288..12351
// ---------------------------------------------------------------------------
__global__ void prep_gb(const float* __restrict__ Cbig,
                        const float* __restrict__ A_log, const float* __restrict__ dt_bias,
                        float* __restrict__ g_buf, float* __restrict__ beta_buf)
{
  int idx = blockIdx.x * blockDim.x + threadIdx.x;
  if (idx >= B_ * HV_ * S_) return;
  int s = idx & (S_ - 1);
  int hv = (idx >> 10) & 31;
  int b = idx >> 15;
  float bv = Cbig[((size_t)(b * S_ + s)) * NBIG + 12288 + hv];
  float av = Cbig[((size_t)(b * S_ + s)) * NBIG + 12320 + hv];
  float x = av + dt_bias[hv];
  float sp = (x > 20.f) ? x : log1pf(__expf(x));
  g_buf[idx] = -__expf(A_log[hv]) * sp;
  beta_buf[idx] = 1.f / (1.f + __expf(-bv));
}

// ---------------------------------------------------------------------------
// cp_kernel: per (b,hv,chunk). G cumsum, M, A, Tinv, Kc, D0.
// ---------------------------------------------------------------------------
__device__ __forceinline__ int swf4(int r, int f) { return r * 32 + (f ^ (r & 31)); }
__device__ __forceinline__ int swf1(int r, int k) {
  return r * 128 + 4 * ((k >> 2) ^ (r & 31)) + (k & 3);
}

__global__ __launch_bounds__(256) void cp_kernel(
    const float* __restrict__ Qn, const float* __restrict__ Kn,
    const float* __restrict__ Vb,
    const float* __restrict__ g_buf, const float* __restrict__ beta_buf,
    float* __restrict__ G_buf, float* __restrict__ M_buf,
    float* __restrict__ KcD, float* __restrict__ D0p)
{
  __shared__ float sK[64 * 128];
  __shared__ float sX[32 * 128];
  __shared__ float sT[64 * 64];
  float* sG  = sT;
  float* sBe = sT + 64;
  float* sA  = sX;
  float* tTw = sX;
  float* tTb = sX;
  float4* sK4 = (float4*)sK;
  float4* sX4 = (float4*)sX;

  const int ch = blockIdx.x;
  const int bh = ch / NC_, c = ch % NC_;
  const int b = bh >> 5, hv = bh & 31, hk = hv >> 1;
  const int s0 = c * CS_;
  const int t = threadIdx.x;
  const size_t gOff = (size_t)bh * S_ + s0;

  float Gw0 = 0.f, Bw0 = 0.f;
  if (t < 64) {
    float gi = g_buf[gOff + t];
    Gw0 = gi;
    #pragma unroll
    for (int off = 1; off < 64; off <<= 1) {
      float o = __shfl_up(Gw0, off);
      if (t >= off) Gw0 += o;
    }
    G_buf[gOff + t] = Gw0;
    sG[t] = Gw0;
    Bw0 = beta_buf[gOff + t];
    sBe[t] = Bw0;
  }
  {
    const float4* src = (const float4*)(Kn + ((size_t)(b * HK_ + hk) * S_ + s0) * DK_);
    #pragma unroll
    for (int u = 0; u < 8; u++) {
      int idx = u * 256 + t;
      sK4[swf4(idx >> 5, idx & 31)] = src[idx];
    }
  }
  __syncthreads();

  const float4* qsrc = (const float4*)(Qn + ((size_t)(b * HK_ + hk) * S_ + s0) * DK_);
  {
    int ti2 = t >> 4, tj = t & 15;
    for (int h = 0; h < 2; h++) {
      #pragma unroll
      for (int u = 0; u < 4; u++) {
        int idx = u * 256 + t;
        sX4[swf4(idx >> 5, idx & 31)] = qsrc[h * 1024 + idx];
      }
      __syncthreads();
      float accM[2][4];
      #pragma unroll
      for (int a = 0; a < 2; a++)
        #pragma unroll
        for (int e = 0; e < 4; e++) accM[a][e] = 0.f;
      for (int k4 = 0; k4 < 32; k4++) {
        float4 qv[2], kv[4];
        qv[0] = sX4[swf4(ti2, k4)];
        qv[1] = sX4[swf4(ti2 + 16, k4)];
        #pragma unroll
        for (int e = 0; e < 4; e++) kv[e] = sK4[swf4(tj + 16 * e, k4)];
        #pragma unroll
        for (int a = 0; a < 2; a++)
          #pragma unroll
          for (int e = 0; e < 4; e++)
            accM[a][e] += qv[a].x * kv[e].x + qv[a].y * kv[e].y +
                          qv[a].z * kv[e].z + qv[a].w * kv[e].w;
      }
      #pragma unroll
      for (int a = 0; a < 2; a++) {
        int iG = h * 32 + ti2 + 16 * a;
        float Gi = sG[iG];
        #pragma unroll
        for (int e = 0; e < 4; e++) {
          int j = tj + 16 * e;
          float m = (j <= iG) ? __expf(Gi - sG[j]) * accM[a][e] : 0.f;
          M_buf[(size_t)ch * 4096 + iG * 64 + j] = m;
        }
      }
      __syncthreads();
    }
  }

  {
    int ti = t >> 4, tj = t & 15;
    float accA[4][4];
    #pragma unroll
    for (int a = 0; a < 4; a++)
      #pragma unroll
      for (int e = 0; e < 4; e++) accA[a][e] = 0.f;
    for (int k4 = 0; k4 < 32; k4++) {
      float4 ki[4], kj[4];
      #pragma unroll
      for (int e = 0; e < 4; e++) {
        ki[e] = sK4[swf4(ti + 16 * e, k4)];
        kj[e] = sK4[swf4(tj + 16 * e, k4)];
      }
      #pragma unroll
      for (int a = 0; a < 4; a++)
        #pragma unroll
        for (int e = 0; e < 4; e++)
          accA[a][e] += ki[a].x * kj[e].x + ki[a].y * kj[e].y +
                        ki[a].z * kj[e].z + ki[a].w * kj[e].w;
    }
    float resA[4][4];
    #pragma unroll
    for (int a = 0; a < 4; a++) {
      int i = ti + 16 * a;
      float Gi = sG[i], Bi = sBe[i];
      #pragma unroll
      for (int e = 0; e < 4; e++) {
        int j = tj + 16 * e;
        resA[a][e] = (j < i) ? Bi * __expf(Gi - sG[j]) * accA[a][e] : 0.f;
      }
    }
    __syncthreads();
    #pragma unroll
    for (int a = 0; a < 4; a++)
      #pragma unroll
      for (int e = 0; e < 4; e++)
        sA[(ti + 16 * a) * 64 + (tj + 16 * e)] = resA[a][e];
  }
  __syncthreads();

  if (t < 64) {
    sT[t] = (t == 0) ? 1.f : 0.f;
    for (int i = 1; i < 64; i++) {
      float acc = 0.f;
      for (int j = 0; j < i; j++) acc += sA[i * 64 + j] * sT[j * 64 + t];
      sT[i * 64 + t] = ((t == i) ? 1.f : 0.f) - acc;
    }
    float w = Bw0 * __expf(Gw0);
    for (int j = 0; j < 64; j++) {
      float wj = __shfl(w, j);
      tTw[j * 64 + t] = sT[t * 64 + j] * wj;
    }
  }
  __syncthreads();

  {
    int i04 = t >> 4, tk = t & 15;
    float accK[4][8];
    #pragma unroll
    for (int r = 0; r < 4; r++)
      #pragma unroll
      for (int u = 0; u < 8; u++) accK[r][u] = 0.f;
    for (int j = 0; j < 64; j++) {
      float4 tw = ((float4*)tTw)[j * 16 + i04];
      #pragma unroll
      for (int u = 0; u < 8; u++) {
        float kv = sK[swf1(j, tk + 16 * u)];
        accK[0][u] += tw.x * kv; accK[1][u] += tw.y * kv;
        accK[2][u] += tw.z * kv; accK[3][u] += tw.w * kv;
      }
    }
    size_t base = (size_t)ch * NBIG;
    #pragma unroll
    for (int r = 0; r < 4; r++)
      #pragma unroll
      for (int u = 0; u < 8; u++)
        KcD[base + (i04 * 4 + r) * 128 + tk + 16 * u] = accK[r][u];
  }
  __syncthreads();

  if (t < 64) {
    for (int j = 0; j < 64; j++) {
      float bj = __shfl(Bw0, j);
      tTb[j * 64 + t] = sT[t * 64 + j] * bj;
    }
  }
  {
    const float4* src = (const float4*)(Vb + ((size_t)bh * S_ + s0) * DV_);
    #pragma unroll
    for (int u = 0; u < 8; u++) {
      int idx = u * 256 + t;
      sK4[swf4(idx >> 5, idx & 31)] = src[idx];
    }
  }
  __syncthreads();

  {
    int i04 = t >> 4, tv_ = t & 15;
    float accD[4][8];
    #pragma unroll
    for (int r = 0; r < 4; r++)
      #pragma unroll
      for (int u = 0; u < 8; u++) accD[r][u] = 0.f;
    for (int j = 0; j < 64; j++) {
      float4 tb = ((float4*)tTb)[j * 16 + i04];
      #pragma unroll
      for (int u = 0; u < 8; u++) {
        float vv = sK[swf1(j, tv_ + 16 * u)];
        accD[0][u] += tb.x * vv; accD[1][u] += tb.y * vv;
        accD[2][u] += tb.z * vv; accD[3][u] += tb.w * vv;
      }
    }
    size_t base = (size_t)ch * NBIG;
    #pragma unroll
    for (int r = 0; r < 4; r++)
      #pragma unroll
      for (int u = 0; u < 8; u++)
        D0p[base + (i04 * 4 + r) * 128 + tv_ + 16 * u] = accD[r][u];
  }
}

// ---------------------------------------------------------------------------
// phaseb v5: 256 blocks x 512 threads (8 waves = 2/SIMD for latency hiding).
// Phase B k-loop split across two 4-wave groups (k<64 | k>=64) with an LDS
// partial reduction; phase D: 2 k-rows/thread, full i-sum (no reduction).
// ---------------------------------------------------------------------------
__global__ __launch_bounds__(512) void phaseb_kernel(
    const float* __restrict__ rec_state, const float* __restrict__ Qn,
    const float* __restrict__ Kn, const float* __restrict__ G_buf,
    float* __restrict__ KcD, const float* __restrict__ D0p,
    float* __restrict__ Oq_buf, float* __restrict__ final_state)
{
  __shared__ float sS[128 * 32];    // state [k][v]
  __shared__ float sKT[128 * 64];   // Kc^T [k][i]; then Kd (swizzled) [i][k]
  __shared__ float sQT[128 * 64];   // Qb^T [k][i]
  __shared__ float sD[64 * 32];     // D [i][v]
  __shared__ float sR[2][64 * 32];  // k-group-1 partials: [0]=D, [1]=O

  const int blk = blockIdx.x;       // xcd | vq<<3 | g<<5
  const int bh = (blk & 7) | ((blk >> 5) << 3);
  const int vq = (blk >> 3) & 3;
  const int b = bh >> 5, hv = bh & 31, hk = hv >> 1;
  const int t = threadIdx.x;
  const int vbase = vq * 32;
  const float* gG = G_buf + (size_t)bh * S_;

  #pragma unroll
  for (int u = 0; u < 2; u++) {
    int idx = u * 512 + t;
    int k = idx >> 3;
    int v4 = (idx & 7) * 4;
    *(float4*)(&sS[k * 32 + v4]) =
        *(const float4*)(&rec_state[((size_t)bh * 128 + k) * 128 + vbase + v4]);
  }
  __syncthreads();

  const int si = t & 63, skq = t >> 6;   // stage: row si, k-block skq (16 k)
  const int kg = t >> 8;                 // phase-B k-group (wave-uniform)
  const int tt = t & 255;
  const int ti = tt >> 3, tv = t & 7;    // phase-B: 2 i-rows, 4 v
  const int tp = t >> 3;                 // phase-D: k-pair in [0,64)

  for (int c = 0; c < NC_; c++) {
    const size_t ch = (size_t)bh * NC_ + c;
    const int s0 = c * CS_;
    const float GC = gG[s0 + 63];
    const float eGC = __expf(GC);

    // phase A: stage Kc^T [k][i] and Qb^T [k][i] (16 k per thread)
    {
      float eGi = __expf(gG[s0 + si]);
      const float* kcRow = KcD + ch * NBIG + si * 128 + skq * 16;
      const float* qRow  = Qn + ((size_t)(b * HK_ + hk) * S_ + s0 + si) * DK_ + skq * 16;
      #pragma unroll
      for (int u = 0; u < 4; u++) {
        float4 kc = *(const float4*)(kcRow + u * 4);
        float4 qv = *(const float4*)(qRow + u * 4);
        int kk = skq * 16 + u * 4;
        sKT[(kk + 0) * 64 + si] = kc.x; sKT[(kk + 1) * 64 + si] = kc.y;
        sKT[(kk + 2) * 64 + si] = kc.z; sKT[(kk + 3) * 64 + si] = kc.w;
        sQT[(kk + 0) * 64 + si] = qv.x * eGi; sQT[(kk + 1) * 64 + si] = qv.y * eGi;
        sQT[(kk + 2) * 64 + si] = qv.z * eGi; sQT[(kk + 3) * 64 + si] = qv.w * eGi;
      }
    }
    __syncthreads();

    // phase B: D/O partials over k in [kg*64, kg*64+64)
    {
      float accD[2][4], accO[2][4];
      #pragma unroll
      for (int r = 0; r < 2; r++) {
        accO[r][0] = accO[r][1] = accO[r][2] = accO[r][3] = 0.f;
        accD[r][0] = accD[r][1] = accD[r][2] = accD[r][3] = 0.f;
      }
      if (kg == 0) {
        #pragma unroll
        for (int r = 0; r < 2; r++) {
          float4 d0 = *(const float4*)(&D0p[ch * NBIG + (size_t)(ti * 2 + r) * 128 + vbase + tv * 4]);
          accD[r][0] = d0.x; accD[r][1] = d0.y; accD[r][2] = d0.z; accD[r][3] = d0.w;
        }
      }
      const int k0 = kg << 6;
      for (int k = k0; k < k0 + 64; k++) {
        float2 kc = *(const float2*)(&sKT[k * 64 + ti * 2]);
        float2 qb = *(const float2*)(&sQT[k * 64 + ti * 2]);
        float4 sv = *(const float4*)(&sS[k * 32 + tv * 4]);
        accD[0][0] -= kc.x * sv.x; accD[0][1] -= kc.x * sv.y;
        accD[0][2] -= kc.x * sv.z; accD[0][3] -= kc.x * sv.w;
        accD[1][0] -= kc.y * sv.x; accD[1][1] -= kc.y * sv.y;
        accD[1][2] -= kc.y * sv.z; accD[1][3] -= kc.y * sv.w;
        accO[0][0] += qb.x * sv.x; accO[0][1] += qb.x * sv.y;
        accO[0][2] += qb.x * sv.z; accO[0][3] += qb.x * sv.w;
        accO[1][0] += qb.y * sv.x; accO[1][1] += qb.y * sv.y;
        accO[1][2] += qb.y * sv.z; accO[1][3] += qb.y * sv.w;
      }
      if (kg == 1) {
        #pragma unroll
        for (int r = 0; r < 2; r++) {
          int i = ti * 2 + r;
          *(float4*)(&sR[0][i * 32 + tv * 4]) =
              make_float4(accD[r][0], accD[r][1], accD[r][2], accD[r][3]);
          *(float4*)(&sR[1][i * 32 + tv * 4]) =
              make_float4(accO[r][0], accO[r][1], accO[r][2], accO[r][3]);
        }
      }
      __syncthreads();   // sKT/sQT reads done; sR partials visible
      if (kg == 0) {
        #pragma unroll
        for (int r = 0; r < 2; r++) {
          int i = ti * 2 + r;
          float4 pD = *(const float4*)(&sR[0][i * 32 + tv * 4]);
          float4 pO = *(const float4*)(&sR[1][i * 32 + tv * 4]);
          float4 dv = make_float4(accD[r][0] + pD.x, accD[r][1] + pD.y,
                                  accD[r][2] + pD.z, accD[r][3] + pD.w);
          float4 ov = make_float4(accO[r][0] + pO.x, accO[r][1] + pO.y,
                                  accO[r][2] + pO.z, accO[r][3] + pO.w);
          *(float4*)(&sD[i * 32 + tv * 4]) = dv;
          *(float4*)(&KcD[ch * NBIG + (size_t)i * 128 + vbase + tv * 4]) = dv;
          *(float4*)(&Oq_buf[ch * 8192 + (size_t)i * 128 + vbase + tv * 4]) = ov;
        }
      }
    }

    // phase C: stage Kd (scaled, swizzled) into sKT (safe: sKT no longer read)
    {
      float sc = __expf(GC - gG[s0 + si]);
      const float* kRow = Kn + ((size_t)(b * HK_ + hk) * S_ + s0 + si) * DK_ + skq * 16;
      #pragma unroll
      for (int u = 0; u < 4; u++) {
        float4 x = *(const float4*)(kRow + u * 4);
        x.x *= sc; x.y *= sc; x.z *= sc; x.w *= sc;
        int kgr = skq * 4 + u;
        *(float4*)(&sKT[si * 128 + 4 * (kgr ^ (si & 31))]) = x;
      }
    }
    __syncthreads();   // sD final + Kd staged

    // phase D: state update, 2 k-rows per thread, full i-sum
    {
      float acc[2][4];
      acc[0][0] = acc[0][1] = acc[0][2] = acc[0][3] = 0.f;
      acc[1][0] = acc[1][1] = acc[1][2] = acc[1][3] = 0.f;
      const int kgr = tp >> 1, kh = (tp & 1) * 2;
      for (int i = 0; i < 64; i++) {
        float4 d  = *(const float4*)(&sD[i * 32 + tv * 4]);
        float2 ka = *(const float2*)(&sKT[i * 128 + 4 * (kgr ^ (i & 31)) + kh]);
        acc[0][0] += ka.x * d.x; acc[0][1] += ka.x * d.y;
        acc[0][2] += ka.x * d.z; acc[0][3] += ka.x * d.w;
        acc[1][0] += ka.y * d.x; acc[1][1] += ka.y * d.y;
        acc[1][2] += ka.y * d.z; acc[1][3] += ka.y * d.w;
      }
      #pragma unroll
      for (int r = 0; r < 2; r++) {
        int k = tp * 2 + r;
        float4 s = *(const float4*)(&sS[k * 32 + tv * 4]);
        s.x = s.x * eGC + acc[r][0]; s.y = s.y * eGC + acc[r][1];
        s.z = s.z * eGC + acc[r][2]; s.w = s.w * eGC + acc[r][3];
        *(float4*)(&sS[k * 32 + tv * 4]) = s;
      }
    }
    __syncthreads();
  }

  #pragma unroll
  for (int u = 0; u < 2; u++) {
    int idx = u * 512 + t;
    int k = idx >> 3;
    int v4 = (idx & 7) * 4;
    *(float4*)(&final_state[((size_t)bh * 128 + k) * 128 + vbase + v4]) =
        *(const float4*)(&sS[k * 32 + v4]);
  }
}

// ---------------------------------------------------------------------------
// phasec: O = Oq + M*D, RMS-norm + weight + silu(z) gate -> bf16 zg
// ---------------------------------------------------------------------------
__global__ __launch_bounds__(128) void phasec_kernel(
    const float* __restrict__ KcD, const float* __restrict__ Oq_buf,
    const float* __restrict__ M_buf, const float* __restrict__ norm_weight,
    const float* __restrict__ Cbig, ushort* __restrict__ zg_bf)
{
  __shared__ float sM[4096];
  __shared__ float red[2][2];
  int ch = blockIdx.x;
  int bh = ch / NC_, c = ch % NC_;
  int b = bh >> 5, hv = bh & 31;
  int s0 = c * CS_;
  int v = threadIdx.x;

  float Dr[64];
  #pragma unroll
  for (int j = 0; j < 64; j++) Dr[j] = KcD[(size_t)ch * NBIG + j * 128 + v];
  {
    const float4* src = (const float4*)(M_buf + (size_t)ch * 4096);
    #pragma unroll
    for (int u = 0; u < 8; u++) ((float4*)sM)[u * 128 + v] = src[u * 128 + v];
  }
  __syncthreads();
  float nw = norm_weight[v];

  for (int i = 0; i < 64; i++) {
    float o = Oq_buf[(size_t)ch * 8192 + i * 128 + v];
    const float4* mr = (const float4*)(sM + i * 64);
    #pragma unroll
    for (int j4 = 0; j4 < 16; j4++) {
      float4 m = mr[j4];
      o += m.x * Dr[4 * j4] + m.y * Dr[4 * j4 + 1] +
           m.z * Dr[4 * j4 + 2] + m.w * Dr[4 * j4 + 3];
    }
    float p = o * o;
    #pragma unroll
    for (int off = 32; off > 0; off >>= 1) p += __shfl_xor(p, off);
    if ((v & 63) == 0) red[i & 1][v >> 6] = p;
    __syncthreads();
    float var = (red[i & 1][0] + red[i & 1][1]) * (1.f / 128.f);
    float xn = o * rsqrtf(var + 1e-6f) * nw;
    float zv = Cbig[((size_t)(b * S_ + s0 + i)) * NBIG + 8192 + hv * DV_ + v];
    zg_bf[((size_t)(b * S_ + s0 + i)) * VALDIM_ + hv * DV_ + v] =
        f2bf_rne(xn * (zv / (1.f + __expf(-zv))));
  }
}

// ---------------------------------------------------------------------------
extern "C" void kernel_launch(void* const* d_in, const int* in_sizes, int n_in,
                              void* d_out, int out_size, void* d_ws, size_t ws_size,
                              hipStream_t stream)
{
  const float* hs          = (const float*)d_in[0];
  const float* conv_state  = (const float*)d_in[1];
  const float* rec_state   = (const float*)d_in[2];
  const float* W_qkv       = (const float*)d_in[3];
  const float* W_z         = (const float*)d_in[4];
  const float* W_b         = (const float*)d_in[5];
  const float* W_a         = (const float*)d_in[6];
  const float* conv_w      = (const float*)d_in[7];
  const float* dt_bias     = (const float*)d_in[8];
  const float* A_log       = (const float*)d_in[9];
  const float* norm_weight = (const float*)d_in[10];
  const float* W_out       = (const float*)d_in[11];

  float* out       = (float*)d_out;                      // (B,S,H)
  float* out_conv  = out + (size_t)B_ * S_ * H_;         // (B,C,3)
  float* out_state = out_conv + (size_t)B_ * CC_ * 3;    // (B,HV,DK,DV)

  float* ws = (float*)d_ws;
  float* Cbig = ws;                            // (2048, 12416) = 25,427,968
  float* KcD  = Cbig;
  float* D0p  = Cbig + (size_t)1024 * NBIG;
  float* g_buf    = ws + 25427968;
  float* beta_buf = ws + 25493504;
  float* G_buf    = ws + 25559040;
  float* Qn       = ws + 25624576;
  float* Kn       = ws + 29818880;
  float* Vb       = ws + 34013184;
  float* M_buf    = ws + 42401792;
  float* Oq_buf   = Vb;

  // Wcat_bf: (12544, 2048) ushorts = 12,845,056 float-slots
  ushort* Wcat_bf = (ushort*)(ws + 25427968);
  // hs_bf past the padded Wcat; lives in Vb's dead window, ends at
  // 40,370,176 < M_buf (42,401,792). Total ws usage unchanged (46,596,096 f).
  ushort* hs_bf   = (ushort*)(ws + 38273024);
  ushort* zg_bf   = (ushort*)Qn;
  ushort* Wout_bf = (ushort*)Kn;

  const int M = B_ * S_;  // 2048

  // 0. converts
  f2bf_kernel<<<(M * H_) / 1024, 256, 0, stream>>>(hs, hs_bf, M * H_);
  wcat_kernel<<<(NBIGP * H_) / 1024, 256, 0, stream>>>(W_qkv, W_z, W_b, W_a, Wcat_bf);
  // 1. fused qkv|z|b|a GEMM -> Cbig (256x256, k-split even phases,
  //    counted vmcnt/lgkm pipeline)
  gemm256_8ph<<<dim3(M / 256, NBIGP / 256), 512, 0, stream>>>(hs_bf, Wcat_bf, Cbig, NBIG, H_);
  // 2. conv_state_new output
  convstate_kernel<<<(B_ * CC_ * 3 + 255) / 256, 256, 0, stream>>>(Cbig, out_conv);
  // 3. conv+silu+l2norm -> Qn,Kn,Vb ; gates
  prep_qkv<<<dim3(64, S_, B_), 128, 0, stream>>>(Cbig, conv_state, conv_w, Qn, Kn, Vb);
  prep_gb<<<(B_ * HV_ * S_ + 255) / 256, 256, 0, stream>>>(Cbig, A_log, dt_bias, g_buf, beta_buf);
  // 4. per-chunk matrices
  cp_kernel<<<B_ * HV_ * NC_, 256, 0, stream>>>(Qn, Kn, Vb, g_buf, beta_buf,
                                                G_buf, M_buf, KcD, D0p);
  // 5. sequential chunk recurrence (512 thr: 2 waves/SIMD latency hiding)
  phaseb_kernel<<<B_ * HV_ * 4, 512, 0, stream>>>(rec_state, Qn, Kn, G_buf,
                                                  KcD, D0p, Oq_buf, out_state);
  // 6. W_out convert + intra-chunk output/RMS/gate -> bf16
  f2bf_kernel<<<(H_ * VALDIM_) / 1024, 256, 0, stream>>>(W_out, Wout_bf, H_ * VALDIM_);
  phasec_kernel<<<B_ * HV_ * NC_, 128, 0, stream>>>(KcD, Oq_buf, M_buf,
                                                    norm_weight, Cbig, zg_bf);
  // 7. output GEMM (128x128: only 64 tiles at 256 width -> keep old kernel)
  gemm_bf16_nt<<<dim3(M / 128, H_ / 128), 256, 0, stream>>>(zg_bf, Wout_bf, out, M, H_, VALDIM_);
}

// Round 5
// 863.180 us; speedup vs baseline: 1.1445x; 1.0226x over previous
//
#include <hip/hip_runtime.h>
#include <cstdint>
#include <cstddef>

#define B_ 2
#define S_ 1024
#define H_ 2048
#define HV_ 32
#define HK_ 16
#define DK_ 128
#define DV_ 128
#define CC_ 8192
#define KEYDIM_ 2048
#define VALDIM_ 4096
#define NC_ 16          // chunks
#define CS_ 64          // chunk size
#define NBIG 12416      // fused GEMM1 N (real, C pitch): 8192 qkv + 4096 z + 32 b + 32 a + 64 pad
#define NBIGP 12544     // padded to 49*256 for the 256-wide GEMM tile (B-matrix rows only)

typedef __attribute__((ext_vector_type(8))) short bf16x8;
typedef __attribute__((ext_vector_type(4))) float f32x4;

__device__ __forceinline__ ushort f2bf_rne(float x) {
  union { float f; uint32_t u; } c; c.f = x;
  uint32_t u = c.u + 0x7FFFu + ((c.u >> 16) & 1u);
  return (ushort)(u >> 16);
}

// async 16B global->LDS (DMA; LDS dest = wave-uniform base + lane*16)
__device__ __forceinline__ void gld16(const void* g, void* l) {
  __builtin_amdgcn_global_load_lds(
      (const __attribute__((address_space(1))) void*)g,
      (__attribute__((address_space(3))) void*)l, 16, 0, 0);
}

// ---------------------------------------------------------------------------
// fp32 -> bf16 convert (n multiple of 1024)
// ---------------------------------------------------------------------------
__global__ void f2bf_kernel(const float* __restrict__ in, ushort* __restrict__ out, int n) {
  int i = (blockIdx.x * 256 + threadIdx.x) * 4;
  if (i >= n) return;
  float4 v = *(const float4*)(in + i);
  ushort4 o;
  o.x = f2bf_rne(v.x); o.y = f2bf_rne(v.y);
  o.z = f2bf_rne(v.z); o.w = f2bf_rne(v.w);
  *(ushort4*)(out + i) = o;
}

// ---------------------------------------------------------------------------
// wcat: build concatenated bf16 weight (NBIGP, H): [W_qkv; W_z; W_b; W_a; 0]
// rows 12352..12543 are zero pad (last 128 rows exist only for tile alignment)
// ---------------------------------------------------------------------------
__global__ void wcat_kernel(const float* __restrict__ Wqkv, const float* __restrict__ Wz,
                            const float* __restrict__ Wb, const float* __restrict__ Wa,
                            ushort* __restrict__ out) {
  int i = (blockIdx.x * 256 + threadIdx.x) * 4;
  if (i >= NBIGP * H_) return;
  int n = i >> 11;           // / H_
  int k = i & (H_ - 1);
  float4 v = make_float4(0.f, 0.f, 0.f, 0.f);
  if (n < 8192)       v = *(const float4*)(Wqkv + (size_t)n * H_ + k);
  else if (n < 12288) v = *(const float4*)(Wz + (size_t)(n - 8192) * H_ + k);
  else if (n < 12320) v = *(const float4*)(Wb + (size_t)(n - 12288) * H_ + k);
  else if (n < 12352) v = *(const float4*)(Wa + (size_t)(n - 12320) * H_ + k);
  ushort4 o;
  o.x = f2bf_rne(v.x); o.y = f2bf_rne(v.y);
  o.z = f2bf_rne(v.z); o.w = f2bf_rne(v.w);
  *(ushort4*)(out + i) = o;
}

// ===========================================================================
// gemm256_8ph v3: bf16 MFMA GEMM (NT), 256x256 tile, BK=64, 8 waves (2Mx4N),
// 128 KiB LDS double-buffer, k-split even phases. (unchanged from round 3)
// ===========================================================================
#define MEMF() asm volatile("" ::: "memory")
#define VMW(n) asm volatile("s_waitcnt vmcnt(" #n ")" ::: "memory")
#define LGKM(n) asm volatile("s_waitcnt lgkmcnt(" #n ")" ::: "memory")
#define BARR() do { __builtin_amdgcn_s_barrier(); MEMF(); } while (0)

__global__ __launch_bounds__(512, 2) void gemm256_8ph(
    const ushort* __restrict__ A, const ushort* __restrict__ B,
    float* __restrict__ C, int Ns, int K)
{
  __shared__ ushort sAm[2][16384];   // 2 bufs x 256 rows x 64 k (fragment-ordered)
  __shared__ ushort sBm[2][16384];

  const int t = threadIdx.x;
  const int wave = t >> 6, lane = t & 63;
  const int wm = wave >> 2, wn = wave & 3;
  const int l15 = lane & 15, l4 = lane >> 4;
  const int mt = blockIdx.x, nt = blockIdx.y;

  // per-wave row-groups (16 rows each) for staging
  const int rgS0 = (wave & 3) + (wave >> 2) * 8;   // A rows {0-63,128-191}
  const int rgS3 = rgS0 + 4;                       // A rows {64-127,192-255}
  const int rgS1 = (wave & 1) + (wave >> 1) * 4;   // B rows, b-half 0
  const int rgS2 = rgS1 + 2;                       // B rows, b-half 1

  const ushort* aP0 = A + (size_t)(mt * 256 + rgS0 * 16 + l15) * K + l4 * 8;
  const ushort* aP1 = A + (size_t)(mt * 256 + rgS3 * 16 + l15) * K + l4 * 8;
  const ushort* bP0 = B + (size_t)(nt * 256 + rgS1 * 16 + l15) * K + l4 * 8;
  const ushort* bP1 = B + (size_t)(nt * 256 + rgS2 * 16 + l15) * K + l4 * 8;

  f32x4 acc[8][4];
  #pragma unroll
  for (int i = 0; i < 8; i++)
    #pragma unroll
    for (int j = 0; j < 4; j++)
      #pragma unroll
      for (int r = 0; r < 4; r++) acc[i][j][r] = 0.f;

  bf16x8 aF[8], bF[4];

  // prologue: stage both halves of tile 0 into buf 0; publish h0
  gld16(aP0,      &sAm[0][(rgS0 * 2 + 0) * 512]);
  gld16(aP1,      &sAm[0][(rgS3 * 2 + 0) * 512]);
  gld16(bP0,      &sBm[0][(rgS1 * 2 + 0) * 512]);
  gld16(bP1,      &sBm[0][(rgS2 * 2 + 0) * 512]);
  MEMF();
  gld16(aP0 + 32, &sAm[0][(rgS0 * 2 + 1) * 512]);
  gld16(aP1 + 32, &sAm[0][(rgS3 * 2 + 1) * 512]);
  gld16(bP0 + 32, &sBm[0][(rgS1 * 2 + 1) * 512]);
  gld16(bP1 + 32, &sBm[0][(rgS2 * 2 + 1) * 512]);
  MEMF();
  VMW(4); BARR();                      // (0,h0) resident for all waves

  const int NT = K >> 6;
  for (int tt = 0; tt < NT; tt++) {
    const int c = tt & 1, o = c ^ 1;
    const int kq = (tt + 1 < NT) ? (tt + 1) << 6 : 0;  // wrap: dummy reload
    #pragma unroll
    for (int h = 0; h < 2; h++) {
      // 12 ds_reads: all frags of (tt,h) — even per phase
      #pragma unroll
      for (int i = 0; i < 8; i++)
        aF[i] = *(const bf16x8*)(&sAm[c][((wm * 8 + i) * 2 + h) * 512 + lane * 8]);
      #pragma unroll
      for (int j = 0; j < 4; j++)
        bF[j] = *(const bf16x8*)(&sBm[c][((wn * 4 + j) * 2 + h) * 512 + lane * 8]);
      MEMF();
      // stage (tt+1, h) into buf o (4 gld16)
      gld16(aP0 + kq + h * 32, &sAm[o][(rgS0 * 2 + h) * 512]);
      gld16(aP1 + kq + h * 32, &sAm[o][(rgS3 * 2 + h) * 512]);
      gld16(bP0 + kq + h * 32, &sBm[o][(rgS1 * 2 + h) * 512]);
      gld16(bP1 + kq + h * 32, &sBm[o][(rgS2 * 2 + h) * 512]);
      MEMF();
      LGKM(8);                          // partial: read tails span the barrier
      BARR();
      LGKM(0);
      __builtin_amdgcn_sched_barrier(0);
      __builtin_amdgcn_s_setprio(1);
      #pragma unroll
      for (int i = 0; i < 8; i++)
        #pragma unroll
        for (int j = 0; j < 4; j++)
          acc[i][j] = __builtin_amdgcn_mfma_f32_16x16x32_bf16(aF[i], bF[j], acc[i][j], 0, 0, 0);
      __builtin_amdgcn_s_setprio(0);
      VMW(4);                           // publish next phase's half
      BARR();
    }
  }
  VMW(0);  // drain wrapped dummy stages before epilogue

  #pragma unroll
  for (int mf = 0; mf < 8; mf++) {
    const int row0 = mt * 256 + wm * 128 + mf * 16 + l4 * 4;
    #pragma unroll
    for (int nf = 0; nf < 4; nf++) {
      const int col = nt * 256 + wn * 64 + nf * 16 + l15;
      if (col < Ns) {
        #pragma unroll
        for (int r = 0; r < 4; r++)
          C[(size_t)(row0 + r) * Ns + col] = acc[mf][nf][r];
      }
    }
  }
}

// ---------------------------------------------------------------------------
// Double-buffered stage of one BK=64 tile half-pair (8 gld16 per wave).
// Fragment-ordered segments: h*4096 + seg*512 ushorts; seg = 16 rows.
// (kept for the 128x128 kernel used by GEMM2)
// ---------------------------------------------------------------------------
__device__ __forceinline__ void stage_tile(
    const ushort* aS0, const ushort* aS1, const ushort* bS0, const ushort* bS1,
    ushort* ldsA, ushort* ldsB, int wave, int k0)
{
  #pragma unroll
  for (int h = 0; h < 2; h++) {
    gld16(aS0 + k0 + h * 32, ldsA + h * 4096 + (wave * 2 + 0) * 512);
    gld16(aS1 + k0 + h * 32, ldsA + h * 4096 + (wave * 2 + 1) * 512);
    gld16(bS0 + k0 + h * 32, ldsB + h * 4096 + (wave * 2 + 0) * 512);
    gld16(bS1 + k0 + h * 32, ldsB + h * 4096 + (wave * 2 + 1) * 512);
  }
}

// ---------------------------------------------------------------------------
// bf16 MFMA GEMM (NT): 128x128 tile, BK=64, double-buffered. Used for GEMM2
// (M=2048,N=2048: only 64 tiles at 256 width -> 128 tile keeps CUs busy).
// ---------------------------------------------------------------------------
__global__ __launch_bounds__(256) void gemm_bf16_nt(
    const ushort* __restrict__ A, const ushort* __restrict__ B,
    float* __restrict__ C, int M, int N, int K)
{
  __shared__ ushort sL[2][2][8192];   // [buf][A/B][2 halves x 8 segs x 512]
  int t = threadIdx.x;
  int wave = t >> 6, lane = t & 63;
  int wm = wave >> 1, wn = wave & 1;
  int lrow = lane & 15, quad = lane >> 4;
  int mt = blockIdx.x, nt = blockIdx.y;

  f32x4 acc[4][4];
  #pragma unroll
  for (int i = 0; i < 4; i++)
    #pragma unroll
    for (int j = 0; j < 4; j++)
      #pragma unroll
      for (int r = 0; r < 4; r++) acc[i][j][r] = 0.f;

  const ushort* aS0 = A + (size_t)(mt * 128 + (wave * 2 + 0) * 16 + lrow) * K + quad * 8;
  const ushort* aS1 = A + (size_t)(mt * 128 + (wave * 2 + 1) * 16 + lrow) * K + quad * 8;
  const ushort* bS0 = B + (size_t)(nt * 128 + (wave * 2 + 0) * 16 + lrow) * K + quad * 8;
  const ushort* bS1 = B + (size_t)(nt * 128 + (wave * 2 + 1) * 16 + lrow) * K + quad * 8;

  stage_tile(aS0, aS1, bS0, bS1, &sL[0][0][0], &sL[0][1][0], wave, 0);
  __syncthreads();

  const int NK = K >> 6;
  for (int it = 0; it < NK; it++) {
    if (it + 1 < NK)
      stage_tile(aS0, aS1, bS0, bS1,
                 &sL[(it + 1) & 1][0][0], &sL[(it + 1) & 1][1][0],
                 wave, (it + 1) * 64);
    const ushort* bufA = &sL[it & 1][0][0];
    const ushort* bufB = &sL[it & 1][1][0];
    #pragma unroll
    for (int h = 0; h < 2; h++) {
      bf16x8 af[4], bfr[4];
      #pragma unroll
      for (int i = 0; i < 4; i++)
        af[i] = *(const bf16x8*)(bufA + h * 4096 + (wm * 4 + i) * 512 + lane * 8);
      #pragma unroll
      for (int j = 0; j < 4; j++)
        bfr[j] = *(const bf16x8*)(bufB + h * 4096 + (wn * 4 + j) * 512 + lane * 8);
      #pragma unroll
      for (int i = 0; i < 4; i++)
        #pragma unroll
        for (int j = 0; j < 4; j++)
          acc[i][j] = __builtin_amdgcn_mfma_f32_16x16x32_bf16(af[i], bfr[j], acc[i][j], 0, 0, 0);
    }
    __syncthreads();
  }

  #pragma unroll
  for (int i = 0; i < 4; i++) {
    int m_base = mt * 128 + wm * 64 + i * 16 + quad * 4;
    #pragma unroll
    for (int j = 0; j < 4; j++) {
      int n = nt * 128 + wn * 64 + j * 16 + lrow;
      #pragma unroll
      for (int rr = 0; rr < 4; rr++)
        C[(size_t)(m_base + rr) * N + n] = acc[i][j][rr];
    }
  }
}

// ---------------------------------------------------------------------------
// conv_state_new[b][c][j] = mixed_qkv[b][S-3+j][c]  (from (B,S,NBIG) C-matrix)
// ---------------------------------------------------------------------------
__global__ void convstate_kernel(const float* __restrict__ Cbig,
                                 float* __restrict__ out)
{
  int idx = blockIdx.x * blockDim.x + threadIdx.x;
  if (idx >= B_ * CC_ * 3) return;
  int j = idx % 3;
  int c = (idx / 3) % CC_;
  int b = idx / (3 * CC_);
  out[idx] = Cbig[((size_t)(b * S_ + (S_ - 3 + j))) * NBIG + c];
}

// ---------------------------------------------------------------------------
// prep_qkv: conv(K=4)+silu; l2norm q/k heads. qkv read from C-matrix cols 0..8191
// ---------------------------------------------------------------------------
__global__ __launch_bounds__(128) void prep_qkv(
    const float* __restrict__ Cbig, const float* __restrict__ conv_state,
    const float* __restrict__ conv_w,
    float* __restrict__ Qn, float* __restrict__ Kn, float* __restrict__ Vb)
{
  int group = blockIdx.x, s = blockIdx.y, b = blockIdx.z;
  int t = threadIdx.x;
  int c = group * 128 + t;
  float acc = 0.f;
  #pragma unroll
  for (int kk = 0; kk < 4; kk++) {
    int sp = s - 3 + kk;
    float x = (sp < 0) ? conv_state[((size_t)(b * CC_ + c)) * 3 + (3 + sp)]
                       : Cbig[((size_t)(b * S_ + sp)) * NBIG + c];
    acc += conv_w[c * 4 + kk] * x;
  }
  float val = acc / (1.f + __expf(-acc));   // silu

  if (group < 32) {
    __shared__ float red2[2];
    float p = val * val;
    #pragma unroll
    for (int off = 32; off > 0; off >>= 1) p += __shfl_xor(p, off);
    if ((t & 63) == 0) red2[t >> 6] = p;
    __syncthreads();
    float r = rsqrtf(red2[0] + red2[1] + 1e-6f);
    if (group < 16) {
      r *= 0.08838834764831845f;  // 128^-0.5
      Qn[(((size_t)(b * HK_ + group)) * S_ + s) * DK_ + t] = val * r;
    } else {
      Kn[(((size_t)(b * HK_ + (group - 16))) * S_ + s) * DK_ + t] = val * r;
    }
  } else {
    Vb[(((size_t)(b * HV_ + (group - 32))) * S_ + s) * DV_ + t] = val;
  }
}

// ---------------------------------------------------------------------------
// prep_gb: g/beta from C-matrix cols 12288..12351
// ---------------------------------------------------------------------------
__global__ void prep_gb(const float* __restrict__ Cbig,
                        const float* __restrict__ A_log, const float* __restrict__ dt_bias,
                        float* __restrict__ g_buf, float* __restrict__ beta_buf)
{
  int idx = blockIdx.x * blockDim.x + threadIdx.x;
  if (idx >= B_ * HV_ * S_) return;
  int s = idx & (S_ - 1);
  int hv = (idx >> 10) & 31;
  int b = idx >> 15;
  float bv = Cbig[((size_t)(b * S_ + s)) * NBIG + 12288 + hv];
  float av = Cbig[((size_t)(b * S_ + s)) * NBIG + 12320 + hv];
  float x = av + dt_bias[hv];
  float sp = (x > 20.f) ? x : log1pf(__expf(x));
  g_buf[idx] = -__expf(A_log[hv]) * sp;
  beta_buf[idx] = 1.f / (1.f + __expf(-bv));
}

// ---------------------------------------------------------------------------
// cp_kernel v2: per (b,hv,chunk). G cumsum, M, A, Tinv, Kc, D0.
//  - sT padded to stride 65 (+ separate sGB): column reads sT[t*65+j] hit
//    banks (t+j)%32 -> conflict-free (was 64-way, the 2M SQ_LDS_BANK_CONFLICT)
//  - tTw/tTb builds parallelized over all 256 threads (was 1 wave serial)
//  - Kc/D0: contiguous col ownership (tk*8..+7): 2x ds_read_b128 per j
//    (was 8 scalar reads + swizzle math) and 2x dwordx4 stores per row
//    (was 32 scalar stores). Same [row][col] output addresses.
// ---------------------------------------------------------------------------
__device__ __forceinline__ int swf4(int r, int f) { return r * 32 + (f ^ (r & 31)); }

__global__ __launch_bounds__(256) void cp_kernel(
    const float* __restrict__ Qn, const float* __restrict__ Kn,
    const float* __restrict__ Vb,
    const float* __restrict__ g_buf, const float* __restrict__ beta_buf,
    float* __restrict__ G_buf, float* __restrict__ M_buf,
    float* __restrict__ KcD, float* __restrict__ D0p)
{
  __shared__ float sK[64 * 128];
  __shared__ float sX[32 * 128];
  __shared__ float sT[64 * 65];   // stride-65: conflict-free column reads
  __shared__ float sGB[128];      // [0:64) G cumsum, [64:128) beta
  float* sG  = sGB;
  float* sBe = sGB + 64;
  float* sA  = sX;
  float* tTw = sX;
  float* tTb = sX;
  float4* sK4 = (float4*)sK;
  float4* sX4 = (float4*)sX;

  const int ch = blockIdx.x;
  const int bh = ch / NC_, c = ch % NC_;
  const int b = bh >> 5, hv = bh & 31, hk = hv >> 1;
  const int s0 = c * CS_;
  const int t = threadIdx.x;
  const size_t gOff = (size_t)bh * S_ + s0;

  if (t < 64) {
    float Gw0 = g_buf[gOff + t];
    #pragma unroll
    for (int off = 1; off < 64; off <<= 1) {
      float o = __shfl_up(Gw0, off);
      if (t >= off) Gw0 += o;
    }
    G_buf[gOff + t] = Gw0;
    sG[t] = Gw0;
    sBe[t] = beta_buf[gOff + t];
  }
  {
    const float4* src = (const float4*)(Kn + ((size_t)(b * HK_ + hk) * S_ + s0) * DK_);
    #pragma unroll
    for (int u = 0; u < 8; u++) {
      int idx = u * 256 + t;
      sK4[swf4(idx >> 5, idx & 31)] = src[idx];
    }
  }
  __syncthreads();

  // ---- M = (Q e^{Gi-Gj} K^T) masked ----
  const float4* qsrc = (const float4*)(Qn + ((size_t)(b * HK_ + hk) * S_ + s0) * DK_);
  {
    int ti2 = t >> 4, tj = t & 15;
    for (int h = 0; h < 2; h++) {
      #pragma unroll
      for (int u = 0; u < 4; u++) {
        int idx = u * 256 + t;
        sX4[swf4(idx >> 5, idx & 31)] = qsrc[h * 1024 + idx];
      }
      __syncthreads();
      float accM[2][4];
      #pragma unroll
      for (int a = 0; a < 2; a++)
        #pragma unroll
        for (int e = 0; e < 4; e++) accM[a][e] = 0.f;
      for (int k4 = 0; k4 < 32; k4++) {
        float4 qv[2], kv[4];
        qv[0] = sX4[swf4(ti2, k4)];
        qv[1] = sX4[swf4(ti2 + 16, k4)];
        #pragma unroll
        for (int e = 0; e < 4; e++) kv[e] = sK4[swf4(tj + 16 * e, k4)];
        #pragma unroll
        for (int a = 0; a < 2; a++)
          #pragma unroll
          for (int e = 0; e < 4; e++)
            accM[a][e] += qv[a].x * kv[e].x + qv[a].y * kv[e].y +
                          qv[a].z * kv[e].z + qv[a].w * kv[e].w;
      }
      #pragma unroll
      for (int a = 0; a < 2; a++) {
        int iG = h * 32 + ti2 + 16 * a;
        float Gi = sG[iG];
        #pragma unroll
        for (int e = 0; e < 4; e++) {
          int j = tj + 16 * e;
          float m = (j <= iG) ? __expf(Gi - sG[j]) * accM[a][e] : 0.f;
          M_buf[(size_t)ch * 4096 + iG * 64 + j] = m;
        }
      }
      __syncthreads();
    }
  }

  // ---- A = beta e^{Gi-Gj} (K K^T) strictly-lower ----
  {
    int ti = t >> 4, tj = t & 15;
    float accA[4][4];
    #pragma unroll
    for (int a = 0; a < 4; a++)
      #pragma unroll
      for (int e = 0; e < 4; e++) accA[a][e] = 0.f;
    for (int k4 = 0; k4 < 32; k4++) {
      float4 ki[4], kj[4];
      #pragma unroll
      for (int e = 0; e < 4; e++) {
        ki[e] = sK4[swf4(ti + 16 * e, k4)];
        kj[e] = sK4[swf4(tj + 16 * e, k4)];
      }
      #pragma unroll
      for (int a = 0; a < 4; a++)
        #pragma unroll
        for (int e = 0; e < 4; e++)
          accA[a][e] += ki[a].x * kj[e].x + ki[a].y * kj[e].y +
                        ki[a].z * kj[e].z + ki[a].w * kj[e].w;
    }
    float resA[4][4];
    #pragma unroll
    for (int a = 0; a < 4; a++) {
      int i = ti + 16 * a;
      float Gi = sG[i], Bi = sBe[i];
      #pragma unroll
      for (int e = 0; e < 4; e++) {
        int j = tj + 16 * e;
        resA[a][e] = (j < i) ? Bi * __expf(Gi - sG[j]) * accA[a][e] : 0.f;
      }
    }
    __syncthreads();
    #pragma unroll
    for (int a = 0; a < 4; a++)
      #pragma unroll
      for (int e = 0; e < 4; e++)
        sA[(ti + 16 * a) * 64 + (tj + 16 * e)] = resA[a][e];
  }
  __syncthreads();

  // ---- Tinv: forward substitution, column t per thread (wave 0) ----
  if (t < 64) {
    sT[t] = (t == 0) ? 1.f : 0.f;
    for (int i = 1; i < 64; i++) {
      float acc = 0.f;
      for (int j = 0; j < i; j++) acc += sA[i * 64 + j] * sT[j * 65 + t];
      sT[i * 65 + t] = ((t == i) ? 1.f : 0.f) - acc;
    }
  }
  __syncthreads();

  // ---- tTw[j][i] = Tinv[i][j] * beta[j] e^{G[j]}  (all 256 threads) ----
  #pragma unroll
  for (int u = 0; u < 16; u++) {
    int idx = u * 256 + t;
    int tcol = idx & 63;
    int j = idx >> 6;
    float wj = sBe[j] * __expf(sG[j]);
    tTw[j * 64 + tcol] = sT[tcol * 65 + j] * wj;
  }
  __syncthreads();

  // ---- Kc = tTw^T K : rows i04*4+r, cols tk*8..tk*8+7 ----
  {
    int i04 = t >> 4, tk = t & 15;
    float accK[4][8];
    #pragma unroll
    for (int r = 0; r < 4; r++)
      #pragma unroll
      for (int u = 0; u < 8; u++) accK[r][u] = 0.f;
    for (int j = 0; j < 64; j++) {
      float4 tw = ((float4*)tTw)[j * 16 + i04];
      float4 ka = sK4[swf4(j, tk * 2)];
      float4 kb = sK4[swf4(j, tk * 2 + 1)];
      float tws[4] = {tw.x, tw.y, tw.z, tw.w};
      float kvv[8] = {ka.x, ka.y, ka.z, ka.w, kb.x, kb.y, kb.z, kb.w};
      #pragma unroll
      for (int r = 0; r < 4; r++)
        #pragma unroll
        for (int u = 0; u < 8; u++)
          accK[r][u] += tws[r] * kvv[u];
    }
    size_t base = (size_t)ch * NBIG;
    #pragma unroll
    for (int r = 0; r < 4; r++) {
      *(float4*)(&KcD[base + (size_t)(i04 * 4 + r) * 128 + tk * 8]) =
          make_float4(accK[r][0], accK[r][1], accK[r][2], accK[r][3]);
      *(float4*)(&KcD[base + (size_t)(i04 * 4 + r) * 128 + tk * 8 + 4]) =
          make_float4(accK[r][4], accK[r][5], accK[r][6], accK[r][7]);
    }
  }
  __syncthreads();

  // ---- tTb[j][i] = Tinv[i][j] * beta[j] (all threads) + stage V into sK ----
  #pragma unroll
  for (int u = 0; u < 16; u++) {
    int idx = u * 256 + t;
    int tcol = idx & 63;
    int j = idx >> 6;
    tTb[j * 64 + tcol] = sT[tcol * 65 + j] * sBe[j];
  }
  {
    const float4* src = (const float4*)(Vb + ((size_t)bh * S_ + s0) * DV_);
    #pragma unroll
    for (int u = 0; u < 8; u++) {
      int idx = u * 256 + t;
      sK4[swf4(idx >> 5, idx & 31)] = src[idx];
    }
  }
  __syncthreads();

  // ---- D0 = tTb^T V : rows i04*4+r, cols tv*8..tv*8+7 ----
  {
    int i04 = t >> 4, tv_ = t & 15;
    float accD[4][8];
    #pragma unroll
    for (int r = 0; r < 4; r++)
      #pragma unroll
      for (int u = 0; u < 8; u++) accD[r][u] = 0.f;
    for (int j = 0; j < 64; j++) {
      float4 tb = ((float4*)tTb)[j * 16 + i04];
      float4 va = sK4[swf4(j, tv_ * 2)];
      float4 vb = sK4[swf4(j, tv_ * 2 + 1)];
      float tbs[4] = {tb.x, tb.y, tb.z, tb.w};
      float vvv[8] = {va.x, va.y, va.z, va.w, vb.x, vb.y, vb.z, vb.w};
      #pragma unroll
      for (int r = 0; r < 4; r++)
        #pragma unroll
        for (int u = 0; u < 8; u++)
          accD[r][u] += tbs[r] * vvv[u];
    }
    size_t base = (size_t)ch * NBIG;
    #pragma unroll
    for (int r = 0; r < 4; r++) {
      *(float4*)(&D0p[base + (size_t)(i04 * 4 + r) * 128 + tv_ * 8]) =
          make_float4(accD[r][0], accD[r][1], accD[r][2], accD[r][3]);
      *(float4*)(&D0p[base + (size_t)(i04 * 4 + r) * 128 + tv_ * 8 + 4]) =
          make_float4(accD[r][4], accD[r][5], accD[r][6], accD[r][7]);
    }
  }
}

// ---------------------------------------------------------------------------
// phaseb v5: 256 blocks x 512 threads (8 waves = 2/SIMD for latency hiding).
// Phase B k-loop split across two 4-wave groups (k<64 | k>=64) with an LDS
// partial reduction; phase D: 2 k-rows/thread, full i-sum (no reduction).
// ---------------------------------------------------------------------------
__global__ __launch_bounds__(512) void phaseb_kernel(
    const float* __restrict__ rec_state, const float* __restrict__ Qn,
    const float* __restrict__ Kn, const float* __restrict__ G_buf,
    float* __restrict__ KcD, const float* __restrict__ D0p,
    float* __restrict__ Oq_buf, float* __restrict__ final_state)
{
  __shared__ float sS[128 * 32];    // state [k][v]
  __shared__ float sKT[128 * 64];   // Kc^T [k][i]; then Kd (swizzled) [i][k]
  __shared__ float sQT[128 * 64];   // Qb^T [k][i]
  __shared__ float sD[64 * 32];     // D [i][v]
  __shared__ float sR[2][64 * 32];  // k-group-1 partials: [0]=D, [1]=O

  const int blk = blockIdx.x;       // xcd | vq<<3 | g<<5
  const int bh = (blk & 7) | ((blk >> 5) << 3);
  const int vq = (blk >> 3) & 3;
  const int b = bh >> 5, hv = bh & 31, hk = hv >> 1;
  const int t = threadIdx.x;
  const int vbase = vq * 32;
  const float* gG = G_buf + (size_t)bh * S_;

  #pragma unroll
  for (int u = 0; u < 2; u++) {
    int idx = u * 512 + t;
    int k = idx >> 3;
    int v4 = (idx & 7) * 4;
    *(float4*)(&sS[k * 32 + v4]) =
        *(const float4*)(&rec_state[((size_t)bh * 128 + k) * 128 + vbase + v4]);
  }
  __syncthreads();

  const int si = t & 63, skq = t >> 6;   // stage: row si, k-block skq (16 k)
  const int kg = t >> 8;                 // phase-B k-group (wave-uniform)
  const int tt = t & 255;
  const int ti = tt >> 3, tv = t & 7;    // phase-B: 2 i-rows, 4 v
  const int tp = t >> 3;                 // phase-D: k-pair in [0,64)

  for (int c = 0; c < NC_; c++) {
    const size_t ch = (size_t)bh * NC_ + c;
    const int s0 = c * CS_;
    const float GC = gG[s0 + 63];
    const float eGC = __expf(GC);

    // phase A: stage Kc^T [k][i] and Qb^T [k][i] (16 k per thread)
    {
      float eGi = __expf(gG[s0 + si]);
      const float* kcRow = KcD + ch * NBIG + si * 128 + skq * 16;
      const float* qRow  = Qn + ((size_t)(b * HK_ + hk) * S_ + s0 + si) * DK_ + skq * 16;
      #pragma unroll
      for (int u = 0; u < 4; u++) {
        float4 kc = *(const float4*)(kcRow + u * 4);
        float4 qv = *(const float4*)(qRow + u * 4);
        int kk = skq * 16 + u * 4;
        sKT[(kk + 0) * 64 + si] = kc.x; sKT[(kk + 1) * 64 + si] = kc.y;
        sKT[(kk + 2) * 64 + si] = kc.z; sKT[(kk + 3) * 64 + si] = kc.w;
        sQT[(kk + 0) * 64 + si] = qv.x * eGi; sQT[(kk + 1) * 64 + si] = qv.y * eGi;
        sQT[(kk + 2) * 64 + si] = qv.z * eGi; sQT[(kk + 3) * 64 + si] = qv.w * eGi;
      }
    }
    __syncthreads();

    // phase B: D/O partials over k in [kg*64, kg*64+64)
    {
      float accD[2][4], accO[2][4];
      #pragma unroll
      for (int r = 0; r < 2; r++) {
        accO[r][0] = accO[r][1] = accO[r][2] = accO[r][3] = 0.f;
        accD[r][0] = accD[r][1] = accD[r][2] = accD[r][3] = 0.f;
      }
      if (kg == 0) {
        #pragma unroll
        for (int r = 0; r < 2; r++) {
          float4 d0 = *(const float4*)(&D0p[ch * NBIG + (size_t)(ti * 2 + r) * 128 + vbase + tv * 4]);
          accD[r][0] = d0.x; accD[r][1] = d0.y; accD[r][2] = d0.z; accD[r][3] = d0.w;
        }
      }
      const int k0 = kg << 6;
      for (int k = k0; k < k0 + 64; k++) {
        float2 kc = *(const float2*)(&sKT[k * 64 + ti * 2]);
        float2 qb = *(const float2*)(&sQT[k * 64 + ti * 2]);
        float4 sv = *(const float4*)(&sS[k * 32 + tv * 4]);
        accD[0][0] -= kc.x * sv.x; accD[0][1] -= kc.x * sv.y;
        accD[0][2] -= kc.x * sv.z; accD[0][3] -= kc.x * sv.w;
        accD[1][0] -= kc.y * sv.x; accD[1][1] -= kc.y * sv.y;
        accD[1][2] -= kc.y * sv.z; accD[1][3] -= kc.y * sv.w;
        accO[0][0] += qb.x * sv.x; accO[0][1] += qb.x * sv.y;
        accO[0][2] += qb.x * sv.z; accO[0][3] += qb.x * sv.w;
        accO[1][0] += qb.y * sv.x; accO[1][1] += qb.y * sv.y;
        accO[1][2] += qb.y * sv.z; accO[1][3] += qb.y * sv.w;
      }
      if (kg == 1) {
        #pragma unroll
        for (int r = 0; r < 2; r++) {
          int i = ti * 2 + r;
          *(float4*)(&sR[0][i * 32 + tv * 4]) =
              make_float4(accD[r][0], accD[r][1], accD[r][2], accD[r][3]);
          *(float4*)(&sR[1][i * 32 + tv * 4]) =
              make_float4(accO[r][0], accO[r][1], accO[r][2], accO[r][3]);
        }
      }
      __syncthreads();   // sKT/sQT reads done; sR partials visible
      if (kg == 0) {
        #pragma unroll
        for (int r = 0; r < 2; r++) {
          int i = ti * 2 + r;
          float4 pD = *(const float4*)(&sR[0][i * 32 + tv * 4]);
          float4 pO = *(const float4*)(&sR[1][i * 32 + tv * 4]);
          float4 dv = make_float4(accD[r][0] + pD.x, accD[r][1] + pD.y,
                                  accD[r][2] + pD.z, accD[r][3] + pD.w);
          float4 ov = make_float4(accO[r][0] + pO.x, accO[r][1] + pO.y,
                                  accO[r][2] + pO.z, accO[r][3] + pO.w);
          *(float4*)(&sD[i * 32 + tv * 4]) = dv;
          *(float4*)(&KcD[ch * NBIG + (size_t)i * 128 + vbase + tv * 4]) = dv;
          *(float4*)(&Oq_buf[ch * 8192 + (size_t)i * 128 + vbase + tv * 4]) = ov;
        }
      }
    }

    // phase C: stage Kd (scaled, swizzled) into sKT (safe: sKT no longer read)
    {
      float sc = __expf(GC - gG[s0 + si]);
      const float* kRow = Kn + ((size_t)(b * HK_ + hk) * S_ + s0 + si) * DK_ + skq * 16;
      #pragma unroll
      for (int u = 0; u < 4; u++) {
        float4 x = *(const float4*)(kRow + u * 4);
        x.x *= sc; x.y *= sc; x.z *= sc; x.w *= sc;
        int kgr = skq * 4 + u;
        *(float4*)(&sKT[si * 128 + 4 * (kgr ^ (si & 31))]) = x;
      }
    }
    __syncthreads();   // sD final + Kd staged

    // phase D: state update, 2 k-rows per thread, full i-sum
    {
      float acc[2][4];
      acc[0][0] = acc[0][1] = acc[0][2] = acc[0][3] = 0.f;
      acc[1][0] = acc[1][1] = acc[1][2] = acc[1][3] = 0.f;
      const int kgr = tp >> 1, kh = (tp & 1) * 2;
      for (int i = 0; i < 64; i++) {
        float4 d  = *(const float4*)(&sD[i * 32 + tv * 4]);
        float2 ka = *(const float2*)(&sKT[i * 128 + 4 * (kgr ^ (i & 31)) + kh]);
        acc[0][0] += ka.x * d.x; acc[0][1] += ka.x * d.y;
        acc[0][2] += ka.x * d.z; acc[0][3] += ka.x * d.w;
        acc[1][0] += ka.y * d.x; acc[1][1] += ka.y * d.y;
        acc[1][2] += ka.y * d.z; acc[1][3] += ka.y * d.w;
      }
      #pragma unroll
      for (int r = 0; r < 2; r++) {
        int k = tp * 2 + r;
        float4 s = *(const float4*)(&sS[k * 32 + tv * 4]);
        s.x = s.x * eGC + acc[r][0]; s.y = s.y * eGC + acc[r][1];
        s.z = s.z * eGC + acc[r][2]; s.w = s.w * eGC + acc[r][3];
        *(float4*)(&sS[k * 32 + tv * 4]) = s;
      }
    }
    __syncthreads();
  }

  #pragma unroll
  for (int u = 0; u < 2; u++) {
    int idx = u * 512 + t;
    int k = idx >> 3;
    int v4 = (idx & 7) * 4;
    *(float4*)(&final_state[((size_t)bh * 128 + k) * 128 + vbase + v4]) =
        *(const float4*)(&sS[k * 32 + v4]);
  }
}

// ---------------------------------------------------------------------------
// phasec: O = Oq + M*D, RMS-norm + weight + silu(z) gate -> bf16 zg
// ---------------------------------------------------------------------------
__global__ __launch_bounds__(128) void phasec_kernel(
    const float* __restrict__ KcD, const float* __restrict__ Oq_buf,
    const float* __restrict__ M_buf, const float* __restrict__ norm_weight,
    const float* __restrict__ Cbig, ushort* __restrict__ zg_bf)
{
  __shared__ float sM[4096];
  __shared__ float red[2][2];
  int ch = blockIdx.x;
  int bh = ch / NC_, c = ch % NC_;
  int b = bh >> 5, hv = bh & 31;
  int s0 = c * CS_;
  int v = threadIdx.x;

  float Dr[64];
  #pragma unroll
  for (int j = 0; j < 64; j++) Dr[j] = KcD[(size_t)ch * NBIG + j * 128 + v];
  {
    const float4* src = (const float4*)(M_buf + (size_t)ch * 4096);
    #pragma unroll
    for (int u = 0; u < 8; u++) ((float4*)sM)[u * 128 + v] = src[u * 128 + v];
  }
  __syncthreads();
  float nw = norm_weight[v];

  for (int i = 0; i < 64; i++) {
    float o = Oq_buf[(size_t)ch * 8192 + i * 128 + v];
    const float4* mr = (const float4*)(sM + i * 64);
    #pragma unroll
    for (int j4 = 0; j4 < 16; j4++) {
      float4 m = mr[j4];
      o += m.x * Dr[4 * j4] + m.y * Dr[4 * j4 + 1] +
           m.z * Dr[4 * j4 + 2] + m.w * Dr[4 * j4 + 3];
    }
    float p = o * o;
    #pragma unroll
    for (int off = 32; off > 0; off >>= 1) p += __shfl_xor(p, off);
    if ((v & 63) == 0) red[i & 1][v >> 6] = p;
    __syncthreads();
    float var = (red[i & 1][0] + red[i & 1][1]) * (1.f / 128.f);
    float xn = o * rsqrtf(var + 1e-6f) * nw;
    float zv = Cbig[((size_t)(b * S_ + s0 + i)) * NBIG + 8192 + hv * DV_ + v];
    zg_bf[((size_t)(b * S_ + s0 + i)) * VALDIM_ + hv * DV_ + v] =
        f2bf_rne(xn * (zv / (1.f + __expf(-zv))));
  }
}

// ---------------------------------------------------------------------------
extern "C" void kernel_launch(void* const* d_in, const int* in_sizes, int n_in,
                              void* d_out, int out_size, void* d_ws, size_t ws_size,
                              hipStream_t stream)
{
  const float* hs          = (const float*)d_in[0];
  const float* conv_state  = (const float*)d_in[1];
  const float* rec_state   = (const float*)d_in[2];
  const float* W_qkv       = (const float*)d_in[3];
  const float* W_z         = (const float*)d_in[4];
  const float* W_b         = (const float*)d_in[5];
  const float* W_a         = (const float*)d_in[6];
  const float* conv_w      = (const float*)d_in[7];
  const float* dt_bias     = (const float*)d_in[8];
  const float* A_log       = (const float*)d_in[9];
  const float* norm_weight = (const float*)d_in[10];
  const float* W_out       = (const float*)d_in[11];

  float* out       = (float*)d_out;                      // (B,S,H)
  float* out_conv  = out + (size_t)B_ * S_ * H_;         // (B,C,3)
  float* out_state = out_conv + (size_t)B_ * CC_ * 3;    // (B,HV,DK,DV)

  float* ws = (float*)d_ws;
  float* Cbig = ws;                            // (2048, 12416) = 25,427,968
  float* KcD  = Cbig;
  float* D0p  = Cbig + (size_t)1024 * NBIG;
  float* g_buf    = ws + 25427968;
  float* beta_buf = ws + 25493504;
  float* G_buf    = ws + 25559040;
  float* Qn       = ws + 25624576;
  float* Kn       = ws + 29818880;
  float* Vb       = ws + 34013184;
  float* M_buf    = ws + 42401792;
  float* Oq_buf   = Vb;

  // Wcat_bf: (12544, 2048) ushorts = 12,845,056 float-slots
  ushort* Wcat_bf = (ushort*)(ws + 25427968);
  // hs_bf past the padded Wcat; lives in Vb's dead window, ends at
  // 40,370,176 < M_buf (42,401,792). Total ws usage unchanged (46,596,096 f).
  ushort* hs_bf   = (ushort*)(ws + 38273024);
  ushort* zg_bf   = (ushort*)Qn;
  ushort* Wout_bf = (ushort*)Kn;

  const int M = B_ * S_;  // 2048

  // 0. converts
  f2bf_kernel<<<(M * H_) / 1024, 256, 0, stream>>>(hs, hs_bf, M * H_);
  wcat_kernel<<<(NBIGP * H_) / 1024, 256, 0, stream>>>(W_qkv, W_z, W_b, W_a, Wcat_bf);
  // 1. fused qkv|z|b|a GEMM -> Cbig (256x256, k-split even phases,
  //    counted vmcnt/lgkm pipeline)
  gemm256_8ph<<<dim3(M / 256, NBIGP / 256), 512, 0, stream>>>(hs_bf, Wcat_bf, Cbig, NBIG, H_);
  // 2. conv_state_new output
  convstate_kernel<<<(B_ * CC_ * 3 + 255) / 256, 256, 0, stream>>>(Cbig, out_conv);
  // 3. conv+silu+l2norm -> Qn,Kn,Vb ; gates
  prep_qkv<<<dim3(64, S_, B_), 128, 0, stream>>>(Cbig, conv_state, conv_w, Qn, Kn, Vb);
  prep_gb<<<(B_ * HV_ * S_ + 255) / 256, 256, 0, stream>>>(Cbig, A_log, dt_bias, g_buf, beta_buf);
  // 4. per-chunk matrices (v2: padded sT, parallel tT builds, float4 Kc/D0)
  cp_kernel<<<B_ * HV_ * NC_, 256, 0, stream>>>(Qn, Kn, Vb, g_buf, beta_buf,
                                                G_buf, M_buf, KcD, D0p);
  // 5. sequential chunk recurrence (512 thr: 2 waves/SIMD latency hiding)
  phaseb_kernel<<<B_ * HV_ * 4, 512, 0, stream>>>(rec_state, Qn, Kn, G_buf,
                                                  KcD, D0p, Oq_buf, out_state);
  // 6. W_out convert + intra-chunk output/RMS/gate -> bf16
  f2bf_kernel<<<(H_ * VALDIM_) / 1024, 256, 0, stream>>>(W_out, Wout_bf, H_ * VALDIM_);
  phasec_kernel<<<B_ * HV_ * NC_, 128, 0, stream>>>(KcD, Oq_buf, M_buf,
                                                    norm_weight, Cbig, zg_bf);
  // 7. output GEMM (128x128: only 64 tiles at 256 width -> keep old kernel)
  gemm_bf16_nt<<<dim3(M / 128, H_ / 128), 256, 0, stream>>>(zg_bf, Wout_bf, out, M, H_, VALDIM_);
}

// Round 6
// 836.705 us; speedup vs baseline: 1.1808x; 1.0316x over previous
//
#include <hip/hip_runtime.h>
#include <cstdint>
#include <cstddef>

#define B_ 2
#define S_ 1024
#define H_ 2048
#define HV_ 32
#define HK_ 16
#define DK_ 128
#define DV_ 128
#define CC_ 8192
#define KEYDIM_ 2048
#define VALDIM_ 4096
#define NC_ 16          // chunks
#define CS_ 64          // chunk size
#define NBIG 12416      // fused GEMM1 N (real, C pitch): 8192 qkv + 4096 z + 32 b + 32 a + 64 pad
#define NBIGP 12544     // padded to 49*256 for the 256-wide GEMM tile (B-matrix rows only)

typedef __attribute__((ext_vector_type(8))) short bf16x8;
typedef __attribute__((ext_vector_type(4))) float f32x4;

__device__ __forceinline__ ushort f2bf_rne(float x) {
  union { float f; uint32_t u; } c; c.f = x;
  uint32_t u = c.u + 0x7FFFu + ((c.u >> 16) & 1u);
  return (ushort)(u >> 16);
}

// async 16B global->LDS (DMA; LDS dest = wave-uniform base + lane*16)
__device__ __forceinline__ void gld16(const void* g, void* l) {
  __builtin_amdgcn_global_load_lds(
      (const __attribute__((address_space(1))) void*)g,
      (__attribute__((address_space(3))) void*)l, 16, 0, 0);
}

// ---------------------------------------------------------------------------
// fp32 -> bf16 convert (n multiple of 1024)
// ---------------------------------------------------------------------------
__global__ void f2bf_kernel(const float* __restrict__ in, ushort* __restrict__ out, int n) {
  int i = (blockIdx.x * 256 + threadIdx.x) * 4;
  if (i >= n) return;
  float4 v = *(const float4*)(in + i);
  ushort4 o;
  o.x = f2bf_rne(v.x); o.y = f2bf_rne(v.y);
  o.z = f2bf_rne(v.z); o.w = f2bf_rne(v.w);
  *(ushort4*)(out + i) = o;
}

// ---------------------------------------------------------------------------
// wcat: build concatenated bf16 weight (NBIGP, H): [W_qkv; W_z; W_b; W_a; 0]
// rows 12352..12543 are zero pad (last 128 rows exist only for tile alignment)
// ---------------------------------------------------------------------------
__global__ void wcat_kernel(const float* __restrict__ Wqkv, const float* __restrict__ Wz,
                            const float* __restrict__ Wb, const float* __restrict__ Wa,
                            ushort* __restrict__ out) {
  int i = (blockIdx.x * 256 + threadIdx.x) * 4;
  if (i >= NBIGP * H_) return;
  int n = i >> 11;           // / H_
  int k = i & (H_ - 1);
  float4 v = make_float4(0.f, 0.f, 0.f, 0.f);
  if (n < 8192)       v = *(const float4*)(Wqkv + (size_t)n * H_ + k);
  else if (n < 12288) v = *(const float4*)(Wz + (size_t)(n - 8192) * H_ + k);
  else if (n < 12320) v = *(const float4*)(Wb + (size_t)(n - 12288) * H_ + k);
  else if (n < 12352) v = *(const float4*)(Wa + (size_t)(n - 12320) * H_ + k);
  ushort4 o;
  o.x = f2bf_rne(v.x); o.y = f2bf_rne(v.y);
  o.z = f2bf_rne(v.z); o.w = f2bf_rne(v.w);
  *(ushort4*)(out + i) = o;
}

// ===========================================================================
// gemm256_8ph v3: bf16 MFMA GEMM (NT), 256x256 tile, BK=64, 8 waves (2Mx4N),
// 128 KiB LDS double-buffer, k-split even phases. (unchanged from round 3)
// ===========================================================================
#define MEMF() asm volatile("" ::: "memory")
#define VMW(n) asm volatile("s_waitcnt vmcnt(" #n ")" ::: "memory")
#define LGKM(n) asm volatile("s_waitcnt lgkmcnt(" #n ")" ::: "memory")
#define BARR() do { __builtin_amdgcn_s_barrier(); MEMF(); } while (0)

__global__ __launch_bounds__(512, 2) void gemm256_8ph(
    const ushort* __restrict__ A, const ushort* __restrict__ B,
    float* __restrict__ C, int Ns, int K)
{
  __shared__ ushort sAm[2][16384];   // 2 bufs x 256 rows x 64 k (fragment-ordered)
  __shared__ ushort sBm[2][16384];

  const int t = threadIdx.x;
  const int wave = t >> 6, lane = t & 63;
  const int wm = wave >> 2, wn = wave & 3;
  const int l15 = lane & 15, l4 = lane >> 4;
  const int mt = blockIdx.x, nt = blockIdx.y;

  // per-wave row-groups (16 rows each) for staging
  const int rgS0 = (wave & 3) + (wave >> 2) * 8;   // A rows {0-63,128-191}
  const int rgS3 = rgS0 + 4;                       // A rows {64-127,192-255}
  const int rgS1 = (wave & 1) + (wave >> 1) * 4;   // B rows, b-half 0
  const int rgS2 = rgS1 + 2;                       // B rows, b-half 1

  const ushort* aP0 = A + (size_t)(mt * 256 + rgS0 * 16 + l15) * K + l4 * 8;
  const ushort* aP1 = A + (size_t)(mt * 256 + rgS3 * 16 + l15) * K + l4 * 8;
  const ushort* bP0 = B + (size_t)(nt * 256 + rgS1 * 16 + l15) * K + l4 * 8;
  const ushort* bP1 = B + (size_t)(nt * 256 + rgS2 * 16 + l15) * K + l4 * 8;

  f32x4 acc[8][4];
  #pragma unroll
  for (int i = 0; i < 8; i++)
    #pragma unroll
    for (int j = 0; j < 4; j++)
      #pragma unroll
      for (int r = 0; r < 4; r++) acc[i][j][r] = 0.f;

  bf16x8 aF[8], bF[4];

  // prologue: stage both halves of tile 0 into buf 0; publish h0
  gld16(aP0,      &sAm[0][(rgS0 * 2 + 0) * 512]);
  gld16(aP1,      &sAm[0][(rgS3 * 2 + 0) * 512]);
  gld16(bP0,      &sBm[0][(rgS1 * 2 + 0) * 512]);
  gld16(bP1,      &sBm[0][(rgS2 * 2 + 0) * 512]);
  MEMF();
  gld16(aP0 + 32, &sAm[0][(rgS0 * 2 + 1) * 512]);
  gld16(aP1 + 32, &sAm[0][(rgS3 * 2 + 1) * 512]);
  gld16(bP0 + 32, &sBm[0][(rgS1 * 2 + 1) * 512]);
  gld16(bP1 + 32, &sBm[0][(rgS2 * 2 + 1) * 512]);
  MEMF();
  VMW(4); BARR();                      // (0,h0) resident for all waves

  const int NT = K >> 6;
  for (int tt = 0; tt < NT; tt++) {
    const int c = tt & 1, o = c ^ 1;
    const int kq = (tt + 1 < NT) ? (tt + 1) << 6 : 0;  // wrap: dummy reload
    #pragma unroll
    for (int h = 0; h < 2; h++) {
      // 12 ds_reads: all frags of (tt,h) — even per phase
      #pragma unroll
      for (int i = 0; i < 8; i++)
        aF[i] = *(const bf16x8*)(&sAm[c][((wm * 8 + i) * 2 + h) * 512 + lane * 8]);
      #pragma unroll
      for (int j = 0; j < 4; j++)
        bF[j] = *(const bf16x8*)(&sBm[c][((wn * 4 + j) * 2 + h) * 512 + lane * 8]);
      MEMF();
      // stage (tt+1, h) into buf o (4 gld16)
      gld16(aP0 + kq + h * 32, &sAm[o][(rgS0 * 2 + h) * 512]);
      gld16(aP1 + kq + h * 32, &sAm[o][(rgS3 * 2 + h) * 512]);
      gld16(bP0 + kq + h * 32, &sBm[o][(rgS1 * 2 + h) * 512]);
      gld16(bP1 + kq + h * 32, &sBm[o][(rgS2 * 2 + h) * 512]);
      MEMF();
      LGKM(8);                          // partial: read tails span the barrier
      BARR();
      LGKM(0);
      __builtin_amdgcn_sched_barrier(0);
      __builtin_amdgcn_s_setprio(1);
      #pragma unroll
      for (int i = 0; i < 8; i++)
        #pragma unroll
        for (int j = 0; j < 4; j++)
          acc[i][j] = __builtin_amdgcn_mfma_f32_16x16x32_bf16(aF[i], bF[j], acc[i][j], 0, 0, 0);
      __builtin_amdgcn_s_setprio(0);
      VMW(4);                           // publish next phase's half
      BARR();
    }
  }
  VMW(0);  // drain wrapped dummy stages before epilogue

  #pragma unroll
  for (int mf = 0; mf < 8; mf++) {
    const int row0 = mt * 256 + wm * 128 + mf * 16 + l4 * 4;
    #pragma unroll
    for (int nf = 0; nf < 4; nf++) {
      const int col = nt * 256 + wn * 64 + nf * 16 + l15;
      if (col < Ns) {
        #pragma unroll
        for (int r = 0; r < 4; r++)
          C[(size_t)(row0 + r) * Ns + col] = acc[mf][nf][r];
      }
    }
  }
}

// ---------------------------------------------------------------------------
// Double-buffered stage of one BK=64 tile half-pair (8 gld16 per wave).
// Fragment-ordered segments: h*4096 + seg*512 ushorts; seg = 16 rows.
// (kept for the 128x128 kernel used by GEMM2)
// ---------------------------------------------------------------------------
__device__ __forceinline__ void stage_tile(
    const ushort* aS0, const ushort* aS1, const ushort* bS0, const ushort* bS1,
    ushort* ldsA, ushort* ldsB, int wave, int k0)
{
  #pragma unroll
  for (int h = 0; h < 2; h++) {
    gld16(aS0 + k0 + h * 32, ldsA + h * 4096 + (wave * 2 + 0) * 512);
    gld16(aS1 + k0 + h * 32, ldsA + h * 4096 + (wave * 2 + 1) * 512);
    gld16(bS0 + k0 + h * 32, ldsB + h * 4096 + (wave * 2 + 0) * 512);
    gld16(bS1 + k0 + h * 32, ldsB + h * 4096 + (wave * 2 + 1) * 512);
  }
}

// ---------------------------------------------------------------------------
// bf16 MFMA GEMM (NT): 128x128 tile, BK=64, double-buffered. Used for GEMM2
// (M=2048,N=2048: only 64 tiles at 256 width -> 128 tile keeps CUs busy).
// ---------------------------------------------------------------------------
__global__ __launch_bounds__(256) void gemm_bf16_nt(
    const ushort* __restrict__ A, const ushort* __restrict__ B,
    float* __restrict__ C, int M, int N, int K)
{
  __shared__ ushort sL[2][2][8192];   // [buf][A/B][2 halves x 8 segs x 512]
  int t = threadIdx.x;
  int wave = t >> 6, lane = t & 63;
  int wm = wave >> 1, wn = wave & 1;
  int lrow = lane & 15, quad = lane >> 4;
  int mt = blockIdx.x, nt = blockIdx.y;

  f32x4 acc[4][4];
  #pragma unroll
  for (int i = 0; i < 4; i++)
    #pragma unroll
    for (int j = 0; j < 4; j++)
      #pragma unroll
      for (int r = 0; r < 4; r++) acc[i][j][r] = 0.f;

  const ushort* aS0 = A + (size_t)(mt * 128 + (wave * 2 + 0) * 16 + lrow) * K + quad * 8;
  const ushort* aS1 = A + (size_t)(mt * 128 + (wave * 2 + 1) * 16 + lrow) * K + quad * 8;
  const ushort* bS0 = B + (size_t)(nt * 128 + (wave * 2 + 0) * 16 + lrow) * K + quad * 8;
  const ushort* bS1 = B + (size_t)(nt * 128 + (wave * 2 + 1) * 16 + lrow) * K + quad * 8;

  stage_tile(aS0, aS1, bS0, bS1, &sL[0][0][0], &sL[0][1][0], wave, 0);
  __syncthreads();

  const int NK = K >> 6;
  for (int it = 0; it < NK; it++) {
    if (it + 1 < NK)
      stage_tile(aS0, aS1, bS0, bS1,
                 &sL[(it + 1) & 1][0][0], &sL[(it + 1) & 1][1][0],
                 wave, (it + 1) * 64);
    const ushort* bufA = &sL[it & 1][0][0];
    const ushort* bufB = &sL[it & 1][1][0];
    #pragma unroll
    for (int h = 0; h < 2; h++) {
      bf16x8 af[4], bfr[4];
      #pragma unroll
      for (int i = 0; i < 4; i++)
        af[i] = *(const bf16x8*)(bufA + h * 4096 + (wm * 4 + i) * 512 + lane * 8);
      #pragma unroll
      for (int j = 0; j < 4; j++)
        bfr[j] = *(const bf16x8*)(bufB + h * 4096 + (wn * 4 + j) * 512 + lane * 8);
      #pragma unroll
      for (int i = 0; i < 4; i++)
        #pragma unroll
        for (int j = 0; j < 4; j++)
          acc[i][j] = __builtin_amdgcn_mfma_f32_16x16x32_bf16(af[i], bfr[j], acc[i][j], 0, 0, 0);
    }
    __syncthreads();
  }

  #pragma unroll
  for (int i = 0; i < 4; i++) {
    int m_base = mt * 128 + wm * 64 + i * 16 + quad * 4;
    #pragma unroll
    for (int j = 0; j < 4; j++) {
      int n = nt * 128 + wn * 64 + j * 16 + lrow;
      #pragma unroll
      for (int rr = 0; rr < 4; rr++)
        C[(size_t)(m_base + rr) * N + n] = acc[i][j][rr];
    }
  }
}

// ---------------------------------------------------------------------------
// conv_state_new[b][c][j] = mixed_qkv[b][S-3+j][c]  (from (B,S,NBIG) C-matrix)
// ---------------------------------------------------------------------------
__global__ void convstate_kernel(const float* __restrict__ Cbig,
                                 float* __restrict__ out)
{
  int idx = blockIdx.x * blockDim.x + threadIdx.x;
  if (idx >= B_ * CC_ * 3) return;
  int j = idx % 3;
  int c = (idx / 3) % CC_;
  int b = idx / (3 * CC_);
  out[idx] = Cbig[((size_t)(b * S_ + (S_ - 3 + j))) * NBIG + c];
}

// ---------------------------------------------------------------------------
// prep_qkv: conv(K=4)+silu; l2norm q/k heads. qkv read from C-matrix cols 0..8191
// ---------------------------------------------------------------------------
__global__ __launch_bounds__(128) void prep_qkv(
    const float* __restrict__ Cbig, const float* __restrict__ conv_state,
    const float* __restrict__ conv_w,
    float* __restrict__ Qn, float* __restrict__ Kn, float* __restrict__ Vb)
{
  int group = blockIdx.x, s = blockIdx.y, b = blockIdx.z;
  int t = threadIdx.x;
  int c = group * 128 + t;
  float acc = 0.f;
  #pragma unroll
  for (int kk = 0; kk < 4; kk++) {
    int sp = s - 3 + kk;
    float x = (sp < 0) ? conv_state[((size_t)(b * CC_ + c)) * 3 + (3 + sp)]
                       : Cbig[((size_t)(b * S_ + sp)) * NBIG + c];
    acc += conv_w[c * 4 + kk] * x;
  }
  float val = acc / (1.f + __expf(-acc));   // silu

  if (group < 32) {
    __shared__ float red2[2];
    float p = val * val;
    #pragma unroll
    for (int off = 32; off > 0; off >>= 1) p += __shfl_xor(p, off);
    if ((t & 63) == 0) red2[t >> 6] = p;
    __syncthreads();
    float r = rsqrtf(red2[0] + red2[1] + 1e-6f);
    if (group < 16) {
      r *= 0.08838834764831845f;  // 128^-0.5
      Qn[(((size_t)(b * HK_ + group)) * S_ + s) * DK_ + t] = val * r;
    } else {
      Kn[(((size_t)(b * HK_ + (group - 16))) * S_ + s) * DK_ + t] = val * r;
    }
  } else {
    Vb[(((size_t)(b * HV_ + (group - 32))) * S_ + s) * DV_ + t] = val;
  }
}

// ---------------------------------------------------------------------------
// prep_gb: g/beta from C-matrix cols 12288..12351
// ---------------------------------------------------------------------------
__global__ void prep_gb(const float* __restrict__ Cbig,
                        const float* __restrict__ A_log, const float* __restrict__ dt_bias,
                        float* __restrict__ g_buf, float* __restrict__ beta_buf)
{
  int idx = blockIdx.x * blockDim.x + threadIdx.x;
  if (idx >= B_ * HV_ * S_) return;
  int s = idx & (S_ - 1);
  int hv = (idx >> 10) & 31;
  int b = idx >> 15;
  float bv = Cbig[((size_t)(b * S_ + s)) * NBIG + 12288 + hv];
  float av = Cbig[((size_t)(b * S_ + s)) * NBIG + 12320 + hv];
  float x = av + dt_bias[hv];
  float sp = (x > 20.f) ? x : log1pf(__expf(x));
  g_buf[idx] = -__expf(A_log[hv]) * sp;
  beta_buf[idx] = 1.f / (1.f + __expf(-bv));
}

// ---------------------------------------------------------------------------
// cp_kernel v2: per (b,hv,chunk). G cumsum, M, A, Tinv, Kc, D0.
// ---------------------------------------------------------------------------
__device__ __forceinline__ int swf4(int r, int f) { return r * 32 + (f ^ (r & 31)); }

__global__ __launch_bounds__(256) void cp_kernel(
    const float* __restrict__ Qn, const float* __restrict__ Kn,
    const float* __restrict__ Vb,
    const float* __restrict__ g_buf, const float* __restrict__ beta_buf,
    float* __restrict__ G_buf, float* __restrict__ M_buf,
    float* __restrict__ KcD, float* __restrict__ D0p)
{
  __shared__ float sK[64 * 128];
  __shared__ float sX[32 * 128];
  __shared__ float sT[64 * 65];   // stride-65: conflict-free column reads
  __shared__ float sGB[128];      // [0:64) G cumsum, [64:128) beta
  float* sG  = sGB;
  float* sBe = sGB + 64;
  float* sA  = sX;
  float* tTw = sX;
  float* tTb = sX;
  float4* sK4 = (float4*)sK;
  float4* sX4 = (float4*)sX;

  const int ch = blockIdx.x;
  const int bh = ch / NC_, c = ch % NC_;
  const int b = bh >> 5, hv = bh & 31, hk = hv >> 1;
  const int s0 = c * CS_;
  const int t = threadIdx.x;
  const size_t gOff = (size_t)bh * S_ + s0;

  if (t < 64) {
    float Gw0 = g_buf[gOff + t];
    #pragma unroll
    for (int off = 1; off < 64; off <<= 1) {
      float o = __shfl_up(Gw0, off);
      if (t >= off) Gw0 += o;
    }
    G_buf[gOff + t] = Gw0;
    sG[t] = Gw0;
    sBe[t] = beta_buf[gOff + t];
  }
  {
    const float4* src = (const float4*)(Kn + ((size_t)(b * HK_ + hk) * S_ + s0) * DK_);
    #pragma unroll
    for (int u = 0; u < 8; u++) {
      int idx = u * 256 + t;
      sK4[swf4(idx >> 5, idx & 31)] = src[idx];
    }
  }
  __syncthreads();

  // ---- M = (Q e^{Gi-Gj} K^T) masked ----
  const float4* qsrc = (const float4*)(Qn + ((size_t)(b * HK_ + hk) * S_ + s0) * DK_);
  {
    int ti2 = t >> 4, tj = t & 15;
    for (int h = 0; h < 2; h++) {
      #pragma unroll
      for (int u = 0; u < 4; u++) {
        int idx = u * 256 + t;
        sX4[swf4(idx >> 5, idx & 31)] = qsrc[h * 1024 + idx];
      }
      __syncthreads();
      float accM[2][4];
      #pragma unroll
      for (int a = 0; a < 2; a++)
        #pragma unroll
        for (int e = 0; e < 4; e++) accM[a][e] = 0.f;
      for (int k4 = 0; k4 < 32; k4++) {
        float4 qv[2], kv[4];
        qv[0] = sX4[swf4(ti2, k4)];
        qv[1] = sX4[swf4(ti2 + 16, k4)];
        #pragma unroll
        for (int e = 0; e < 4; e++) kv[e] = sK4[swf4(tj + 16 * e, k4)];
        #pragma unroll
        for (int a = 0; a < 2; a++)
          #pragma unroll
          for (int e = 0; e < 4; e++)
            accM[a][e] += qv[a].x * kv[e].x + qv[a].y * kv[e].y +
                          qv[a].z * kv[e].z + qv[a].w * kv[e].w;
      }
      #pragma unroll
      for (int a = 0; a < 2; a++) {
        int iG = h * 32 + ti2 + 16 * a;
        float Gi = sG[iG];
        #pragma unroll
        for (int e = 0; e < 4; e++) {
          int j = tj + 16 * e;
          float m = (j <= iG) ? __expf(Gi - sG[j]) * accM[a][e] : 0.f;
          M_buf[(size_t)ch * 4096 + iG * 64 + j] = m;
        }
      }
      __syncthreads();
    }
  }

  // ---- A = beta e^{Gi-Gj} (K K^T) strictly-lower ----
  {
    int ti = t >> 4, tj = t & 15;
    float accA[4][4];
    #pragma unroll
    for (int a = 0; a < 4; a++)
      #pragma unroll
      for (int e = 0; e < 4; e++) accA[a][e] = 0.f;
    for (int k4 = 0; k4 < 32; k4++) {
      float4 ki[4], kj[4];
      #pragma unroll
      for (int e = 0; e < 4; e++) {
        ki[e] = sK4[swf4(ti + 16 * e, k4)];
        kj[e] = sK4[swf4(tj + 16 * e, k4)];
      }
      #pragma unroll
      for (int a = 0; a < 4; a++)
        #pragma unroll
        for (int e = 0; e < 4; e++)
          accA[a][e] += ki[a].x * kj[e].x + ki[a].y * kj[e].y +
                        ki[a].z * kj[e].z + ki[a].w * kj[e].w;
    }
    float resA[4][4];
    #pragma unroll
    for (int a = 0; a < 4; a++) {
      int i = ti + 16 * a;
      float Gi = sG[i], Bi = sBe[i];
      #pragma unroll
      for (int e = 0; e < 4; e++) {
        int j = tj + 16 * e;
        resA[a][e] = (j < i) ? Bi * __expf(Gi - sG[j]) * accA[a][e] : 0.f;
      }
    }
    __syncthreads();
    #pragma unroll
    for (int a = 0; a < 4; a++)
      #pragma unroll
      for (int e = 0; e < 4; e++)
        sA[(ti + 16 * a) * 64 + (tj + 16 * e)] = resA[a][e];
  }
  __syncthreads();

  // ---- Tinv: forward substitution, column t per thread (wave 0) ----
  if (t < 64) {
    sT[t] = (t == 0) ? 1.f : 0.f;
    for (int i = 1; i < 64; i++) {
      float acc = 0.f;
      for (int j = 0; j < i; j++) acc += sA[i * 64 + j] * sT[j * 65 + t];
      sT[i * 65 + t] = ((t == i) ? 1.f : 0.f) - acc;
    }
  }
  __syncthreads();

  // ---- tTw[j][i] = Tinv[i][j] * beta[j] e^{G[j]}  (all 256 threads) ----
  #pragma unroll
  for (int u = 0; u < 16; u++) {
    int idx = u * 256 + t;
    int tcol = idx & 63;
    int j = idx >> 6;
    float wj = sBe[j] * __expf(sG[j]);
    tTw[j * 64 + tcol] = sT[tcol * 65 + j] * wj;
  }
  __syncthreads();

  // ---- Kc = tTw^T K : rows i04*4+r, cols tk*8..tk*8+7 ----
  {
    int i04 = t >> 4, tk = t & 15;
    float accK[4][8];
    #pragma unroll
    for (int r = 0; r < 4; r++)
      #pragma unroll
      for (int u = 0; u < 8; u++) accK[r][u] = 0.f;
    for (int j = 0; j < 64; j++) {
      float4 tw = ((float4*)tTw)[j * 16 + i04];
      float4 ka = sK4[swf4(j, tk * 2)];
      float4 kb = sK4[swf4(j, tk * 2 + 1)];
      float tws[4] = {tw.x, tw.y, tw.z, tw.w};
      float kvv[8] = {ka.x, ka.y, ka.z, ka.w, kb.x, kb.y, kb.z, kb.w};
      #pragma unroll
      for (int r = 0; r < 4; r++)
        #pragma unroll
        for (int u = 0; u < 8; u++)
          accK[r][u] += tws[r] * kvv[u];
    }
    size_t base = (size_t)ch * NBIG;
    #pragma unroll
    for (int r = 0; r < 4; r++) {
      *(float4*)(&KcD[base + (size_t)(i04 * 4 + r) * 128 + tk * 8]) =
          make_float4(accK[r][0], accK[r][1], accK[r][2], accK[r][3]);
      *(float4*)(&KcD[base + (size_t)(i04 * 4 + r) * 128 + tk * 8 + 4]) =
          make_float4(accK[r][4], accK[r][5], accK[r][6], accK[r][7]);
    }
  }
  __syncthreads();

  // ---- tTb[j][i] = Tinv[i][j] * beta[j] (all threads) + stage V into sK ----
  #pragma unroll
  for (int u = 0; u < 16; u++) {
    int idx = u * 256 + t;
    int tcol = idx & 63;
    int j = idx >> 6;
    tTb[j * 64 + tcol] = sT[tcol * 65 + j] * sBe[j];
  }
  {
    const float4* src = (const float4*)(Vb + ((size_t)bh * S_ + s0) * DV_);
    #pragma unroll
    for (int u = 0; u < 8; u++) {
      int idx = u * 256 + t;
      sK4[swf4(idx >> 5, idx & 31)] = src[idx];
    }
  }
  __syncthreads();

  // ---- D0 = tTb^T V : rows i04*4+r, cols tv*8..tv*8+7 ----
  {
    int i04 = t >> 4, tv_ = t & 15;
    float accD[4][8];
    #pragma unroll
    for (int r = 0; r < 4; r++)
      #pragma unroll
      for (int u = 0; u < 8; u++) accD[r][u] = 0.f;
    for (int j = 0; j < 64; j++) {
      float4 tb = ((float4*)tTb)[j * 16 + i04];
      float4 va = sK4[swf4(j, tv_ * 2)];
      float4 vb = sK4[swf4(j, tv_ * 2 + 1)];
      float tbs[4] = {tb.x, tb.y, tb.z, tb.w};
      float vvv[8] = {va.x, va.y, va.z, va.w, vb.x, vb.y, vb.z, vb.w};
      #pragma unroll
      for (int r = 0; r < 4; r++)
        #pragma unroll
        for (int u = 0; u < 8; u++)
          accD[r][u] += tbs[r] * vvv[u];
    }
    size_t base = (size_t)ch * NBIG;
    #pragma unroll
    for (int r = 0; r < 4; r++) {
      *(float4*)(&D0p[base + (size_t)(i04 * 4 + r) * 128 + tv_ * 8]) =
          make_float4(accD[r][0], accD[r][1], accD[r][2], accD[r][3]);
      *(float4*)(&D0p[base + (size_t)(i04 * 4 + r) * 128 + tv_ * 8 + 4]) =
          make_float4(accD[r][4], accD[r][5], accD[r][6], accD[r][7]);
    }
  }
}

// ---------------------------------------------------------------------------
// phaseb v6: 256 blocks x 512 threads. T14 async-stage: next-chunk globals
// (KcD/Qn after phase A, D0p after phase B, Kn after phase C) prefetched into
// registers with ~1 chunk of latency slack; G_buf staged once in LDS (sGf);
// #pragma unroll 4 on phase B/D k-loops so LDS loads pipeline under FMAs.
// Same arithmetic & summation order as v5.
// ---------------------------------------------------------------------------
__global__ __launch_bounds__(512) void phaseb_kernel(
    const float* __restrict__ rec_state, const float* __restrict__ Qn,
    const float* __restrict__ Kn, const float* __restrict__ G_buf,
    float* __restrict__ KcD, const float* __restrict__ D0p,
    float* __restrict__ Oq_buf, float* __restrict__ final_state)
{
  __shared__ float sS[128 * 32];    // state [k][v]
  __shared__ float sKT[128 * 64];   // Kc^T [k][i]; then Kd (swizzled) [i][k]
  __shared__ float sQT[128 * 64];   // Qb^T [k][i]
  __shared__ float sD[64 * 32];     // D [i][v]
  __shared__ float sR[2][64 * 32];  // k-group-1 partials: [0]=D, [1]=O
  __shared__ float sGf[1024];       // G cumsum for this bh (whole sequence)

  const int blk = blockIdx.x;       // xcd | vq<<3 | g<<5
  const int bh = (blk & 7) | ((blk >> 5) << 3);
  const int vq = (blk >> 3) & 3;
  const int b = bh >> 5, hv = bh & 31, hk = hv >> 1;
  const int t = threadIdx.x;
  const int vbase = vq * 32;
  const float* gG = G_buf + (size_t)bh * S_;

  #pragma unroll
  for (int u = 0; u < 2; u++) {
    int idx = u * 512 + t;
    int k = idx >> 3;
    int v4 = (idx & 7) * 4;
    *(float4*)(&sS[k * 32 + v4]) =
        *(const float4*)(&rec_state[((size_t)bh * 128 + k) * 128 + vbase + v4]);
  }
  sGf[t] = gG[t];
  sGf[t + 512] = gG[t + 512];
  __syncthreads();

  const int si = t & 63, skq = t >> 6;   // stage: row si, k-block skq (16 k)
  const int kg = t >> 8;                 // phase-B k-group (wave-uniform)
  const int tt = t & 255;
  const int ti = tt >> 3, tv = t & 7;    // phase-B: 2 i-rows, 4 v
  const int tp = t >> 3;                 // phase-D: k-pair in [0,64)

  const float* qBase = Qn + ((size_t)(b * HK_ + hk) * S_ + si) * DK_ + skq * 16;
  const float* kBase = Kn + ((size_t)(b * HK_ + hk) * S_ + si) * DK_ + skq * 16;

  float4 rKc[4], rQ[4], rKn[4], rD0[2];
  {  // prologue prefetch: chunk 0
    const size_t ch0 = (size_t)bh * NC_;
    const float* kcRow = KcD + ch0 * NBIG + si * 128 + skq * 16;
    #pragma unroll
    for (int u = 0; u < 4; u++) {
      rKc[u] = *(const float4*)(kcRow + u * 4);
      rQ[u]  = *(const float4*)(qBase + u * 4);
      rKn[u] = *(const float4*)(kBase + u * 4);
    }
    if (kg == 0) {
      #pragma unroll
      for (int r = 0; r < 2; r++)
        rD0[r] = *(const float4*)(&D0p[ch0 * NBIG + (size_t)(ti * 2 + r) * 128 + vbase + tv * 4]);
    }
  }

  for (int c = 0; c < NC_; c++) {
    const size_t ch = (size_t)bh * NC_ + c;
    const int s0 = c * CS_;
    const int cn = (c + 1 < NC_) ? c + 1 : c;   // clamped (last prefetch dead)
    const size_t chn = (size_t)bh * NC_ + cn;
    const int s0n = cn * CS_;
    const float GC = sGf[s0 + 63];
    const float eGC = __expf(GC);

    // phase A: write prefetched Kc^T [k][i] and Qb^T [k][i] to LDS
    {
      float eGi = __expf(sGf[s0 + si]);
      #pragma unroll
      for (int u = 0; u < 4; u++) {
        float4 kc = rKc[u];
        float4 qv = rQ[u];
        int kk = skq * 16 + u * 4;
        sKT[(kk + 0) * 64 + si] = kc.x; sKT[(kk + 1) * 64 + si] = kc.y;
        sKT[(kk + 2) * 64 + si] = kc.z; sKT[(kk + 3) * 64 + si] = kc.w;
        sQT[(kk + 0) * 64 + si] = qv.x * eGi; sQT[(kk + 1) * 64 + si] = qv.y * eGi;
        sQT[(kk + 2) * 64 + si] = qv.z * eGi; sQT[(kk + 3) * 64 + si] = qv.w * eGi;
      }
    }
    __syncthreads();

    // prefetch next chunk's Kc/Q (consumed at next phase A; ~1 chunk slack)
    {
      const float* kcRow = KcD + chn * NBIG + si * 128 + skq * 16;
      const float* qRow  = qBase + (size_t)s0n * DK_;
      #pragma unroll
      for (int u = 0; u < 4; u++) {
        rKc[u] = *(const float4*)(kcRow + u * 4);
        rQ[u]  = *(const float4*)(qRow + u * 4);
      }
    }

    // phase B: D/O partials over k in [kg*64, kg*64+64)
    {
      float accD[2][4], accO[2][4];
      #pragma unroll
      for (int r = 0; r < 2; r++) {
        accO[r][0] = accO[r][1] = accO[r][2] = accO[r][3] = 0.f;
        accD[r][0] = accD[r][1] = accD[r][2] = accD[r][3] = 0.f;
      }
      if (kg == 0) {
        #pragma unroll
        for (int r = 0; r < 2; r++) {
          accD[r][0] = rD0[r].x; accD[r][1] = rD0[r].y;
          accD[r][2] = rD0[r].z; accD[r][3] = rD0[r].w;
        }
      }
      const int k0 = kg << 6;
      #pragma unroll 4
      for (int k = k0; k < k0 + 64; k++) {
        float2 kc = *(const float2*)(&sKT[k * 64 + ti * 2]);
        float2 qb = *(const float2*)(&sQT[k * 64 + ti * 2]);
        float4 sv = *(const float4*)(&sS[k * 32 + tv * 4]);
        accD[0][0] -= kc.x * sv.x; accD[0][1] -= kc.x * sv.y;
        accD[0][2] -= kc.x * sv.z; accD[0][3] -= kc.x * sv.w;
        accD[1][0] -= kc.y * sv.x; accD[1][1] -= kc.y * sv.y;
        accD[1][2] -= kc.y * sv.z; accD[1][3] -= kc.y * sv.w;
        accO[0][0] += qb.x * sv.x; accO[0][1] += qb.x * sv.y;
        accO[0][2] += qb.x * sv.z; accO[0][3] += qb.x * sv.w;
        accO[1][0] += qb.y * sv.x; accO[1][1] += qb.y * sv.y;
        accO[1][2] += qb.y * sv.z; accO[1][3] += qb.y * sv.w;
      }
      if (kg == 1) {
        #pragma unroll
        for (int r = 0; r < 2; r++) {
          int i = ti * 2 + r;
          *(float4*)(&sR[0][i * 32 + tv * 4]) =
              make_float4(accD[r][0], accD[r][1], accD[r][2], accD[r][3]);
          *(float4*)(&sR[1][i * 32 + tv * 4]) =
              make_float4(accO[r][0], accO[r][1], accO[r][2], accO[r][3]);
        }
      }
      __syncthreads();   // sKT/sQT reads done; sR partials visible
      if (kg == 0) {
        #pragma unroll
        for (int r = 0; r < 2; r++) {
          int i = ti * 2 + r;
          float4 pD = *(const float4*)(&sR[0][i * 32 + tv * 4]);
          float4 pO = *(const float4*)(&sR[1][i * 32 + tv * 4]);
          float4 dv = make_float4(accD[r][0] + pD.x, accD[r][1] + pD.y,
                                  accD[r][2] + pD.z, accD[r][3] + pD.w);
          float4 ov = make_float4(accO[r][0] + pO.x, accO[r][1] + pO.y,
                                  accO[r][2] + pO.z, accO[r][3] + pO.w);
          *(float4*)(&sD[i * 32 + tv * 4]) = dv;
          *(float4*)(&KcD[ch * NBIG + (size_t)i * 128 + vbase + tv * 4]) = dv;
          *(float4*)(&Oq_buf[ch * 8192 + (size_t)i * 128 + vbase + tv * 4]) = ov;
        }
        // prefetch next chunk's D0 (consumed at next phase B)
        #pragma unroll
        for (int r = 0; r < 2; r++)
          rD0[r] = *(const float4*)(&D0p[chn * NBIG + (size_t)(ti * 2 + r) * 128 + vbase + tv * 4]);
      }
    }

    // phase C: stage Kd (scaled, swizzled) into sKT (safe: sKT no longer read)
    {
      float sc = __expf(GC - sGf[s0 + si]);
      #pragma unroll
      for (int u = 0; u < 4; u++) {
        float4 x = rKn[u];
        x.x *= sc; x.y *= sc; x.z *= sc; x.w *= sc;
        int kgr = skq * 4 + u;
        *(float4*)(&sKT[si * 128 + 4 * (kgr ^ (si & 31))]) = x;
      }
    }
    // prefetch next chunk's Kn (consumed at next phase C)
    {
      const float* kRow = kBase + (size_t)s0n * DK_;
      #pragma unroll
      for (int u = 0; u < 4; u++) rKn[u] = *(const float4*)(kRow + u * 4);
    }
    __syncthreads();   // sD final + Kd staged

    // phase D: state update, 2 k-rows per thread, full i-sum
    {
      float acc[2][4];
      acc[0][0] = acc[0][1] = acc[0][2] = acc[0][3] = 0.f;
      acc[1][0] = acc[1][1] = acc[1][2] = acc[1][3] = 0.f;
      const int kgr = tp >> 1, kh = (tp & 1) * 2;
      #pragma unroll 4
      for (int i = 0; i < 64; i++) {
        float4 d  = *(const float4*)(&sD[i * 32 + tv * 4]);
        float2 ka = *(const float2*)(&sKT[i * 128 + 4 * (kgr ^ (i & 31)) + kh]);
        acc[0][0] += ka.x * d.x; acc[0][1] += ka.x * d.y;
        acc[0][2] += ka.x * d.z; acc[0][3] += ka.x * d.w;
        acc[1][0] += ka.y * d.x; acc[1][1] += ka.y * d.y;
        acc[1][2] += ka.y * d.z; acc[1][3] += ka.y * d.w;
      }
      #pragma unroll
      for (int r = 0; r < 2; r++) {
        int k = tp * 2 + r;
        float4 s = *(const float4*)(&sS[k * 32 + tv * 4]);
        s.x = s.x * eGC + acc[r][0]; s.y = s.y * eGC + acc[r][1];
        s.z = s.z * eGC + acc[r][2]; s.w = s.w * eGC + acc[r][3];
        *(float4*)(&sS[k * 32 + tv * 4]) = s;
      }
    }
    __syncthreads();
  }

  #pragma unroll
  for (int u = 0; u < 2; u++) {
    int idx = u * 512 + t;
    int k = idx >> 3;
    int v4 = (idx & 7) * 4;
    *(float4*)(&final_state[((size_t)bh * 128 + k) * 128 + vbase + v4]) =
        *(const float4*)(&sS[k * 32 + v4]);
  }
}

// ---------------------------------------------------------------------------
// phasec: O = Oq + M*D, RMS-norm + weight + silu(z) gate -> bf16 zg
// ---------------------------------------------------------------------------
__global__ __launch_bounds__(128) void phasec_kernel(
    const float* __restrict__ KcD, const float* __restrict__ Oq_buf,
    const float* __restrict__ M_buf, const float* __restrict__ norm_weight,
    const float* __restrict__ Cbig, ushort* __restrict__ zg_bf)
{
  __shared__ float sM[4096];
  __shared__ float red[2][2];
  int ch = blockIdx.x;
  int bh = ch / NC_, c = ch % NC_;
  int b = bh >> 5, hv = bh & 31;
  int s0 = c * CS_;
  int v = threadIdx.x;

  float Dr[64];
  #pragma unroll
  for (int j = 0; j < 64; j++) Dr[j] = KcD[(size_t)ch * NBIG + j * 128 + v];
  {
    const float4* src = (const float4*)(M_buf + (size_t)ch * 4096);
    #pragma unroll
    for (int u = 0; u < 8; u++) ((float4*)sM)[u * 128 + v] = src[u * 128 + v];
  }
  __syncthreads();
  float nw = norm_weight[v];

  for (int i = 0; i < 64; i++) {
    float o = Oq_buf[(size_t)ch * 8192 + i * 128 + v];
    const float4* mr = (const float4*)(sM + i * 64);
    #pragma unroll
    for (int j4 = 0; j4 < 16; j4++) {
      float4 m = mr[j4];
      o += m.x * Dr[4 * j4] + m.y * Dr[4 * j4 + 1] +
           m.z * Dr[4 * j4 + 2] + m.w * Dr[4 * j4 + 3];
    }
    float p = o * o;
    #pragma unroll
    for (int off = 32; off > 0; off >>= 1) p += __shfl_xor(p, off);
    if ((v & 63) == 0) red[i & 1][v >> 6] = p;
    __syncthreads();
    float var = (red[i & 1][0] + red[i & 1][1]) * (1.f / 128.f);
    float xn = o * rsqrtf(var + 1e-6f) * nw;
    float zv = Cbig[((size_t)(b * S_ + s0 + i)) * NBIG + 8192 + hv * DV_ + v];
    zg_bf[((size_t)(b * S_ + s0 + i)) * VALDIM_ + hv * DV_ + v] =
        f2bf_rne(xn * (zv / (1.f + __expf(-zv))));
  }
}

// ---------------------------------------------------------------------------
extern "C" void kernel_launch(void* const* d_in, const int* in_sizes, int n_in,
                              void* d_out, int out_size, void* d_ws, size_t ws_size,
                              hipStream_t stream)
{
  const float* hs          = (const float*)d_in[0];
  const float* conv_state  = (const float*)d_in[1];
  const float* rec_state   = (const float*)d_in[2];
  const float* W_qkv       = (const float*)d_in[3];
  const float* W_z         = (const float*)d_in[4];
  const float* W_b         = (const float*)d_in[5];
  const float* W_a         = (const float*)d_in[6];
  const float* conv_w      = (const float*)d_in[7];
  const float* dt_bias     = (const float*)d_in[8];
  const float* A_log       = (const float*)d_in[9];
  const float* norm_weight = (const float*)d_in[10];
  const float* W_out       = (const float*)d_in[11];

  float* out       = (float*)d_out;                      // (B,S,H)
  float* out_conv  = out + (size_t)B_ * S_ * H_;         // (B,C,3)
  float* out_state = out_conv + (size_t)B_ * CC_ * 3;    // (B,HV,DK,DV)

  float* ws = (float*)d_ws;
  float* Cbig = ws;                            // (2048, 12416) = 25,427,968
  float* KcD  = Cbig;
  float* D0p  = Cbig + (size_t)1024 * NBIG;
  float* g_buf    = ws + 25427968;
  float* beta_buf = ws + 25493504;
  float* G_buf    = ws + 25559040;
  float* Qn       = ws + 25624576;
  float* Kn       = ws + 29818880;
  float* Vb       = ws + 34013184;
  float* M_buf    = ws + 42401792;
  float* Oq_buf   = Vb;

  // Wcat_bf: (12544, 2048) ushorts = 12,845,056 float-slots
  ushort* Wcat_bf = (ushort*)(ws + 25427968);
  // hs_bf past the padded Wcat; lives in Vb's dead window, ends at
  // 40,370,176 < M_buf (42,401,792). Total ws usage unchanged (46,596,096 f).
  ushort* hs_bf   = (ushort*)(ws + 38273024);
  ushort* zg_bf   = (ushort*)Qn;
  ushort* Wout_bf = (ushort*)Kn;

  const int M = B_ * S_;  // 2048

  // 0. converts
  f2bf_kernel<<<(M * H_) / 1024, 256, 0, stream>>>(hs, hs_bf, M * H_);
  wcat_kernel<<<(NBIGP * H_) / 1024, 256, 0, stream>>>(W_qkv, W_z, W_b, W_a, Wcat_bf);
  // 1. fused qkv|z|b|a GEMM -> Cbig (256x256, k-split even phases,
  //    counted vmcnt/lgkm pipeline)
  gemm256_8ph<<<dim3(M / 256, NBIGP / 256), 512, 0, stream>>>(hs_bf, Wcat_bf, Cbig, NBIG, H_);
  // 2. conv_state_new output
  convstate_kernel<<<(B_ * CC_ * 3 + 255) / 256, 256, 0, stream>>>(Cbig, out_conv);
  // 3. conv+silu+l2norm -> Qn,Kn,Vb ; gates
  prep_qkv<<<dim3(64, S_, B_), 128, 0, stream>>>(Cbig, conv_state, conv_w, Qn, Kn, Vb);
  prep_gb<<<(B_ * HV_ * S_ + 255) / 256, 256, 0, stream>>>(Cbig, A_log, dt_bias, g_buf, beta_buf);
  // 4. per-chunk matrices (v2: padded sT, parallel tT builds, float4 Kc/D0)
  cp_kernel<<<B_ * HV_ * NC_, 256, 0, stream>>>(Qn, Kn, Vb, g_buf, beta_buf,
                                                G_buf, M_buf, KcD, D0p);
  // 5. sequential chunk recurrence (v6: register prefetch + LDS G + unroll)
  phaseb_kernel<<<B_ * HV_ * 4, 512, 0, stream>>>(rec_state, Qn, Kn, G_buf,
                                                  KcD, D0p, Oq_buf, out_state);
  // 6. W_out convert + intra-chunk output/RMS/gate -> bf16
  f2bf_kernel<<<(H_ * VALDIM_) / 1024, 256, 0, stream>>>(W_out, Wout_bf, H_ * VALDIM_);
  phasec_kernel<<<B_ * HV_ * NC_, 128, 0, stream>>>(KcD, Oq_buf, M_buf,
                                                    norm_weight, Cbig, zg_bf);
  // 7. output GEMM (128x128: only 64 tiles at 256 width -> keep old kernel)
  gemm_bf16_nt<<<dim3(M / 128, H_ / 128), 256, 0, stream>>>(zg_bf, Wout_bf, out, M, H_, VALDIM_);
}